// Round 8
// baseline (17345.117 us; speedup 1.0000x reference)
//
#include <hip/hip_runtime.h>
#include <hip/hip_bf16.h>

typedef unsigned short u16;
typedef unsigned int u32;
typedef __bf16 bf16t;
typedef bf16t bf16x8 __attribute__((ext_vector_type(8)));
typedef float f32x4 __attribute__((ext_vector_type(4)));

constexpr int S_   = 2048;
constexpr int D_   = 2048;
constexpr int H_   = 16;
constexpr int DH_  = 128;
constexpr int L_   = 2;
constexpr int DFF_ = 8192;
constexpr int V_   = 32000;
constexpr int R_   = 8;

#define MFMA16(a, b, c) __builtin_amdgcn_mfma_f32_16x16x32_bf16(a, b, c, 0, 0, 0)

__constant__ float c_nf4[16] = {
  -1.0f, -0.6961928009986877f, -0.5250730514526367f, -0.39491748809814453f,
  -0.28444138169288635f, -0.18477343022823334f, -0.09105003625154495f, 0.0f,
  0.07958029955625534f, 0.16093020141124725f, 0.24611230194568634f,
  0.33791524171829224f, 0.44070982933044434f, 0.5626170039176941f,
  0.7229568362236023f, 1.0f };

__device__ __forceinline__ u16 f2bf(float f) {
  union { float f; u32 u; } v; v.f = f;
  u32 r = v.u + 0x7fffu + ((v.u >> 16) & 1u);
  return (u16)(r >> 16);
}
__device__ __forceinline__ float bf2f(u16 h) {
  union { u32 u; float f; } v; v.u = ((u32)h) << 16; return v.f;
}

// ---------------- embedding gather ----------------
__global__ __launch_bounds__(256) void k_gather(const int* __restrict__ ids,
                                                const float* __restrict__ emb,
                                                float* __restrict__ h) {
  int t = blockIdx.x * 256 + threadIdx.x;
  int s = t >> 11;
  int d = t & 2047;
  h[t] = emb[(size_t)ids[s] * D_ + d];
}

// ---------------- rmsnorm f32 -> bf16 ----------------
__global__ __launch_bounds__(256) void k_rmsnorm(const float* __restrict__ in,
                                                 const float* __restrict__ w,
                                                 u16* __restrict__ out) {
  int s = blockIdx.x;
  const float* x = in + (size_t)s * D_;
  float ss = 0.f;
  for (int d = threadIdx.x; d < D_; d += 256) { float v = x[d]; ss += v * v; }
#pragma unroll
  for (int m = 1; m < 64; m <<= 1) ss += __shfl_xor(ss, m, 64);
  __shared__ float sh[4];
  if ((threadIdx.x & 63) == 0) sh[threadIdx.x >> 6] = ss;
  __syncthreads();
  ss = sh[0] + sh[1] + sh[2] + sh[3];
  float sc = rsqrtf(ss * (1.0f / D_) + 1e-6f);
  u16* o = out + (size_t)s * D_;
  for (int d = threadIdx.x; d < D_; d += 256) o[d] = f2bf(x[d] * sc * w[d]);
}

// ---------------- NF4 dequant ----------------
__global__ __launch_bounds__(256) void k_dequant(const int* __restrict__ idx,
                                                 const float* __restrict__ scale,
                                                 u16* __restrict__ out, int kshift) {
  size_t t = (size_t)blockIdx.x * 256 + threadIdx.x;
  size_t e = t * 8;
  int k = (int)(e & ((1u << kshift) - 1));
  size_t n = e >> kshift;
  float s = scale[(n << (kshift - 6)) + (k >> 6)];
  int4 i0 = *(const int4*)(idx + e);
  int4 i1 = *(const int4*)(idx + e + 4);
  uint4 o;
  o.x = (u32)f2bf(c_nf4[i0.x] * s) | ((u32)f2bf(c_nf4[i0.y] * s) << 16);
  o.y = (u32)f2bf(c_nf4[i0.z] * s) | ((u32)f2bf(c_nf4[i0.w] * s) << 16);
  o.z = (u32)f2bf(c_nf4[i1.x] * s) | ((u32)f2bf(c_nf4[i1.y] * s) << 16);
  o.w = (u32)f2bf(c_nf4[i1.z] * s) | ((u32)f2bf(c_nf4[i1.w] * s) << 16);
  *(uint4*)(out + e) = o;
}

// ---------------- f32 -> bf16 convert (emb) ----------------
__global__ __launch_bounds__(256) void k_f2b(const float* __restrict__ src,
                                             u16* __restrict__ dst) {
  size_t e = ((size_t)blockIdx.x * 256 + threadIdx.x) * 8;
  float4 f0 = *(const float4*)(src + e);
  float4 f1 = *(const float4*)(src + e + 4);
  uint4 o;
  o.x = (u32)f2bf(f0.x) | ((u32)f2bf(f0.y) << 16);
  o.y = (u32)f2bf(f0.z) | ((u32)f2bf(f0.w) << 16);
  o.z = (u32)f2bf(f1.x) | ((u32)f2bf(f1.y) << 16);
  o.w = (u32)f2bf(f1.z) | ((u32)f2bf(f1.w) << 16);
  *(uint4*)(dst + e) = o;
}

// ---------------- transpose-convert: emb f32 [V,D] -> embT bf16 [D,V] ----------
__global__ __launch_bounds__(256) void k_transpose(const float* __restrict__ src,
                                                   u16* __restrict__ dst) {
  __shared__ u16 tile[64][65];
  int v0 = blockIdx.x * 64, d0 = blockIdx.y * 64;
  int tid = threadIdx.x;
  int rr = tid >> 4, cc = (tid & 15) * 4;
#pragma unroll
  for (int j = 0; j < 4; ++j) {
    int r = j * 16 + rr;
    float4 f = *(const float4*)(src + (size_t)(v0 + r) * D_ + d0 + cc);
    tile[r][cc + 0] = f2bf(f.x); tile[r][cc + 1] = f2bf(f.y);
    tile[r][cc + 2] = f2bf(f.z); tile[r][cc + 3] = f2bf(f.w);
  }
  __syncthreads();
#pragma unroll
  for (int j = 0; j < 4; ++j) {
    int r = j * 16 + rr;
    ushort4 w;
    w.x = tile[cc + 0][r]; w.y = tile[cc + 1][r];
    w.z = tile[cc + 2][r]; w.w = tile[cc + 3][r];
    *(ushort4*)(dst + (size_t)(d0 + r) * V_ + v0 + cc) = w;
  }
}

// ======== 256x256 MFMA GEMM v3: 4 waves x (128x128)/wave, BK=64, ========
// single-buffered 64 KiB LDS -> 2 blocks/CU; 2 barriers per K-tile.
// Per tile: {32 ds_read_b128; lgkmcnt(0); barrier; stage(t+1) 16 gload_lds;
//            setprio 128xMFMA; vmcnt(0); barrier}. Cross-block overlap hides
// the drains (m97 mechanism); 32 reads feed 128 MFMA (2x reuse vs r7).
enum { OUT_F32 = 0, OUT_F32_ACC = 1, OUT_BF16 = 2 };

template<int OUTMODE>
__global__ __launch_bounds__(256, 2) void k_gemm256(const u16* __restrict__ A, int lda,
                                                    const u16* __restrict__ B, int ldb,
                                                    void* __restrict__ Cv, int ldc,
                                                    int Kc, size_t zstride) {
  __shared__ u16 As[256 * 64];
  __shared__ u16 Bs[256 * 64];
  const int tid = threadIdx.x;
  const int lane = tid & 63, w = tid >> 6;
  const int wr = w >> 1, wc = w & 1;
  const int g = lane >> 4, l15 = lane & 15, sl7 = lane & 7;

  // bijective XCD swizzle, N-major within chunk (gx*gy % 8 == 0 for all call sites)
  const int gx = gridDim.x, gy = gridDim.y;
  const int cpx = (gx * gy) >> 3;
  int d = blockIdx.y * gx + blockIdx.x;
  int swz = (d & 7) * cpx + (d >> 3);
  const int m0 = (swz % gy) * 256;
  const int n0 = (swz / gy) * 256;

  A += (size_t)blockIdx.z * Kc;
  B += (size_t)blockIdx.z * Kc;
  float* Cf = (float*)Cv + (size_t)blockIdx.z * zstride;

  const int NT = Kc >> 6;
  const int srow = w * 8 + (lane >> 3);       // staged row within 32-row round
  const int sch  = (lane & 7) ^ (lane >> 3);  // pre-swizzled source chunk

  auto stageA = [&](int tile) {
    const u16* src = A + (size_t)(m0 + srow) * lda + tile * 64 + sch * 8;
    u16* dst = &As[(w * 8) * 64];
#pragma unroll
    for (int r = 0; r < 8; ++r)
      __builtin_amdgcn_global_load_lds(
          (const __attribute__((address_space(1))) void*)(src + (size_t)(r * 32) * lda),
          (__attribute__((address_space(3))) void*)(dst + r * 32 * 64), 16, 0, 0);
  };
  auto stageB = [&](int tile) {
    const u16* src = B + (size_t)(n0 + srow) * ldb + tile * 64 + sch * 8;
    u16* dst = &Bs[(w * 8) * 64];
#pragma unroll
    for (int r = 0; r < 8; ++r)
      __builtin_amdgcn_global_load_lds(
          (const __attribute__((address_space(1))) void*)(src + (size_t)(r * 32) * ldb),
          (__attribute__((address_space(3))) void*)(dst + r * 32 * 64), 16, 0, 0);
  };

  f32x4 acc[8][8] = {};

  stageA(0); stageB(0);
  asm volatile("s_waitcnt vmcnt(0)" ::: "memory");
  __builtin_amdgcn_s_barrier();

  for (int t = 0; t < NT; ++t) {
    bf16x8 af[8][2], bfv[8][2];
#pragma unroll
    for (int m = 0; m < 8; ++m)
#pragma unroll
      for (int kh = 0; kh < 2; ++kh) {
        int hr = wr * 128 + m * 16 + l15;
        af[m][kh] = *(const bf16x8*)&As[hr * 64 + ((((kh << 2) | g) ^ sl7) << 3)];
        int br = wc * 128 + m * 16 + l15;
        bfv[m][kh] = *(const bf16x8*)&Bs[br * 64 + ((((kh << 2) | g) ^ sl7) << 3)];
      }
    asm volatile("s_waitcnt lgkmcnt(0)" ::: "memory");
    __builtin_amdgcn_s_barrier();        // all waves' reads landed -> safe to overwrite
    if (t + 1 < NT) { stageA(t + 1); stageB(t + 1); }
    __builtin_amdgcn_s_setprio(1);
#pragma unroll
    for (int m = 0; m < 8; ++m)
#pragma unroll
      for (int n = 0; n < 8; ++n)
#pragma unroll
        for (int kh = 0; kh < 2; ++kh)
          acc[m][n] = MFMA16(af[m][kh], bfv[n][kh], acc[m][n]);
    __builtin_amdgcn_s_setprio(0);
    if (t + 1 < NT) {
      asm volatile("s_waitcnt vmcnt(0)" ::: "memory");   // t+1 arrived (hidden under MFMA)
      __builtin_amdgcn_s_barrier();
    }
  }

  const int er = g * 4;
#pragma unroll
  for (int i = 0; i < 8; ++i)
#pragma unroll
    for (int j = 0; j < 8; ++j)
#pragma unroll
      for (int r = 0; r < 4; ++r) {
        int row = m0 + wr * 128 + i * 16 + er + r;
        int col = n0 + wc * 128 + j * 16 + l15;
        if (OUTMODE == OUT_BF16) {
          ((u16*)Cv)[(size_t)row * ldc + col] = f2bf(acc[i][j][r]);
        } else if (OUTMODE == OUT_F32_ACC) {
          Cf[(size_t)row * ldc + col] += acc[i][j][r];
        } else {
          Cf[(size_t)row * ldc + col] = acc[i][j][r];
        }
      }
}

// ---------------- split-K reduce ----------------
__global__ __launch_bounds__(256) void k_red(const float* __restrict__ P,
                                             float* __restrict__ dst, int accmode) {
  size_t i = ((size_t)blockIdx.x * 256 + threadIdx.x) * 4;
  const size_t n = (size_t)4 * 1024 * 1024;
  float4 a = *(const float4*)(P + i);
  float4 b = *(const float4*)(P + n + i);
  float4 c = *(const float4*)(P + 2 * n + i);
  float4 d = *(const float4*)(P + 3 * n + i);
  float4 r;
  r.x = (a.x + b.x) + (c.x + d.x);
  r.y = (a.y + b.y) + (c.y + d.y);
  r.z = (a.z + b.z) + (c.z + d.z);
  r.w = (a.w + b.w) + (c.w + d.w);
  if (accmode) {
    float4 o = *(const float4*)(dst + i);
    r.x += o.x; r.y += o.y; r.z += o.z; r.w += o.w;
  }
  *(float4*)(dst + i) = r;
}

// ---------------- LoRA ----------------
__global__ __launch_bounds__(256) void k_lora_down(const u16* __restrict__ X,
                                                   const float* __restrict__ A,
                                                   float* __restrict__ T, int nproj) {
  int s = blockIdx.x;
  int lane = threadIdx.x & 63, wv = threadIdx.x >> 6;
  const u16* x = X + (size_t)s * D_;
  for (int p = wv; p < nproj * R_; p += 4) {
    const float* a = A + (size_t)p * D_;
    float sum = 0.f;
    for (int d = lane; d < D_; d += 64) sum += bf2f(x[d]) * a[d];
#pragma unroll
    for (int m = 1; m < 64; m <<= 1) sum += __shfl_xor(sum, m, 64);
    if (lane == 0) T[(size_t)s * (nproj * R_) + p] = sum;
  }
}

__global__ __launch_bounds__(256) void k_lora_up(float* __restrict__ Y, int ystride,
                                                 const float* __restrict__ T,
                                                 const float* __restrict__ Bm, int nproj) {
  int t = blockIdx.x * 256 + threadIdx.x;
  int d = t & (D_ - 1);
  int si = t >> 11;
  int i = si % nproj;
  int s = si / nproj;
  const float* tp = T + ((size_t)s * nproj + i) * R_;
  const float* bp = Bm + ((size_t)i * D_ + d) * R_;
  float acc = 0.f;
#pragma unroll
  for (int r = 0; r < R_; r++) acc += tp[r] * bp[r];
  Y[(size_t)s * ystride + (size_t)i * D_ + d] += 2.0f * acc;
}

// ---- LoRA-up for qkv, bf16 in-place: qkvb += 2 * T . B ----
__global__ __launch_bounds__(256) void k_lora_up_qkv(u16* __restrict__ qkvb,
                                                     const float* __restrict__ T,
                                                     const float* __restrict__ Bm) {
  size_t t = ((size_t)blockIdx.x * 256 + threadIdx.x) * 8;
  int c = (int)(t % 6144);
  int s = (int)(t / 6144);
  int i = c >> 11, dd = c & 2047;
  const float* tp = T + ((size_t)s * 3 + i) * R_;
  float tr[8];
#pragma unroll
  for (int r = 0; r < R_; ++r) tr[r] = tp[r];
  uint4 q = *(const uint4*)(qkvb + t);
  u16 qs[8] = {(u16)(q.x & 0xffff), (u16)(q.x >> 16), (u16)(q.y & 0xffff), (u16)(q.y >> 16),
               (u16)(q.z & 0xffff), (u16)(q.z >> 16), (u16)(q.w & 0xffff), (u16)(q.w >> 16)};
  u16 os[8];
#pragma unroll
  for (int j = 0; j < 8; ++j) {
    const float* bp = Bm + ((size_t)i * D_ + dd + j) * R_;
    float a = 0.f;
#pragma unroll
    for (int r = 0; r < R_; ++r) a += tr[r] * bp[r];
    os[j] = f2bf(bf2f(qs[j]) + 2.0f * a);
  }
  uint4 o;
  o.x = (u32)os[0] | ((u32)os[1] << 16);
  o.y = (u32)os[2] | ((u32)os[3] << 16);
  o.z = (u32)os[4] | ((u32)os[5] << 16);
  o.w = (u32)os[6] | ((u32)os[7] << 16);
  *(uint4*)(qkvb + t) = o;
}

// ---- per-head V transpose: Vt[h][dh][s] = qkvb[s][4096 + h*128 + dh] ----
__global__ __launch_bounds__(256) void k_vtrans(const u16* __restrict__ qkvb,
                                                u16* __restrict__ Vt) {
  __shared__ u16 t[64][136];
  int s0 = blockIdx.x * 64, hh = blockIdx.y;
  int tid = threadIdx.x;
#pragma unroll
  for (int it = 0; it < 4; ++it) {
    int e = it * 2048 + tid * 8;
    int sr = e >> 7, sc = e & 127;
    *(uint4*)&t[sr][sc] =
        *(const uint4*)(qkvb + (size_t)(s0 + sr) * 6144 + 4096 + hh * 128 + sc);
  }
  __syncthreads();
#pragma unroll
  for (int it = 0; it < 4; ++it) {
    int q = it * 256 + tid;
    int dh = q >> 3, sc = (q & 7) * 8;
    u16 e0 = t[sc + 0][dh], e1 = t[sc + 1][dh], e2 = t[sc + 2][dh], e3 = t[sc + 3][dh];
    u16 e4 = t[sc + 4][dh], e5 = t[sc + 5][dh], e6 = t[sc + 6][dh], e7 = t[sc + 7][dh];
    uint4 o;
    o.x = (u32)e0 | ((u32)e1 << 16);
    o.y = (u32)e2 | ((u32)e3 << 16);
    o.z = (u32)e4 | ((u32)e5 << 16);
    o.w = (u32)e6 | ((u32)e7 << 16);
    *(uint4*)(Vt + ((size_t)hh * DH_ + dh) * S_ + s0 + sc) = o;
  }
}

// ======== MFMA flash attention v2 (unchanged) ========
__global__ __launch_bounds__(256) void k_attn2(const u16* __restrict__ qkvb,
                                               const u16* __restrict__ Vt,
                                               u16* __restrict__ out) {
  __shared__ u16 Ks[2][64 * 128];
  __shared__ u16 VTs[2][128 * 64];
  __shared__ u16 PT[4][64 * 16];
  const int tid = threadIdx.x;
  const int lane = tid & 63, w = tid >> 6;
  const int g = lane >> 4, l4 = lane & 15;
  const int p = blockIdx.x;
  const int hh = blockIdx.y;
  const int ld = 6144;
  const float rs = 0.08838834764831845f;
  const int qa0 = p * 64, qb0 = (31 - p) * 64;
  const int ntb = 32 - p;
  char* pt_w = (char*)&PT[w][0];

  const int qga = qa0 + w * 16 + l4;
  const int qgb = qb0 + w * 16 + l4;

  bf16x8 qfa[4], qfb[4];
#pragma unroll
  for (int kh = 0; kh < 4; ++kh) {
    qfa[kh] = *(const bf16x8*)(qkvb + (size_t)qga * ld + hh * DH_ + kh * 32 + g * 8);
    qfb[kh] = *(const bf16x8*)(qkvb + (size_t)qgb * ld + hh * DH_ + kh * 32 + g * 8);
  }

  float ma = -3.0e38f, la = 0.f, mb = -3.0e38f, lb = 0.f;
  f32x4 acc_a[8] = {}, acc_b[8] = {};
  bf16x8 pba[2], pbb[2];

  auto stage = [&](int buf, int kt) {
    const int kv0 = kt * 64;
#pragma unroll
    for (int i = 0; i < 4; ++i) {
      int rl = (w * 4 + i) * 4 + (lane >> 4);
      int cs = (lane & 15) ^ ((rl & 7) ^ (((rl >> 3) & 3) << 1));
      __builtin_amdgcn_global_load_lds(
          (const __attribute__((address_space(1))) void*)(
              qkvb + (size_t)(kv0 + rl) * ld + 2048 + hh * DH_ + cs * 8),
          (__attribute__((address_space(3))) void*)(&Ks[buf][(w * 4 + i) * 512]), 16, 0, 0);
    }
#pragma unroll
    for (int i = 0; i < 4; ++i) {
      int dh = (w * 4 + i) * 8 + (lane >> 3);
      int cs = (lane & 7) ^ (dh & 7);
      __builtin_amdgcn_global_load_lds(
          (const __attribute__((address_space(1))) void*)(
              Vt + ((size_t)hh * DH_ + dh) * S_ + kv0 + cs * 8),
          (__attribute__((address_space(3))) void*)(&VTs[buf][(w * 4 + i) * 512]), 16, 0, 0);
    }
  };

  auto softpb = [&](f32x4* sv, float& m, float& l, f32x4* acc, int qg, bool diag,
                    int kv0, bf16x8* pb) {
    float pv[16];
    float tmax = -3.0e38f;
#pragma unroll
    for (int kb = 0; kb < 4; ++kb)
#pragma unroll
      for (int r = 0; r < 4; ++r) {
        float s = sv[kb][r] * rs;
        if (diag) {
          int kglob = kv0 + kb * 16 + g * 4 + r;
          if (kglob > qg) s = -1.0e30f;
        }
        pv[kb * 4 + r] = s;
        tmax = fmaxf(tmax, s);
      }
    tmax = fmaxf(tmax, __shfl_xor(tmax, 16, 64));
    tmax = fmaxf(tmax, __shfl_xor(tmax, 32, 64));
    float mn = fmaxf(m, tmax);
    float corr = __expf(m - mn);
    m = mn;
    float ps = 0.f;
#pragma unroll
    for (int i = 0; i < 16; ++i) { pv[i] = __expf(pv[i] - mn); ps += pv[i]; }
    ps += __shfl_xor(ps, 16, 64);
    ps += __shfl_xor(ps, 32, 64);
    l = l * corr + ps;
#pragma unroll
    for (int f = 0; f < 8; ++f) {
      acc[f][0] *= corr; acc[f][1] *= corr; acc[f][2] *= corr; acc[f][3] *= corr;
    }
#pragma unroll
    for (int kb = 0; kb < 4; ++kb)
#pragma unroll
      for (int r = 0; r < 4; ++r) {
        int key = kb * 16 + g * 4 + r;
        int byte = (key * 32 + l4 * 2) ^ (((key >> 3) & 3) << 5);
        *(u16*)(pt_w + byte) = f2bf(pv[kb * 4 + r]);
      }
#pragma unroll
    for (int ks = 0; ks < 2; ++ks) {
      union { bf16x8 v; u16 s[8]; } ub;
#pragma unroll
      for (int j = 0; j < 8; ++j) {
        int key = ks * 32 + g * 8 + j;
        int byte = (key * 32 + l4 * 2) ^ (((key >> 3) & 3) << 5);
        ub.s[j] = *(const u16*)(pt_w + byte);
      }
      pb[ks] = ub.v;
    }
  };

  stage(0, 0);
  asm volatile("s_waitcnt vmcnt(0)" ::: "memory");
  __syncthreads();

  for (int kt = 0; kt < ntb; ++kt) {
    const int kv0 = kt * 64;
    const int buf = kt & 1;
    if (kt + 1 < ntb) stage(buf ^ 1, kt + 1);

    const char* kb_base = (const char*)&Ks[buf][0];
    const char* vb_base = (const char*)&VTs[buf][0];
    const bool doa = (kt <= p);

    f32x4 sa[4] = {}, sb[4] = {};
#pragma unroll
    for (int kb = 0; kb < 4; ++kb) {
#pragma unroll
      for (int kh = 0; kh < 4; ++kh) {
        int key = kb * 16 + l4;
        int ch = (kh * 4 + g) ^ ((key & 7) ^ (((key >> 3) & 3) << 1));
        bf16x8 af = *(const bf16x8*)(kb_base + key * 256 + ch * 16);
        if (doa) sa[kb] = MFMA16(af, qfa[kh], sa[kb]);
        sb[kb] = MFMA16(af, qfb[kh], sb[kb]);
      }
    }

    if (doa) softpb(sa, ma, la, acc_a, qga, kt == p, kv0, pba);
    softpb(sb, mb, lb, acc_b, qgb, kt == ntb - 1, kv0, pbb);

#pragma unroll
    for (int f = 0; f < 8; ++f) {
#pragma unroll
      for (int ks = 0; ks < 2; ++ks) {
        int dh = f * 16 + l4;
        int ch = (ks * 4 + g) ^ (dh & 7);
        bf16x8 va = *(const bf16x8*)(vb_base + dh * 128 + ch * 16);
        if (doa) acc_a[f] = MFMA16(va, pba[ks], acc_a[f]);
        acc_b[f] = MFMA16(va, pbb[ks], acc_b[f]);
      }
    }

    if (kt + 1 < ntb) {
      asm volatile("s_waitcnt vmcnt(0)" ::: "memory");
      __syncthreads();
    }
  }

  float inva = 1.f / la, invb = 1.f / lb;
  u16* opa = out + (size_t)qga * D_ + hh * DH_;
  u16* opb = out + (size_t)qgb * D_ + hh * DH_;
#pragma unroll
  for (int f = 0; f < 8; ++f)
#pragma unroll
    for (int r = 0; r < 4; ++r) {
      opa[f * 16 + g * 4 + r] = f2bf(acc_a[f][r] * inva);
      opb[f * 16 + g * 4 + r] = f2bf(acc_b[f][r] * invb);
    }
}

// ---------------- silu(gate)*up ----------------
__global__ __launch_bounds__(256) void k_silumul(u16* __restrict__ gu) {
  size_t i = ((size_t)blockIdx.x * 256 + threadIdx.x) * 4;
  int s = (int)(i >> 13);
  int f = (int)(i & 8191);
  u16* gp = gu + (size_t)s * (2 * DFF_) + f;
  ushort4 gt = *(ushort4*)gp;
  ushort4 up = *(ushort4*)(gp + DFF_);
  float g0 = bf2f(gt.x), g1 = bf2f(gt.y), g2 = bf2f(gt.z), g3 = bf2f(gt.w);
  float u0 = bf2f(up.x), u1 = bf2f(up.y), u2 = bf2f(up.z), u3 = bf2f(up.w);
  ushort4 o;
  o.x = f2bf(g0 / (1.f + __expf(-g0)) * u0);
  o.y = f2bf(g1 / (1.f + __expf(-g1)) * u1);
  o.z = f2bf(g2 / (1.f + __expf(-g2)) * u2);
  o.w = f2bf(g3 / (1.f + __expf(-g3)) * u3);
  *(ushort4*)gp = o;
}

// ---------------- gumbel softmax -> g (bf16) ----------------
__global__ __launch_bounds__(256) void k_gumbel(const float* __restrict__ logits,
                                                const float* __restrict__ u,
                                                u16* __restrict__ g) {
  int s = blockIdx.x;
  const float* lp = logits + (size_t)s * V_;
  const float* up = u + (size_t)s * V_;
  float m = -3.0e38f, l = 0.f;
  for (int v = threadIdx.x; v < V_; v += 256) {
    float z = lp[v] - __logf(-__logf(up[v] + 1e-10f) + 1e-10f);
    float mn = fmaxf(m, z);
    l = l * __expf(m - mn) + __expf(z - mn);
    m = mn;
  }
#pragma unroll
  for (int msk = 1; msk < 64; msk <<= 1) {
    float m2 = __shfl_xor(m, msk, 64), l2 = __shfl_xor(l, msk, 64);
    float mn = fmaxf(m, m2);
    l = l * __expf(m - mn) + l2 * __expf(m2 - mn);
    m = mn;
  }
  __shared__ float shm[4], shl[4];
  if ((threadIdx.x & 63) == 0) { shm[threadIdx.x >> 6] = m; shl[threadIdx.x >> 6] = l; }
  __syncthreads();
  float M = fmaxf(fmaxf(shm[0], shm[1]), fmaxf(shm[2], shm[3]));
  float L = shl[0] * __expf(shm[0] - M) + shl[1] * __expf(shm[1] - M) +
            shl[2] * __expf(shm[2] - M) + shl[3] * __expf(shm[3] - M);
  float inv = 1.f / L;
  u16* gp = g + (size_t)s * V_;
  for (int v = threadIdx.x; v < V_; v += 256) {
    float z = lp[v] - __logf(-__logf(up[v] + 1e-10f) + 1e-10f);
    gp[v] = f2bf(__expf(z - M) * inv);
  }
}

extern "C" void kernel_launch(void* const* d_in, const int* in_sizes, int n_in,
                              void* d_out, int out_size, void* d_ws, size_t ws_size,
                              hipStream_t stream) {
  const int*   ids        = (const int*)d_in[0];
  const float* u          = (const float*)d_in[1];
  const float* emb        = (const float*)d_in[2];
  const float* attn_scale = (const float*)d_in[3];
  const float* gu_scale   = (const float*)d_in[4];
  const float* dn_scale   = (const float*)d_in[5];
  const float* lora_A     = (const float*)d_in[6];
  const float* lora_B     = (const float*)d_in[7];
  const float* norm_w     = (const float*)d_in[8];
  const float* fnorm_w    = (const float*)d_in[9];
  const int*   attn_idx   = (const int*)d_in[10];
  const int*   gu_idx     = (const int*)d_in[11];
  const int*   dn_idx     = (const int*)d_in[12];

  float* out_se = (float*)d_out;
  float* out_lg = (float*)d_out + (size_t)S_ * D_;

  char* W = (char*)d_ws;
  float* h    = (float*)(W);                          // 16 MiB
  u16*   xb   = (u16*)(W + ((size_t)16 << 20));       // 8 MiB
  u16*   qkvb = (u16*)(W + ((size_t)72 << 20));       // 24 MiB
  u16*   Vtb  = (u16*)(W + ((size_t)96 << 20));       // 8 MiB
  u16*   ob   = (u16*)(W + ((size_t)104 << 20));      // 8 MiB
  u16*   gub  = (u16*)(W + ((size_t)112 << 20));      // 64 MiB
  u16*   wdq  = (u16*)(W + ((size_t)176 << 20));      // 64 MiB
  float* Tl   = (float*)(W + ((size_t)240 << 20));    // 192 KiB
  u16*   embb = (u16*)(W);                            // 125 MiB (head)
  u16*   gsm  = (u16*)(W + ((size_t)125 << 20));      // 125 MiB (head)
  u16*   embT = (u16*)(W);                            // 125 MiB (replaces embb)
  u16*   xbh  = (u16*)d_out;                          // final-norm out, parked in out_se
  float* Pk   = (float*)(W + ((size_t)250 << 20));    // 64 MiB split-K partials
  const bool big = ws_size >= ((size_t)314 << 20);
  const size_t ZS = (size_t)4 * 1024 * 1024;

  dim3 b256(256);

  k_gather<<<dim3(S_ * D_ / 256), b256, 0, stream>>>(ids, emb, h);

  for (int l = 0; l < L_; ++l) {
    const int*   aidx = attn_idx + (size_t)l * 4 * D_ * D_;
    const float* ascl = attn_scale + (size_t)l * 4 * D_ * (D_ / 64);
    const float* lA   = lora_A + (size_t)l * 4 * R_ * D_;
    const float* lB   = lora_B + (size_t)l * 4 * D_ * R_;

    // ---- attention ----
    k_rmsnorm<<<dim3(S_), b256, 0, stream>>>(h, norm_w + (size_t)l * 2 * D_, xb);
    k_dequant<<<dim3(4 * D_ * D_ / 8 / 256), b256, 0, stream>>>(aidx, ascl, wdq, 11);
    k_gemm256<OUT_BF16><<<dim3(3 * D_ / 256, 8), b256, 0, stream>>>(
        xb, D_, wdq, D_, qkvb, 3 * D_, D_, 0);
    k_lora_down<<<dim3(S_), b256, 0, stream>>>(xb, lA, Tl, 3);
    k_lora_up_qkv<<<dim3(S_ * 3 * D_ / 8 / 256), b256, 0, stream>>>(qkvb, Tl, lB);
    k_vtrans<<<dim3(S_ / 64, H_), b256, 0, stream>>>(qkvb, Vtb);
    k_attn2<<<dim3(16, H_), b256, 0, stream>>>(qkvb, Vtb, ob);
    k_gemm256<OUT_F32_ACC><<<dim3(D_ / 256, 8), b256, 0, stream>>>(
        ob, D_, wdq + (size_t)3 * D_ * D_, D_, h, D_, D_, 0);
    k_lora_down<<<dim3(S_), b256, 0, stream>>>(ob, lA + (size_t)3 * R_ * D_, Tl, 1);
    k_lora_up<<<dim3(S_ * D_ / 256), b256, 0, stream>>>(h, D_, Tl, lB + (size_t)3 * D_ * R_, 1);

    // ---- ffn ----
    k_rmsnorm<<<dim3(S_), b256, 0, stream>>>(h, norm_w + (size_t)l * 2 * D_ + D_, xb);
    k_dequant<<<dim3(2 * DFF_ * D_ / 8 / 256), b256, 0, stream>>>(
        gu_idx + (size_t)l * 2 * DFF_ * D_, gu_scale + (size_t)l * 2 * DFF_ * (D_ / 64), wdq, 11);
    k_gemm256<OUT_BF16><<<dim3(2 * DFF_ / 256, 8), b256, 0, stream>>>(
        xb, D_, wdq, D_, gub, 2 * DFF_, D_, 0);
    k_silumul<<<dim3(S_ * DFF_ / 4 / 256), b256, 0, stream>>>(gub);
    k_dequant<<<dim3(D_ * DFF_ / 8 / 256), b256, 0, stream>>>(
        dn_idx + (size_t)l * D_ * DFF_, dn_scale + (size_t)l * D_ * (DFF_ / 64), wdq, 13);
    if (big) {
      k_gemm256<OUT_F32><<<dim3(D_ / 256, 8, 4), b256, 0, stream>>>(
          gub, 2 * DFF_, wdq, DFF_, Pk, D_, DFF_ / 4, ZS);
      k_red<<<dim3(4096), b256, 0, stream>>>(Pk, h, 1);
    } else {
      k_gemm256<OUT_F32_ACC><<<dim3(D_ / 256, 8), b256, 0, stream>>>(
          gub, 2 * DFF_, wdq, DFF_, h, D_, DFF_, 0);
    }
  }

  // ---- head ----
  k_rmsnorm<<<dim3(S_), b256, 0, stream>>>(h, fnorm_w, xbh);
  k_f2b<<<dim3(V_ * D_ / 8 / 256), b256, 0, stream>>>(emb, embb);
  k_gemm256<OUT_F32><<<dim3(V_ / 256, 8), b256, 0, stream>>>(
      xbh, D_, embb, D_, out_lg, V_, D_, 0);
  k_gumbel<<<dim3(S_), b256, 0, stream>>>(out_lg, u, gsm);
  k_transpose<<<dim3(V_ / 64, D_ / 64), b256, 0, stream>>>(emb, embT);
  if (big) {
    k_gemm256<OUT_F32><<<dim3(D_ / 256, 8, 4), b256, 0, stream>>>(
        gsm, V_, embT, V_, Pk, D_, V_ / 4, ZS);
    k_red<<<dim3(4096), b256, 0, stream>>>(Pk, out_se, 0);
  } else {
    k_gemm256<OUT_F32><<<dim3(D_ / 256, 8), b256, 0, stream>>>(
        gsm, V_, embT, V_, out_se, D_, V_, 0);
  }
}

// Round 9
// 2444.170 us; speedup vs baseline: 7.0965x; 7.0965x over previous
//
#include <hip/hip_runtime.h>
#include <hip/hip_bf16.h>

typedef unsigned short u16;
typedef unsigned int u32;
typedef __bf16 bf16t;
typedef bf16t bf16x8 __attribute__((ext_vector_type(8)));
typedef float f32x4 __attribute__((ext_vector_type(4)));

constexpr int S_   = 2048;
constexpr int D_   = 2048;
constexpr int H_   = 16;
constexpr int DH_  = 128;
constexpr int L_   = 2;
constexpr int DFF_ = 8192;
constexpr int V_   = 32000;
constexpr int R_   = 8;

#define MFMA16(a, b, c) __builtin_amdgcn_mfma_f32_16x16x32_bf16(a, b, c, 0, 0, 0)

__constant__ float c_nf4[16] = {
  -1.0f, -0.6961928009986877f, -0.5250730514526367f, -0.39491748809814453f,
  -0.28444138169288635f, -0.18477343022823334f, -0.09105003625154495f, 0.0f,
  0.07958029955625534f, 0.16093020141124725f, 0.24611230194568634f,
  0.33791524171829224f, 0.44070982933044434f, 0.5626170039176941f,
  0.7229568362236023f, 1.0f };

__device__ __forceinline__ u16 f2bf(float f) {
  union { float f; u32 u; } v; v.f = f;
  u32 r = v.u + 0x7fffu + ((v.u >> 16) & 1u);
  return (u16)(r >> 16);
}
__device__ __forceinline__ float bf2f(u16 h) {
  union { u32 u; float f; } v; v.u = ((u32)h) << 16; return v.f;
}

// ---------------- embedding gather ----------------
__global__ __launch_bounds__(256) void k_gather(const int* __restrict__ ids,
                                                const float* __restrict__ emb,
                                                float* __restrict__ h) {
  int t = blockIdx.x * 256 + threadIdx.x;
  int s = t >> 11;
  int d = t & 2047;
  h[t] = emb[(size_t)ids[s] * D_ + d];
}

// ---------------- rmsnorm f32 -> bf16 ----------------
__global__ __launch_bounds__(256) void k_rmsnorm(const float* __restrict__ in,
                                                 const float* __restrict__ w,
                                                 u16* __restrict__ out) {
  int s = blockIdx.x;
  const float* x = in + (size_t)s * D_;
  float ss = 0.f;
  for (int d = threadIdx.x; d < D_; d += 256) { float v = x[d]; ss += v * v; }
#pragma unroll
  for (int m = 1; m < 64; m <<= 1) ss += __shfl_xor(ss, m, 64);
  __shared__ float sh[4];
  if ((threadIdx.x & 63) == 0) sh[threadIdx.x >> 6] = ss;
  __syncthreads();
  ss = sh[0] + sh[1] + sh[2] + sh[3];
  float sc = rsqrtf(ss * (1.0f / D_) + 1e-6f);
  u16* o = out + (size_t)s * D_;
  for (int d = threadIdx.x; d < D_; d += 256) o[d] = f2bf(x[d] * sc * w[d]);
}

// ---------------- NF4 dequant ----------------
__global__ __launch_bounds__(256) void k_dequant(const int* __restrict__ idx,
                                                 const float* __restrict__ scale,
                                                 u16* __restrict__ out, int kshift) {
  size_t t = (size_t)blockIdx.x * 256 + threadIdx.x;
  size_t e = t * 8;
  int k = (int)(e & ((1u << kshift) - 1));
  size_t n = e >> kshift;
  float s = scale[(n << (kshift - 6)) + (k >> 6)];
  int4 i0 = *(const int4*)(idx + e);
  int4 i1 = *(const int4*)(idx + e + 4);
  uint4 o;
  o.x = (u32)f2bf(c_nf4[i0.x] * s) | ((u32)f2bf(c_nf4[i0.y] * s) << 16);
  o.y = (u32)f2bf(c_nf4[i0.z] * s) | ((u32)f2bf(c_nf4[i0.w] * s) << 16);
  o.z = (u32)f2bf(c_nf4[i1.x] * s) | ((u32)f2bf(c_nf4[i1.y] * s) << 16);
  o.w = (u32)f2bf(c_nf4[i1.z] * s) | ((u32)f2bf(c_nf4[i1.w] * s) << 16);
  *(uint4*)(out + e) = o;
}

// ---------------- f32 -> bf16 convert (emb) ----------------
__global__ __launch_bounds__(256) void k_f2b(const float* __restrict__ src,
                                             u16* __restrict__ dst) {
  size_t e = ((size_t)blockIdx.x * 256 + threadIdx.x) * 8;
  float4 f0 = *(const float4*)(src + e);
  float4 f1 = *(const float4*)(src + e + 4);
  uint4 o;
  o.x = (u32)f2bf(f0.x) | ((u32)f2bf(f0.y) << 16);
  o.y = (u32)f2bf(f0.z) | ((u32)f2bf(f0.w) << 16);
  o.z = (u32)f2bf(f1.x) | ((u32)f2bf(f1.y) << 16);
  o.w = (u32)f2bf(f1.z) | ((u32)f2bf(f1.w) << 16);
  *(uint4*)(dst + e) = o;
}

// ---------------- transpose-convert: emb f32 [V,D] -> embT bf16 [D,V] ----------
__global__ __launch_bounds__(256) void k_transpose(const float* __restrict__ src,
                                                   u16* __restrict__ dst) {
  __shared__ u16 tile[64][65];
  int v0 = blockIdx.x * 64, d0 = blockIdx.y * 64;
  int tid = threadIdx.x;
  int rr = tid >> 4, cc = (tid & 15) * 4;
#pragma unroll
  for (int j = 0; j < 4; ++j) {
    int r = j * 16 + rr;
    float4 f = *(const float4*)(src + (size_t)(v0 + r) * D_ + d0 + cc);
    tile[r][cc + 0] = f2bf(f.x); tile[r][cc + 1] = f2bf(f.y);
    tile[r][cc + 2] = f2bf(f.z); tile[r][cc + 3] = f2bf(f.w);
  }
  __syncthreads();
#pragma unroll
  for (int j = 0; j < 4; ++j) {
    int r = j * 16 + rr;
    ushort4 w;
    w.x = tile[cc + 0][r]; w.y = tile[cc + 1][r];
    w.z = tile[cc + 2][r]; w.w = tile[cc + 3][r];
    *(ushort4*)(dst + (size_t)(d0 + r) * V_ + v0 + cc) = w;
  }
}

// ======== 256x256 pipelined MFMA GEMM (round-6 version, known-good) ========
// 512 thr = 8 waves (2M x 4N), BK=64, LDS 128 KiB double-buffered.
// Tile t+2 staged at phases 3/4 of tile t; boundary vmcnt(8) counted.
enum { OUT_F32 = 0, OUT_F32_ACC = 1, OUT_BF16 = 2 };

template<int OUTMODE>
__global__ __launch_bounds__(512, 2) void k_gemm256(const u16* __restrict__ A, int lda,
                                                    const u16* __restrict__ B, int ldb,
                                                    void* __restrict__ Cv, int ldc,
                                                    int Kc, size_t zstride) {
  __shared__ u16 As[2][256][64];
  __shared__ u16 Bs[2][256][64];
  const int tid = threadIdx.x;
  const int lane = tid & 63, w = tid >> 6;
  const int wr = w >> 2, wc = w & 3;
  const int g = (lane >> 4), l15 = lane & 15, sl7 = lane & 7;

  // XCD swizzle, N-major within chunk
  const int gx = gridDim.x, gy = gridDim.y;
  const int cpx = (gx * gy) >> 3;
  int d = blockIdx.y * gx + blockIdx.x;
  int swz = (d & 7) * cpx + (d >> 3);
  const int m0 = (swz % gy) * 256;
  const int n0 = (swz / gy) * 256;

  A += (size_t)blockIdx.z * Kc;
  B += (size_t)blockIdx.z * Kc;
  float* Cf = (float*)Cv + (size_t)blockIdx.z * zstride;

  const int NT = Kc >> 6;
  const int srow = w * 8 + (lane >> 3);
  const int sch  = (lane & 7) ^ (lane >> 3);

  auto stageA = [&](int half, int tile) {
    const u16* src = A + (size_t)(m0 + half * 128 + srow) * lda + tile * 64 + sch * 8;
    u16* dst = &As[tile & 1][half * 128 + w * 8][0];
#pragma unroll
    for (int rnd = 0; rnd < 2; ++rnd)
      __builtin_amdgcn_global_load_lds(
          (const __attribute__((address_space(1))) void*)(src + (size_t)rnd * 64 * lda),
          (__attribute__((address_space(3))) void*)(dst + rnd * 64 * 64), 16, 0, 0);
  };
  auto stageB = [&](int half, int tile) {
    const u16* src = B + (size_t)(n0 + half * 128 + srow) * ldb + tile * 64 + sch * 8;
    u16* dst = &Bs[tile & 1][half * 128 + w * 8][0];
#pragma unroll
    for (int rnd = 0; rnd < 2; ++rnd)
      __builtin_amdgcn_global_load_lds(
          (const __attribute__((address_space(1))) void*)(src + (size_t)rnd * 64 * ldb),
          (__attribute__((address_space(3))) void*)(dst + rnd * 64 * 64), 16, 0, 0);
  };

  f32x4 acc[8][4] = {};
  bf16x8 areg[4][2], breg[2][2][2];

  stageB(0, 0); stageB(1, 0); stageA(0, 0); stageA(1, 0);
  if (NT > 1) {
    stageB(0, 1); stageB(1, 1); stageA(0, 1); stageA(1, 1);
    asm volatile("s_waitcnt vmcnt(8)" ::: "memory");
  } else {
    asm volatile("s_waitcnt vmcnt(0)" ::: "memory");
  }
  __builtin_amdgcn_s_barrier();

#define LOADA(QR)                                                                   \
  _Pragma("unroll") for (int m = 0; m < 4; ++m)                                     \
    _Pragma("unroll") for (int kh = 0; kh < 2; ++kh) {                              \
      int hr = wr * 128 + (QR) * 64 + m * 16 + l15;                                 \
      areg[m][kh] = *(const bf16x8*)(abase + hr * 64 + ((((kh << 2) | g) ^ sl7) << 3)); \
    }
#define LOADB(QC)                                                                   \
  _Pragma("unroll") for (int n = 0; n < 2; ++n)                                     \
    _Pragma("unroll") for (int kh = 0; kh < 2; ++kh) {                              \
      int br = wc * 64 + (QC) * 32 + n * 16 + l15;                                  \
      breg[QC][n][kh] = *(const bf16x8*)(bbase + br * 64 + ((((kh << 2) | g) ^ sl7) << 3)); \
    }
#define QPHASE(QR, QC)                                                              \
  __builtin_amdgcn_s_setprio(1);                                                    \
  _Pragma("unroll") for (int m = 0; m < 4; ++m)                                     \
    _Pragma("unroll") for (int n = 0; n < 2; ++n)                                   \
      _Pragma("unroll") for (int kh = 0; kh < 2; ++kh)                              \
        acc[(QR) * 4 + m][(QC) * 2 + n] = __builtin_amdgcn_mfma_f32_16x16x32_bf16(  \
            areg[m][kh], breg[QC][n][kh], acc[(QR) * 4 + m][(QC) * 2 + n], 0, 0, 0); \
  __builtin_amdgcn_s_setprio(0);

  for (int t = 0; t < NT; ++t) {
    const u16* abase = &As[t & 1][0][0];
    const u16* bbase = &Bs[t & 1][0][0];
    LOADA(0); LOADB(0);
    __builtin_amdgcn_s_barrier();
    asm volatile("s_waitcnt lgkmcnt(0)" ::: "memory");
    QPHASE(0, 0);
    __builtin_amdgcn_s_barrier();
    LOADB(1);
    __builtin_amdgcn_s_barrier();
    asm volatile("s_waitcnt lgkmcnt(0)" ::: "memory");
    QPHASE(0, 1);
    __builtin_amdgcn_s_barrier();
    LOADA(1);
    if (t + 2 < NT) { stageB(0, t + 2); stageB(1, t + 2); }
    __builtin_amdgcn_s_barrier();
    asm volatile("s_waitcnt lgkmcnt(0)" ::: "memory");
    QPHASE(1, 1);
    __builtin_amdgcn_s_barrier();
    if (t + 2 < NT) { stageA(0, t + 2); stageA(1, t + 2); }
    QPHASE(1, 0);
    if (t + 1 < NT) {
      if (t + 2 < NT) asm volatile("s_waitcnt vmcnt(8)" ::: "memory");
      else            asm volatile("s_waitcnt vmcnt(0)" ::: "memory");
    }
    __builtin_amdgcn_s_barrier();
  }
#undef LOADA
#undef LOADB
#undef QPHASE

  const int er = g * 4;
#pragma unroll
  for (int i = 0; i < 8; ++i)
#pragma unroll
    for (int j = 0; j < 4; ++j)
#pragma unroll
      for (int r = 0; r < 4; ++r) {
        int row = m0 + wr * 128 + i * 16 + er + r;
        int col = n0 + wc * 64 + j * 16 + l15;
        if (OUTMODE == OUT_BF16) {
          ((u16*)Cv)[(size_t)row * ldc + col] = f2bf(acc[i][j][r]);
        } else if (OUTMODE == OUT_F32_ACC) {
          Cf[(size_t)row * ldc + col] += acc[i][j][r];
        } else {
          Cf[(size_t)row * ldc + col] = acc[i][j][r];
        }
      }
}

// ---------------- split-K reduce ----------------
__global__ __launch_bounds__(256) void k_red(const float* __restrict__ P,
                                             float* __restrict__ dst, int accmode) {
  size_t i = ((size_t)blockIdx.x * 256 + threadIdx.x) * 4;
  const size_t n = (size_t)4 * 1024 * 1024;
  float4 a = *(const float4*)(P + i);
  float4 b = *(const float4*)(P + n + i);
  float4 c = *(const float4*)(P + 2 * n + i);
  float4 d = *(const float4*)(P + 3 * n + i);
  float4 r;
  r.x = (a.x + b.x) + (c.x + d.x);
  r.y = (a.y + b.y) + (c.y + d.y);
  r.z = (a.z + b.z) + (c.z + d.z);
  r.w = (a.w + b.w) + (c.w + d.w);
  if (accmode) {
    float4 o = *(const float4*)(dst + i);
    r.x += o.x; r.y += o.y; r.z += o.z; r.w += o.w;
  }
  *(float4*)(dst + i) = r;
}

// ---------------- LoRA ----------------
__global__ __launch_bounds__(256) void k_lora_down(const u16* __restrict__ X,
                                                   const float* __restrict__ A,
                                                   float* __restrict__ T, int nproj) {
  int s = blockIdx.x;
  int lane = threadIdx.x & 63, wv = threadIdx.x >> 6;
  const u16* x = X + (size_t)s * D_;
  for (int p = wv; p < nproj * R_; p += 4) {
    const float* a = A + (size_t)p * D_;
    float sum = 0.f;
    for (int d = lane; d < D_; d += 64) sum += bf2f(x[d]) * a[d];
#pragma unroll
    for (int m = 1; m < 64; m <<= 1) sum += __shfl_xor(sum, m, 64);
    if (lane == 0) T[(size_t)s * (nproj * R_) + p] = sum;
  }
}

__global__ __launch_bounds__(256) void k_lora_up(float* __restrict__ Y, int ystride,
                                                 const float* __restrict__ T,
                                                 const float* __restrict__ Bm, int nproj) {
  int t = blockIdx.x * 256 + threadIdx.x;
  int d = t & (D_ - 1);
  int si = t >> 11;
  int i = si % nproj;
  int s = si / nproj;
  const float* tp = T + ((size_t)s * nproj + i) * R_;
  const float* bp = Bm + ((size_t)i * D_ + d) * R_;
  float acc = 0.f;
#pragma unroll
  for (int r = 0; r < R_; r++) acc += tp[r] * bp[r];
  Y[(size_t)s * ystride + (size_t)i * D_ + d] += 2.0f * acc;
}

// ---- LoRA-up for qkv, bf16 in-place: qkvb += 2 * T . B ----
__global__ __launch_bounds__(256) void k_lora_up_qkv(u16* __restrict__ qkvb,
                                                     const float* __restrict__ T,
                                                     const float* __restrict__ Bm) {
  size_t t = ((size_t)blockIdx.x * 256 + threadIdx.x) * 8;
  int c = (int)(t % 6144);
  int s = (int)(t / 6144);
  int i = c >> 11, dd = c & 2047;
  const float* tp = T + ((size_t)s * 3 + i) * R_;
  float tr[8];
#pragma unroll
  for (int r = 0; r < R_; ++r) tr[r] = tp[r];
  uint4 q = *(const uint4*)(qkvb + t);
  u16 qs[8] = {(u16)(q.x & 0xffff), (u16)(q.x >> 16), (u16)(q.y & 0xffff), (u16)(q.y >> 16),
               (u16)(q.z & 0xffff), (u16)(q.z >> 16), (u16)(q.w & 0xffff), (u16)(q.w >> 16)};
  u16 os[8];
#pragma unroll
  for (int j = 0; j < 8; ++j) {
    const float* bp = Bm + ((size_t)i * D_ + dd + j) * R_;
    float a = 0.f;
#pragma unroll
    for (int r = 0; r < R_; ++r) a += tr[r] * bp[r];
    os[j] = f2bf(bf2f(qs[j]) + 2.0f * a);
  }
  uint4 o;
  o.x = (u32)os[0] | ((u32)os[1] << 16);
  o.y = (u32)os[2] | ((u32)os[3] << 16);
  o.z = (u32)os[4] | ((u32)os[5] << 16);
  o.w = (u32)os[6] | ((u32)os[7] << 16);
  *(uint4*)(qkvb + t) = o;
}

// ---- per-head V transpose: Vt[h][dh][s] = qkvb[s][4096 + h*128 + dh] ----
__global__ __launch_bounds__(256) void k_vtrans(const u16* __restrict__ qkvb,
                                                u16* __restrict__ Vt) {
  __shared__ u16 t[64][136];
  int s0 = blockIdx.x * 64, hh = blockIdx.y;
  int tid = threadIdx.x;
#pragma unroll
  for (int it = 0; it < 4; ++it) {
    int e = it * 2048 + tid * 8;
    int sr = e >> 7, sc = e & 127;
    *(uint4*)&t[sr][sc] =
        *(const uint4*)(qkvb + (size_t)(s0 + sr) * 6144 + 4096 + hh * 128 + sc);
  }
  __syncthreads();
#pragma unroll
  for (int it = 0; it < 4; ++it) {
    int q = it * 256 + tid;
    int dh = q >> 3, sc = (q & 7) * 8;
    u16 e0 = t[sc + 0][dh], e1 = t[sc + 1][dh], e2 = t[sc + 2][dh], e3 = t[sc + 3][dh];
    u16 e4 = t[sc + 4][dh], e5 = t[sc + 5][dh], e6 = t[sc + 6][dh], e7 = t[sc + 7][dh];
    uint4 o;
    o.x = (u32)e0 | ((u32)e1 << 16);
    o.y = (u32)e2 | ((u32)e3 << 16);
    o.z = (u32)e4 | ((u32)e5 << 16);
    o.w = (u32)e6 | ((u32)e7 << 16);
    *(uint4*)(Vt + ((size_t)hh * DH_ + dh) * S_ + s0 + sc) = o;
  }
}

// ======== MFMA flash attention v2 (unchanged) ========
__global__ __launch_bounds__(256) void k_attn2(const u16* __restrict__ qkvb,
                                               const u16* __restrict__ Vt,
                                               u16* __restrict__ out) {
  __shared__ u16 Ks[2][64 * 128];
  __shared__ u16 VTs[2][128 * 64];
  __shared__ u16 PT[4][64 * 16];
  const int tid = threadIdx.x;
  const int lane = tid & 63, w = tid >> 6;
  const int g = lane >> 4, l4 = lane & 15;
  const int p = blockIdx.x;
  const int hh = blockIdx.y;
  const int ld = 6144;
  const float rs = 0.08838834764831845f;
  const int qa0 = p * 64, qb0 = (31 - p) * 64;
  const int ntb = 32 - p;
  char* pt_w = (char*)&PT[w][0];

  const int qga = qa0 + w * 16 + l4;
  const int qgb = qb0 + w * 16 + l4;

  bf16x8 qfa[4], qfb[4];
#pragma unroll
  for (int kh = 0; kh < 4; ++kh) {
    qfa[kh] = *(const bf16x8*)(qkvb + (size_t)qga * ld + hh * DH_ + kh * 32 + g * 8);
    qfb[kh] = *(const bf16x8*)(qkvb + (size_t)qgb * ld + hh * DH_ + kh * 32 + g * 8);
  }

  float ma = -3.0e38f, la = 0.f, mb = -3.0e38f, lb = 0.f;
  f32x4 acc_a[8] = {}, acc_b[8] = {};
  bf16x8 pba[2], pbb[2];

  auto stage = [&](int buf, int kt) {
    const int kv0 = kt * 64;
#pragma unroll
    for (int i = 0; i < 4; ++i) {
      int rl = (w * 4 + i) * 4 + (lane >> 4);
      int cs = (lane & 15) ^ ((rl & 7) ^ (((rl >> 3) & 3) << 1));
      __builtin_amdgcn_global_load_lds(
          (const __attribute__((address_space(1))) void*)(
              qkvb + (size_t)(kv0 + rl) * ld + 2048 + hh * DH_ + cs * 8),
          (__attribute__((address_space(3))) void*)(&Ks[buf][(w * 4 + i) * 512]), 16, 0, 0);
    }
#pragma unroll
    for (int i = 0; i < 4; ++i) {
      int dh = (w * 4 + i) * 8 + (lane >> 3);
      int cs = (lane & 7) ^ (dh & 7);
      __builtin_amdgcn_global_load_lds(
          (const __attribute__((address_space(1))) void*)(
              Vt + ((size_t)hh * DH_ + dh) * S_ + kv0 + cs * 8),
          (__attribute__((address_space(3))) void*)(&VTs[buf][(w * 4 + i) * 512]), 16, 0, 0);
    }
  };

  auto softpb = [&](f32x4* sv, float& m, float& l, f32x4* acc, int qg, bool diag,
                    int kv0, bf16x8* pb) {
    float pv[16];
    float tmax = -3.0e38f;
#pragma unroll
    for (int kb = 0; kb < 4; ++kb)
#pragma unroll
      for (int r = 0; r < 4; ++r) {
        float s = sv[kb][r] * rs;
        if (diag) {
          int kglob = kv0 + kb * 16 + g * 4 + r;
          if (kglob > qg) s = -1.0e30f;
        }
        pv[kb * 4 + r] = s;
        tmax = fmaxf(tmax, s);
      }
    tmax = fmaxf(tmax, __shfl_xor(tmax, 16, 64));
    tmax = fmaxf(tmax, __shfl_xor(tmax, 32, 64));
    float mn = fmaxf(m, tmax);
    float corr = __expf(m - mn);
    m = mn;
    float ps = 0.f;
#pragma unroll
    for (int i = 0; i < 16; ++i) { pv[i] = __expf(pv[i] - mn); ps += pv[i]; }
    ps += __shfl_xor(ps, 16, 64);
    ps += __shfl_xor(ps, 32, 64);
    l = l * corr + ps;
#pragma unroll
    for (int f = 0; f < 8; ++f) {
      acc[f][0] *= corr; acc[f][1] *= corr; acc[f][2] *= corr; acc[f][3] *= corr;
    }
#pragma unroll
    for (int kb = 0; kb < 4; ++kb)
#pragma unroll
      for (int r = 0; r < 4; ++r) {
        int key = kb * 16 + g * 4 + r;
        int byte = (key * 32 + l4 * 2) ^ (((key >> 3) & 3) << 5);
        *(u16*)(pt_w + byte) = f2bf(pv[kb * 4 + r]);
      }
#pragma unroll
    for (int ks = 0; ks < 2; ++ks) {
      union { bf16x8 v; u16 s[8]; } ub;
#pragma unroll
      for (int j = 0; j < 8; ++j) {
        int key = ks * 32 + g * 8 + j;
        int byte = (key * 32 + l4 * 2) ^ (((key >> 3) & 3) << 5);
        ub.s[j] = *(const u16*)(pt_w + byte);
      }
      pb[ks] = ub.v;
    }
  };

  stage(0, 0);
  asm volatile("s_waitcnt vmcnt(0)" ::: "memory");
  __syncthreads();

  for (int kt = 0; kt < ntb; ++kt) {
    const int kv0 = kt * 64;
    const int buf = kt & 1;
    if (kt + 1 < ntb) stage(buf ^ 1, kt + 1);

    const char* kb_base = (const char*)&Ks[buf][0];
    const char* vb_base = (const char*)&VTs[buf][0];
    const bool doa = (kt <= p);

    f32x4 sa[4] = {}, sb[4] = {};
#pragma unroll
    for (int kb = 0; kb < 4; ++kb) {
#pragma unroll
      for (int kh = 0; kh < 4; ++kh) {
        int key = kb * 16 + l4;
        int ch = (kh * 4 + g) ^ ((key & 7) ^ (((key >> 3) & 3) << 1));
        bf16x8 af = *(const bf16x8*)(kb_base + key * 256 + ch * 16);
        if (doa) sa[kb] = MFMA16(af, qfa[kh], sa[kb]);
        sb[kb] = MFMA16(af, qfb[kh], sb[kb]);
      }
    }

    if (doa) softpb(sa, ma, la, acc_a, qga, kt == p, kv0, pba);
    softpb(sb, mb, lb, acc_b, qgb, kt == ntb - 1, kv0, pbb);

#pragma unroll
    for (int f = 0; f < 8; ++f) {
#pragma unroll
      for (int ks = 0; ks < 2; ++ks) {
        int dh = f * 16 + l4;
        int ch = (ks * 4 + g) ^ (dh & 7);
        bf16x8 va = *(const bf16x8*)(vb_base + dh * 128 + ch * 16);
        if (doa) acc_a[f] = MFMA16(va, pba[ks], acc_a[f]);
        acc_b[f] = MFMA16(va, pbb[ks], acc_b[f]);
      }
    }

    if (kt + 1 < ntb) {
      asm volatile("s_waitcnt vmcnt(0)" ::: "memory");
      __syncthreads();
    }
  }

  float inva = 1.f / la, invb = 1.f / lb;
  u16* opa = out + (size_t)qga * D_ + hh * DH_;
  u16* opb = out + (size_t)qgb * D_ + hh * DH_;
#pragma unroll
  for (int f = 0; f < 8; ++f)
#pragma unroll
    for (int r = 0; r < 4; ++r) {
      opa[f * 16 + g * 4 + r] = f2bf(acc_a[f][r] * inva);
      opb[f * 16 + g * 4 + r] = f2bf(acc_b[f][r] * invb);
    }
}

// ---------------- silu(gate)*up ----------------
__global__ __launch_bounds__(256) void k_silumul(u16* __restrict__ gu) {
  size_t i = ((size_t)blockIdx.x * 256 + threadIdx.x) * 4;
  int s = (int)(i >> 13);
  int f = (int)(i & 8191);
  u16* gp = gu + (size_t)s * (2 * DFF_) + f;
  ushort4 gt = *(ushort4*)gp;
  ushort4 up = *(ushort4*)(gp + DFF_);
  float g0 = bf2f(gt.x), g1 = bf2f(gt.y), g2 = bf2f(gt.z), g3 = bf2f(gt.w);
  float u0 = bf2f(up.x), u1 = bf2f(up.y), u2 = bf2f(up.z), u3 = bf2f(up.w);
  ushort4 o;
  o.x = f2bf(g0 / (1.f + __expf(-g0)) * u0);
  o.y = f2bf(g1 / (1.f + __expf(-g1)) * u1);
  o.z = f2bf(g2 / (1.f + __expf(-g2)) * u2);
  o.w = f2bf(g3 / (1.f + __expf(-g3)) * u3);
  *(ushort4*)gp = o;
}

// ---------------- gumbel softmax, ONE-PASS (z row staged in LDS) ----------------
// Block per row. z[32000] f32 in LDS (125 KiB). Each thread touches only its own
// strided entries (no cross-thread z hazard); inputs read once, one exp/elem.
__global__ __launch_bounds__(256) void k_gumbel(const float* __restrict__ logits,
                                                const float* __restrict__ u,
                                                u16* __restrict__ g) {
  __shared__ float z[V_];
  __shared__ float sred[4];
  int s = blockIdx.x;
  const float* lp = logits + (size_t)s * V_;
  const float* up = u + (size_t)s * V_;
  float m = -3.0e38f;
  for (int v4 = threadIdx.x; v4 < V_ / 4; v4 += 256) {
    float4 lv = *(const float4*)(lp + v4 * 4);
    float4 uv = *(const float4*)(up + v4 * 4);
    float z0 = lv.x - __logf(-__logf(uv.x + 1e-10f) + 1e-10f);
    float z1 = lv.y - __logf(-__logf(uv.y + 1e-10f) + 1e-10f);
    float z2 = lv.z - __logf(-__logf(uv.z + 1e-10f) + 1e-10f);
    float z3 = lv.w - __logf(-__logf(uv.w + 1e-10f) + 1e-10f);
    *(float4*)(z + v4 * 4) = make_float4(z0, z1, z2, z3);
    m = fmaxf(fmaxf(fmaxf(m, z0), fmaxf(z1, z2)), z3);
  }
#pragma unroll
  for (int msk = 1; msk < 64; msk <<= 1) m = fmaxf(m, __shfl_xor(m, msk, 64));
  if ((threadIdx.x & 63) == 0) sred[threadIdx.x >> 6] = m;
  __syncthreads();
  float M = fmaxf(fmaxf(sred[0], sred[1]), fmaxf(sred[2], sred[3]));
  float l = 0.f;
  for (int v4 = threadIdx.x; v4 < V_ / 4; v4 += 256) {
    float4 zv = *(float4*)(z + v4 * 4);
    zv.x = __expf(zv.x - M); zv.y = __expf(zv.y - M);
    zv.z = __expf(zv.z - M); zv.w = __expf(zv.w - M);
    *(float4*)(z + v4 * 4) = zv;
    l += (zv.x + zv.y) + (zv.z + zv.w);
  }
#pragma unroll
  for (int msk = 1; msk < 64; msk <<= 1) l += __shfl_xor(l, msk, 64);
  __syncthreads();
  if ((threadIdx.x & 63) == 0) sred[threadIdx.x >> 6] = l;
  __syncthreads();
  float inv = 1.f / (sred[0] + sred[1] + sred[2] + sred[3]);
  u16* gp = g + (size_t)s * V_;
  for (int v4 = threadIdx.x; v4 < V_ / 4; v4 += 256) {
    float4 zv = *(float4*)(z + v4 * 4);
    ushort4 o;
    o.x = f2bf(zv.x * inv); o.y = f2bf(zv.y * inv);
    o.z = f2bf(zv.z * inv); o.w = f2bf(zv.w * inv);
    *(ushort4*)(gp + v4 * 4) = o;
  }
}

extern "C" void kernel_launch(void* const* d_in, const int* in_sizes, int n_in,
                              void* d_out, int out_size, void* d_ws, size_t ws_size,
                              hipStream_t stream) {
  const int*   ids        = (const int*)d_in[0];
  const float* u          = (const float*)d_in[1];
  const float* emb        = (const float*)d_in[2];
  const float* attn_scale = (const float*)d_in[3];
  const float* gu_scale   = (const float*)d_in[4];
  const float* dn_scale   = (const float*)d_in[5];
  const float* lora_A     = (const float*)d_in[6];
  const float* lora_B     = (const float*)d_in[7];
  const float* norm_w     = (const float*)d_in[8];
  const float* fnorm_w    = (const float*)d_in[9];
  const int*   attn_idx   = (const int*)d_in[10];
  const int*   gu_idx     = (const int*)d_in[11];
  const int*   dn_idx     = (const int*)d_in[12];

  float* out_se = (float*)d_out;
  float* out_lg = (float*)d_out + (size_t)S_ * D_;

  char* W = (char*)d_ws;
  float* h    = (float*)(W);                          // 16 MiB
  u16*   xb   = (u16*)(W + ((size_t)16 << 20));       // 8 MiB
  u16*   qkvb = (u16*)(W + ((size_t)72 << 20));       // 24 MiB
  u16*   Vtb  = (u16*)(W + ((size_t)96 << 20));       // 8 MiB
  u16*   ob   = (u16*)(W + ((size_t)104 << 20));      // 8 MiB
  u16*   gub  = (u16*)(W + ((size_t)112 << 20));      // 64 MiB
  u16*   wdq  = (u16*)(W + ((size_t)176 << 20));      // 64 MiB
  float* Tl   = (float*)(W + ((size_t)240 << 20));    // 192 KiB
  u16*   embb = (u16*)(W);                            // 125 MiB (head)
  u16*   gsm  = (u16*)(W + ((size_t)125 << 20));      // 125 MiB (head)
  u16*   embT = (u16*)(W);                            // 125 MiB (replaces embb)
  u16*   xbh  = (u16*)d_out;                          // final-norm out, parked in out_se
  float* Pk   = (float*)(W + ((size_t)250 << 20));    // 64 MiB split-K partials
  const bool big = ws_size >= ((size_t)314 << 20);
  const size_t ZS = (size_t)4 * 1024 * 1024;

  dim3 b256(256), b512(512);

  k_gather<<<dim3(S_ * D_ / 256), b256, 0, stream>>>(ids, emb, h);

  for (int l = 0; l < L_; ++l) {
    const int*   aidx = attn_idx + (size_t)l * 4 * D_ * D_;
    const float* ascl = attn_scale + (size_t)l * 4 * D_ * (D_ / 64);
    const float* lA   = lora_A + (size_t)l * 4 * R_ * D_;
    const float* lB   = lora_B + (size_t)l * 4 * D_ * R_;

    // ---- attention ----
    k_rmsnorm<<<dim3(S_), b256, 0, stream>>>(h, norm_w + (size_t)l * 2 * D_, xb);
    k_dequant<<<dim3(4 * D_ * D_ / 8 / 256), b256, 0, stream>>>(aidx, ascl, wdq, 11);
    k_gemm256<OUT_BF16><<<dim3(3 * D_ / 256, 8), b512, 0, stream>>>(
        xb, D_, wdq, D_, qkvb, 3 * D_, D_, 0);
    k_lora_down<<<dim3(S_), b256, 0, stream>>>(xb, lA, Tl, 3);
    k_lora_up_qkv<<<dim3(S_ * 3 * D_ / 8 / 256), b256, 0, stream>>>(qkvb, Tl, lB);
    k_vtrans<<<dim3(S_ / 64, H_), b256, 0, stream>>>(qkvb, Vtb);
    k_attn2<<<dim3(16, H_), b256, 0, stream>>>(qkvb, Vtb, ob);
    k_gemm256<OUT_F32_ACC><<<dim3(D_ / 256, 8), b512, 0, stream>>>(
        ob, D_, wdq + (size_t)3 * D_ * D_, D_, h, D_, D_, 0);
    k_lora_down<<<dim3(S_), b256, 0, stream>>>(ob, lA + (size_t)3 * R_ * D_, Tl, 1);
    k_lora_up<<<dim3(S_ * D_ / 256), b256, 0, stream>>>(h, D_, Tl, lB + (size_t)3 * D_ * R_, 1);

    // ---- ffn ----
    k_rmsnorm<<<dim3(S_), b256, 0, stream>>>(h, norm_w + (size_t)l * 2 * D_ + D_, xb);
    k_dequant<<<dim3(2 * DFF_ * D_ / 8 / 256), b256, 0, stream>>>(
        gu_idx + (size_t)l * 2 * DFF_ * D_, gu_scale + (size_t)l * 2 * DFF_ * (D_ / 64), wdq, 11);
    k_gemm256<OUT_BF16><<<dim3(2 * DFF_ / 256, 8), b512, 0, stream>>>(
        xb, D_, wdq, D_, gub, 2 * DFF_, D_, 0);
    k_silumul<<<dim3(S_ * DFF_ / 4 / 256), b256, 0, stream>>>(gub);
    k_dequant<<<dim3(D_ * DFF_ / 8 / 256), b256, 0, stream>>>(
        dn_idx + (size_t)l * D_ * DFF_, dn_scale + (size_t)l * D_ * (DFF_ / 64), wdq, 13);
    if (big) {
      k_gemm256<OUT_F32><<<dim3(D_ / 256, 8, 4), b512, 0, stream>>>(
          gub, 2 * DFF_, wdq, DFF_, Pk, D_, DFF_ / 4, ZS);
      k_red<<<dim3(4096), b256, 0, stream>>>(Pk, h, 1);
    } else {
      k_gemm256<OUT_F32_ACC><<<dim3(D_ / 256, 8), b512, 0, stream>>>(
          gub, 2 * DFF_, wdq, DFF_, h, D_, DFF_, 0);
    }
  }

  // ---- head ----
  k_rmsnorm<<<dim3(S_), b256, 0, stream>>>(h, fnorm_w, xbh);
  k_f2b<<<dim3(V_ * D_ / 8 / 256), b256, 0, stream>>>(emb, embb);
  k_gemm256<OUT_F32><<<dim3(V_ / 256, 8), b512, 0, stream>>>(
      xbh, D_, embb, D_, out_lg, V_, D_, 0);
  k_gumbel<<<dim3(S_), b256, 0, stream>>>(out_lg, u, gsm);
  k_transpose<<<dim3(V_ / 64, D_ / 64), b256, 0, stream>>>(emb, embT);
  if (big) {
    k_gemm256<OUT_F32><<<dim3(D_ / 256, 8, 4), b512, 0, stream>>>(
        gsm, V_, embT, V_, Pk, D_, V_ / 4, ZS);
    k_red<<<dim3(4096), b256, 0, stream>>>(Pk, out_se, 0);
  } else {
    k_gemm256<OUT_F32><<<dim3(D_ / 256, 8), b512, 0, stream>>>(
        gsm, V_, embT, V_, out_se, D_, V_, 0);
  }
}

// Round 11
// 2442.041 us; speedup vs baseline: 7.1027x; 1.0009x over previous
//
#include <hip/hip_runtime.h>
#include <hip/hip_bf16.h>

typedef unsigned short u16;
typedef unsigned int u32;
typedef __bf16 bf16t;
typedef bf16t bf16x8 __attribute__((ext_vector_type(8)));
typedef float f32x4 __attribute__((ext_vector_type(4)));

constexpr int S_   = 2048;
constexpr int D_   = 2048;
constexpr int H_   = 16;
constexpr int DH_  = 128;
constexpr int L_   = 2;
constexpr int DFF_ = 8192;
constexpr int V_   = 32000;
constexpr int R_   = 8;

#define MFMA16(a, b, c) __builtin_amdgcn_mfma_f32_16x16x32_bf16(a, b, c, 0, 0, 0)

__constant__ float c_nf4[16] = {
  -1.0f, -0.6961928009986877f, -0.5250730514526367f, -0.39491748809814453f,
  -0.28444138169288635f, -0.18477343022823334f, -0.09105003625154495f, 0.0f,
  0.07958029955625534f, 0.16093020141124725f, 0.24611230194568634f,
  0.33791524171829224f, 0.44070982933044434f, 0.5626170039176941f,
  0.7229568362236023f, 1.0f };

__device__ __forceinline__ u16 f2bf(float f) {
  union { float f; u32 u; } v; v.f = f;
  u32 r = v.u + 0x7fffu + ((v.u >> 16) & 1u);
  return (u16)(r >> 16);
}
__device__ __forceinline__ float bf2f(u16 h) {
  union { u32 u; float f; } v; v.u = ((u32)h) << 16; return v.f;
}

// ---------------- embedding gather ----------------
__global__ __launch_bounds__(256) void k_gather(const int* __restrict__ ids,
                                                const float* __restrict__ emb,
                                                float* __restrict__ h) {
  int t = blockIdx.x * 256 + threadIdx.x;
  int s = t >> 11;
  int d = t & 2047;
  h[t] = emb[(size_t)ids[s] * D_ + d];
}

// ---------------- rmsnorm f32 -> bf16 ----------------
__global__ __launch_bounds__(256) void k_rmsnorm(const float* __restrict__ in,
                                                 const float* __restrict__ w,
                                                 u16* __restrict__ out) {
  int s = blockIdx.x;
  const float* x = in + (size_t)s * D_;
  float ss = 0.f;
  for (int d = threadIdx.x; d < D_; d += 256) { float v = x[d]; ss += v * v; }
#pragma unroll
  for (int m = 1; m < 64; m <<= 1) ss += __shfl_xor(ss, m, 64);
  __shared__ float sh[4];
  if ((threadIdx.x & 63) == 0) sh[threadIdx.x >> 6] = ss;
  __syncthreads();
  ss = sh[0] + sh[1] + sh[2] + sh[3];
  float sc = rsqrtf(ss * (1.0f / D_) + 1e-6f);
  u16* o = out + (size_t)s * D_;
  for (int d = threadIdx.x; d < D_; d += 256) o[d] = f2bf(x[d] * sc * w[d]);
}

// ---------------- NF4 dequant ----------------
__global__ __launch_bounds__(256) void k_dequant(const int* __restrict__ idx,
                                                 const float* __restrict__ scale,
                                                 u16* __restrict__ out, int kshift) {
  size_t t = (size_t)blockIdx.x * 256 + threadIdx.x;
  size_t e = t * 8;
  int k = (int)(e & ((1u << kshift) - 1));
  size_t n = e >> kshift;
  float s = scale[(n << (kshift - 6)) + (k >> 6)];
  int4 i0 = *(const int4*)(idx + e);
  int4 i1 = *(const int4*)(idx + e + 4);
  uint4 o;
  o.x = (u32)f2bf(c_nf4[i0.x] * s) | ((u32)f2bf(c_nf4[i0.y] * s) << 16);
  o.y = (u32)f2bf(c_nf4[i0.z] * s) | ((u32)f2bf(c_nf4[i0.w] * s) << 16);
  o.z = (u32)f2bf(c_nf4[i1.x] * s) | ((u32)f2bf(c_nf4[i1.y] * s) << 16);
  o.w = (u32)f2bf(c_nf4[i1.z] * s) | ((u32)f2bf(c_nf4[i1.w] * s) << 16);
  *(uint4*)(out + e) = o;
}

// ---------------- f32 -> bf16 convert (emb) ----------------
__global__ __launch_bounds__(256) void k_f2b(const float* __restrict__ src,
                                             u16* __restrict__ dst) {
  size_t e = ((size_t)blockIdx.x * 256 + threadIdx.x) * 8;
  float4 f0 = *(const float4*)(src + e);
  float4 f1 = *(const float4*)(src + e + 4);
  uint4 o;
  o.x = (u32)f2bf(f0.x) | ((u32)f2bf(f0.y) << 16);
  o.y = (u32)f2bf(f0.z) | ((u32)f2bf(f0.w) << 16);
  o.z = (u32)f2bf(f1.x) | ((u32)f2bf(f1.y) << 16);
  o.w = (u32)f2bf(f1.z) | ((u32)f2bf(f1.w) << 16);
  *(uint4*)(dst + e) = o;
}

// ---------------- transpose-convert: emb f32 [V,D] -> embT bf16 [D,V] ----------
__global__ __launch_bounds__(256) void k_transpose(const float* __restrict__ src,
                                                   u16* __restrict__ dst) {
  __shared__ u16 tile[64][65];
  int v0 = blockIdx.x * 64, d0 = blockIdx.y * 64;
  int tid = threadIdx.x;
  int rr = tid >> 4, cc = (tid & 15) * 4;
#pragma unroll
  for (int j = 0; j < 4; ++j) {
    int r = j * 16 + rr;
    float4 f = *(const float4*)(src + (size_t)(v0 + r) * D_ + d0 + cc);
    tile[r][cc + 0] = f2bf(f.x); tile[r][cc + 1] = f2bf(f.y);
    tile[r][cc + 2] = f2bf(f.z); tile[r][cc + 3] = f2bf(f.w);
  }
  __syncthreads();
#pragma unroll
  for (int j = 0; j < 4; ++j) {
    int r = j * 16 + rr;
    ushort4 w;
    w.x = tile[cc + 0][r]; w.y = tile[cc + 1][r];
    w.z = tile[cc + 2][r]; w.w = tile[cc + 3][r];
    *(ushort4*)(dst + (size_t)(d0 + r) * V_ + v0 + cc) = w;
  }
}

// ======== 256x256 pipelined MFMA GEMM (round-9 version, known-good) ========
enum { OUT_F32 = 0, OUT_F32_ACC = 1, OUT_BF16 = 2 };

template<int OUTMODE>
__global__ __launch_bounds__(512, 2) void k_gemm256(const u16* __restrict__ A, int lda,
                                                    const u16* __restrict__ B, int ldb,
                                                    void* __restrict__ Cv, int ldc,
                                                    int Kc, size_t zstride) {
  __shared__ u16 As[2][256][64];
  __shared__ u16 Bs[2][256][64];
  const int tid = threadIdx.x;
  const int lane = tid & 63, w = tid >> 6;
  const int wr = w >> 2, wc = w & 3;
  const int g = (lane >> 4), l15 = lane & 15, sl7 = lane & 7;

  const int gx = gridDim.x, gy = gridDim.y;
  const int cpx = (gx * gy) >> 3;
  int d = blockIdx.y * gx + blockIdx.x;
  int swz = (d & 7) * cpx + (d >> 3);
  const int m0 = (swz % gy) * 256;
  const int n0 = (swz / gy) * 256;

  A += (size_t)blockIdx.z * Kc;
  B += (size_t)blockIdx.z * Kc;
  float* Cf = (float*)Cv + (size_t)blockIdx.z * zstride;

  const int NT = Kc >> 6;
  const int srow = w * 8 + (lane >> 3);
  const int sch  = (lane & 7) ^ (lane >> 3);

  auto stageA = [&](int half, int tile) {
    const u16* src = A + (size_t)(m0 + half * 128 + srow) * lda + tile * 64 + sch * 8;
    u16* dst = &As[tile & 1][half * 128 + w * 8][0];
#pragma unroll
    for (int rnd = 0; rnd < 2; ++rnd)
      __builtin_amdgcn_global_load_lds(
          (const __attribute__((address_space(1))) void*)(src + (size_t)rnd * 64 * lda),
          (__attribute__((address_space(3))) void*)(dst + rnd * 64 * 64), 16, 0, 0);
  };
  auto stageB = [&](int half, int tile) {
    const u16* src = B + (size_t)(n0 + half * 128 + srow) * ldb + tile * 64 + sch * 8;
    u16* dst = &Bs[tile & 1][half * 128 + w * 8][0];
#pragma unroll
    for (int rnd = 0; rnd < 2; ++rnd)
      __builtin_amdgcn_global_load_lds(
          (const __attribute__((address_space(1))) void*)(src + (size_t)rnd * 64 * ldb),
          (__attribute__((address_space(3))) void*)(dst + rnd * 64 * 64), 16, 0, 0);
  };

  f32x4 acc[8][4] = {};
  bf16x8 areg[4][2], breg[2][2][2];

  stageB(0, 0); stageB(1, 0); stageA(0, 0); stageA(1, 0);
  if (NT > 1) {
    stageB(0, 1); stageB(1, 1); stageA(0, 1); stageA(1, 1);
    asm volatile("s_waitcnt vmcnt(8)" ::: "memory");
  } else {
    asm volatile("s_waitcnt vmcnt(0)" ::: "memory");
  }
  __builtin_amdgcn_s_barrier();

#define LOADA(QR)                                                                   \
  _Pragma("unroll") for (int m = 0; m < 4; ++m)                                     \
    _Pragma("unroll") for (int kh = 0; kh < 2; ++kh) {                              \
      int hr = wr * 128 + (QR) * 64 + m * 16 + l15;                                 \
      areg[m][kh] = *(const bf16x8*)(abase + hr * 64 + ((((kh << 2) | g) ^ sl7) << 3)); \
    }
#define LOADB(QC)                                                                   \
  _Pragma("unroll") for (int n = 0; n < 2; ++n)                                     \
    _Pragma("unroll") for (int kh = 0; kh < 2; ++kh) {                              \
      int br = wc * 64 + (QC) * 32 + n * 16 + l15;                                  \
      breg[QC][n][kh] = *(const bf16x8*)(bbase + br * 64 + ((((kh << 2) | g) ^ sl7) << 3)); \
    }
#define QPHASE(QR, QC)                                                              \
  __builtin_amdgcn_s_setprio(1);                                                    \
  _Pragma("unroll") for (int m = 0; m < 4; ++m)                                     \
    _Pragma("unroll") for (int n = 0; n < 2; ++n)                                   \
      _Pragma("unroll") for (int kh = 0; kh < 2; ++kh)                              \
        acc[(QR) * 4 + m][(QC) * 2 + n] = __builtin_amdgcn_mfma_f32_16x16x32_bf16(  \
            areg[m][kh], breg[QC][n][kh], acc[(QR) * 4 + m][(QC) * 2 + n], 0, 0, 0); \
  __builtin_amdgcn_s_setprio(0);

  for (int t = 0; t < NT; ++t) {
    const u16* abase = &As[t & 1][0][0];
    const u16* bbase = &Bs[t & 1][0][0];
    LOADA(0); LOADB(0);
    __builtin_amdgcn_s_barrier();
    asm volatile("s_waitcnt lgkmcnt(0)" ::: "memory");
    QPHASE(0, 0);
    __builtin_amdgcn_s_barrier();
    LOADB(1);
    __builtin_amdgcn_s_barrier();
    asm volatile("s_waitcnt lgkmcnt(0)" ::: "memory");
    QPHASE(0, 1);
    __builtin_amdgcn_s_barrier();
    LOADA(1);
    if (t + 2 < NT) { stageB(0, t + 2); stageB(1, t + 2); }
    __builtin_amdgcn_s_barrier();
    asm volatile("s_waitcnt lgkmcnt(0)" ::: "memory");
    QPHASE(1, 1);
    __builtin_amdgcn_s_barrier();
    if (t + 2 < NT) { stageA(0, t + 2); stageA(1, t + 2); }
    QPHASE(1, 0);
    if (t + 1 < NT) {
      if (t + 2 < NT) asm volatile("s_waitcnt vmcnt(8)" ::: "memory");
      else            asm volatile("s_waitcnt vmcnt(0)" ::: "memory");
    }
    __builtin_amdgcn_s_barrier();
  }
#undef LOADA
#undef LOADB
#undef QPHASE

  const int er = g * 4;
#pragma unroll
  for (int i = 0; i < 8; ++i)
#pragma unroll
    for (int j = 0; j < 4; ++j)
#pragma unroll
      for (int r = 0; r < 4; ++r) {
        int row = m0 + wr * 128 + i * 16 + er + r;
        int col = n0 + wc * 64 + j * 16 + l15;
        if (OUTMODE == OUT_BF16) {
          ((u16*)Cv)[(size_t)row * ldc + col] = f2bf(acc[i][j][r]);
        } else if (OUTMODE == OUT_F32_ACC) {
          Cf[(size_t)row * ldc + col] += acc[i][j][r];
        } else {
          Cf[(size_t)row * ldc + col] = acc[i][j][r];
        }
      }
}

// ---------------- split-K reduce ----------------
__global__ __launch_bounds__(256) void k_red(const float* __restrict__ P,
                                             float* __restrict__ dst, int accmode) {
  size_t i = ((size_t)blockIdx.x * 256 + threadIdx.x) * 4;
  const size_t n = (size_t)4 * 1024 * 1024;
  float4 a = *(const float4*)(P + i);
  float4 b = *(const float4*)(P + n + i);
  float4 c = *(const float4*)(P + 2 * n + i);
  float4 d = *(const float4*)(P + 3 * n + i);
  float4 r;
  r.x = (a.x + b.x) + (c.x + d.x);
  r.y = (a.y + b.y) + (c.y + d.y);
  r.z = (a.z + b.z) + (c.z + d.z);
  r.w = (a.w + b.w) + (c.w + d.w);
  if (accmode) {
    float4 o = *(const float4*)(dst + i);
    r.x += o.x; r.y += o.y; r.z += o.z; r.w += o.w;
  }
  *(float4*)(dst + i) = r;
}

// ---------------- LoRA ----------------
__global__ __launch_bounds__(256) void k_lora_down(const u16* __restrict__ X,
                                                   const float* __restrict__ A,
                                                   float* __restrict__ T, int nproj) {
  int s = blockIdx.x;
  int lane = threadIdx.x & 63, wv = threadIdx.x >> 6;
  const u16* x = X + (size_t)s * D_;
  for (int p = wv; p < nproj * R_; p += 4) {
    const float* a = A + (size_t)p * D_;
    float sum = 0.f;
    for (int d = lane; d < D_; d += 64) sum += bf2f(x[d]) * a[d];
#pragma unroll
    for (int m = 1; m < 64; m <<= 1) sum += __shfl_xor(sum, m, 64);
    if (lane == 0) T[(size_t)s * (nproj * R_) + p] = sum;
  }
}

__global__ __launch_bounds__(256) void k_lora_up(float* __restrict__ Y, int ystride,
                                                 const float* __restrict__ T,
                                                 const float* __restrict__ Bm, int nproj) {
  int t = blockIdx.x * 256 + threadIdx.x;
  int d = t & (D_ - 1);
  int si = t >> 11;
  int i = si % nproj;
  int s = si / nproj;
  const float* tp = T + ((size_t)s * nproj + i) * R_;
  const float* bp = Bm + ((size_t)i * D_ + d) * R_;
  float acc = 0.f;
#pragma unroll
  for (int r = 0; r < R_; r++) acc += tp[r] * bp[r];
  Y[(size_t)s * ystride + (size_t)i * D_ + d] += 2.0f * acc;
}

// ---- LoRA-up for qkv, bf16 in-place ----
__global__ __launch_bounds__(256) void k_lora_up_qkv(u16* __restrict__ qkvb,
                                                     const float* __restrict__ T,
                                                     const float* __restrict__ Bm) {
  size_t t = ((size_t)blockIdx.x * 256 + threadIdx.x) * 8;
  int c = (int)(t % 6144);
  int s = (int)(t / 6144);
  int i = c >> 11, dd = c & 2047;
  const float* tp = T + ((size_t)s * 3 + i) * R_;
  float tr[8];
#pragma unroll
  for (int r = 0; r < R_; ++r) tr[r] = tp[r];
  uint4 q = *(const uint4*)(qkvb + t);
  u16 qs[8] = {(u16)(q.x & 0xffff), (u16)(q.x >> 16), (u16)(q.y & 0xffff), (u16)(q.y >> 16),
               (u16)(q.z & 0xffff), (u16)(q.z >> 16), (u16)(q.w & 0xffff), (u16)(q.w >> 16)};
  u16 os[8];
#pragma unroll
  for (int j = 0; j < 8; ++j) {
    const float* bp = Bm + ((size_t)i * D_ + dd + j) * R_;
    float a = 0.f;
#pragma unroll
    for (int r = 0; r < R_; ++r) a += tr[r] * bp[r];
    os[j] = f2bf(bf2f(qs[j]) + 2.0f * a);
  }
  uint4 o;
  o.x = (u32)os[0] | ((u32)os[1] << 16);
  o.y = (u32)os[2] | ((u32)os[3] << 16);
  o.z = (u32)os[4] | ((u32)os[5] << 16);
  o.w = (u32)os[6] | ((u32)os[7] << 16);
  *(uint4*)(qkvb + t) = o;
}

// ---- per-head V transpose ----
__global__ __launch_bounds__(256) void k_vtrans(const u16* __restrict__ qkvb,
                                                u16* __restrict__ Vt) {
  __shared__ u16 t[64][136];
  int s0 = blockIdx.x * 64, hh = blockIdx.y;
  int tid = threadIdx.x;
#pragma unroll
  for (int it = 0; it < 4; ++it) {
    int e = it * 2048 + tid * 8;
    int sr = e >> 7, sc = e & 127;
    *(uint4*)&t[sr][sc] =
        *(const uint4*)(qkvb + (size_t)(s0 + sr) * 6144 + 4096 + hh * 128 + sc);
  }
  __syncthreads();
#pragma unroll
  for (int it = 0; it < 4; ++it) {
    int q = it * 256 + tid;
    int dh = q >> 3, sc = (q & 7) * 8;
    u16 e0 = t[sc + 0][dh], e1 = t[sc + 1][dh], e2 = t[sc + 2][dh], e3 = t[sc + 3][dh];
    u16 e4 = t[sc + 4][dh], e5 = t[sc + 5][dh], e6 = t[sc + 6][dh], e7 = t[sc + 7][dh];
    uint4 o;
    o.x = (u32)e0 | ((u32)e1 << 16);
    o.y = (u32)e2 | ((u32)e3 << 16);
    o.z = (u32)e4 | ((u32)e5 << 16);
    o.w = (u32)e6 | ((u32)e7 << 16);
    *(uint4*)(Vt + ((size_t)hh * DH_ + dh) * S_ + s0 + sc) = o;
  }
}

// ======== MFMA flash attention v2 ========
__global__ __launch_bounds__(256) void k_attn2(const u16* __restrict__ qkvb,
                                               const u16* __restrict__ Vt,
                                               u16* __restrict__ out) {
  __shared__ u16 Ks[2][64 * 128];
  __shared__ u16 VTs[2][128 * 64];
  __shared__ u16 PT[4][64 * 16];
  const int tid = threadIdx.x;
  const int lane = tid & 63, w = tid >> 6;
  const int g = lane >> 4, l4 = lane & 15;
  const int p = blockIdx.x;
  const int hh = blockIdx.y;
  const int ld = 6144;
  const float rs = 0.08838834764831845f;
  const int qa0 = p * 64, qb0 = (31 - p) * 64;
  const int ntb = 32 - p;
  char* pt_w = (char*)&PT[w][0];

  const int qga = qa0 + w * 16 + l4;
  const int qgb = qb0 + w * 16 + l4;

  bf16x8 qfa[4], qfb[4];
#pragma unroll
  for (int kh = 0; kh < 4; ++kh) {
    qfa[kh] = *(const bf16x8*)(qkvb + (size_t)qga * ld + hh * DH_ + kh * 32 + g * 8);
    qfb[kh] = *(const bf16x8*)(qkvb + (size_t)qgb * ld + hh * DH_ + kh * 32 + g * 8);
  }

  float ma = -3.0e38f, la = 0.f, mb = -3.0e38f, lb = 0.f;
  f32x4 acc_a[8] = {}, acc_b[8] = {};
  bf16x8 pba[2], pbb[2];

  auto stage = [&](int buf, int kt) {
    const int kv0 = kt * 64;
#pragma unroll
    for (int i = 0; i < 4; ++i) {
      int rl = (w * 4 + i) * 4 + (lane >> 4);
      int cs = (lane & 15) ^ ((rl & 7) ^ (((rl >> 3) & 3) << 1));
      __builtin_amdgcn_global_load_lds(
          (const __attribute__((address_space(1))) void*)(
              qkvb + (size_t)(kv0 + rl) * ld + 2048 + hh * DH_ + cs * 8),
          (__attribute__((address_space(3))) void*)(&Ks[buf][(w * 4 + i) * 512]), 16, 0, 0);
    }
#pragma unroll
    for (int i = 0; i < 4; ++i) {
      int dh = (w * 4 + i) * 8 + (lane >> 3);
      int cs = (lane & 7) ^ (dh & 7);
      __builtin_amdgcn_global_load_lds(
          (const __attribute__((address_space(1))) void*)(
              Vt + ((size_t)hh * DH_ + dh) * S_ + kv0 + cs * 8),
          (__attribute__((address_space(3))) void*)(&VTs[buf][(w * 4 + i) * 512]), 16, 0, 0);
    }
  };

  auto softpb = [&](f32x4* sv, float& m, float& l, f32x4* acc, int qg, bool diag,
                    int kv0, bf16x8* pb) {
    float pv[16];
    float tmax = -3.0e38f;
#pragma unroll
    for (int kb = 0; kb < 4; ++kb)
#pragma unroll
      for (int r = 0; r < 4; ++r) {
        float s = sv[kb][r] * rs;
        if (diag) {
          int kglob = kv0 + kb * 16 + g * 4 + r;
          if (kglob > qg) s = -1.0e30f;
        }
        pv[kb * 4 + r] = s;
        tmax = fmaxf(tmax, s);
      }
    tmax = fmaxf(tmax, __shfl_xor(tmax, 16, 64));
    tmax = fmaxf(tmax, __shfl_xor(tmax, 32, 64));
    float mn = fmaxf(m, tmax);
    float corr = __expf(m - mn);
    m = mn;
    float ps = 0.f;
#pragma unroll
    for (int i = 0; i < 16; ++i) { pv[i] = __expf(pv[i] - mn); ps += pv[i]; }
    ps += __shfl_xor(ps, 16, 64);
    ps += __shfl_xor(ps, 32, 64);
    l = l * corr + ps;
#pragma unroll
    for (int f = 0; f < 8; ++f) {
      acc[f][0] *= corr; acc[f][1] *= corr; acc[f][2] *= corr; acc[f][3] *= corr;
    }
#pragma unroll
    for (int kb = 0; kb < 4; ++kb)
#pragma unroll
      for (int r = 0; r < 4; ++r) {
        int key = kb * 16 + g * 4 + r;
        int byte = (key * 32 + l4 * 2) ^ (((key >> 3) & 3) << 5);
        *(u16*)(pt_w + byte) = f2bf(pv[kb * 4 + r]);
      }
#pragma unroll
    for (int ks = 0; ks < 2; ++ks) {
      union { bf16x8 v; u16 s[8]; } ub;
#pragma unroll
      for (int j = 0; j < 8; ++j) {
        int key = ks * 32 + g * 8 + j;
        int byte = (key * 32 + l4 * 2) ^ (((key >> 3) & 3) << 5);
        ub.s[j] = *(const u16*)(pt_w + byte);
      }
      pb[ks] = ub.v;
    }
  };

  stage(0, 0);
  asm volatile("s_waitcnt vmcnt(0)" ::: "memory");
  __syncthreads();

  for (int kt = 0; kt < ntb; ++kt) {
    const int kv0 = kt * 64;
    const int buf = kt & 1;
    if (kt + 1 < ntb) stage(buf ^ 1, kt + 1);

    const char* kb_base = (const char*)&Ks[buf][0];
    const char* vb_base = (const char*)&VTs[buf][0];
    const bool doa = (kt <= p);

    f32x4 sa[4] = {}, sb[4] = {};
#pragma unroll
    for (int kb = 0; kb < 4; ++kb) {
#pragma unroll
      for (int kh = 0; kh < 4; ++kh) {
        int key = kb * 16 + l4;
        int ch = (kh * 4 + g) ^ ((key & 7) ^ (((key >> 3) & 3) << 1));
        bf16x8 af = *(const bf16x8*)(kb_base + key * 256 + ch * 16);
        if (doa) sa[kb] = MFMA16(af, qfa[kh], sa[kb]);
        sb[kb] = MFMA16(af, qfb[kh], sb[kb]);
      }
    }

    if (doa) softpb(sa, ma, la, acc_a, qga, kt == p, kv0, pba);
    softpb(sb, mb, lb, acc_b, qgb, kt == ntb - 1, kv0, pbb);

#pragma unroll
    for (int f = 0; f < 8; ++f) {
#pragma unroll
      for (int ks = 0; ks < 2; ++ks) {
        int dh = f * 16 + l4;
        int ch = (ks * 4 + g) ^ (dh & 7);
        bf16x8 va = *(const bf16x8*)(vb_base + dh * 128 + ch * 16);
        if (doa) acc_a[f] = MFMA16(va, pba[ks], acc_a[f]);
        acc_b[f] = MFMA16(va, pbb[ks], acc_b[f]);
      }
    }

    if (kt + 1 < ntb) {
      asm volatile("s_waitcnt vmcnt(0)" ::: "memory");
      __syncthreads();
    }
  }

  float inva = 1.f / la, invb = 1.f / lb;
  u16* opa = out + (size_t)qga * D_ + hh * DH_;
  u16* opb = out + (size_t)qgb * D_ + hh * DH_;
#pragma unroll
  for (int f = 0; f < 8; ++f)
#pragma unroll
    for (int r = 0; r < 4; ++r) {
      opa[f * 16 + g * 4 + r] = f2bf(acc_a[f][r] * inva);
      opb[f * 16 + g * 4 + r] = f2bf(acc_b[f][r] * invb);
    }
}

// ---------------- silu(gate)*up ----------------
__global__ __launch_bounds__(256) void k_silumul(u16* __restrict__ gu) {
  size_t i = ((size_t)blockIdx.x * 256 + threadIdx.x) * 4;
  int s = (int)(i >> 13);
  int f = (int)(i & 8191);
  u16* gp = gu + (size_t)s * (2 * DFF_) + f;
  ushort4 gt = *(ushort4*)gp;
  ushort4 up = *(ushort4*)(gp + DFF_);
  float g0 = bf2f(gt.x), g1 = bf2f(gt.y), g2 = bf2f(gt.z), g3 = bf2f(gt.w);
  float u0 = bf2f(up.x), u1 = bf2f(up.y), u2 = bf2f(up.z), u3 = bf2f(up.w);
  ushort4 o;
  o.x = f2bf(g0 / (1.f + __expf(-g0)) * u0);
  o.y = f2bf(g1 / (1.f + __expf(-g1)) * u1);
  o.z = f2bf(g2 / (1.f + __expf(-g2)) * u2);
  o.w = f2bf(g3 / (1.f + __expf(-g3)) * u3);
  *(ushort4*)gp = o;
}

// ---------------- gumbel softmax, ONE-PASS ----------------
__global__ __launch_bounds__(256) void k_gumbel(const float* __restrict__ logits,
                                                const float* __restrict__ u,
                                                u16* __restrict__ g) {
  __shared__ float z[V_];
  __shared__ float sred[4];
  int s = blockIdx.x;
  const float* lp = logits + (size_t)s * V_;
  const float* up = u + (size_t)s * V_;
  float m = -3.0e38f;
  for (int v4 = threadIdx.x; v4 < V_ / 4; v4 += 256) {
    float4 lv = *(const float4*)(lp + v4 * 4);
    float4 uv = *(const float4*)(up + v4 * 4);
    float z0 = lv.x - __logf(-__logf(uv.x + 1e-10f) + 1e-10f);
    float z1 = lv.y - __logf(-__logf(uv.y + 1e-10f) + 1e-10f);
    float z2 = lv.z - __logf(-__logf(uv.z + 1e-10f) + 1e-10f);
    float z3 = lv.w - __logf(-__logf(uv.w + 1e-10f) + 1e-10f);
    *(float4*)(z + v4 * 4) = make_float4(z0, z1, z2, z3);
    m = fmaxf(fmaxf(fmaxf(m, z0), fmaxf(z1, z2)), z3);
  }
#pragma unroll
  for (int msk = 1; msk < 64; msk <<= 1) m = fmaxf(m, __shfl_xor(m, msk, 64));
  if ((threadIdx.x & 63) == 0) sred[threadIdx.x >> 6] = m;
  __syncthreads();
  float M = fmaxf(fmaxf(sred[0], sred[1]), fmaxf(sred[2], sred[3]));
  float l = 0.f;
  for (int v4 = threadIdx.x; v4 < V_ / 4; v4 += 256) {
    float4 zv = *(float4*)(z + v4 * 4);
    zv.x = __expf(zv.x - M); zv.y = __expf(zv.y - M);
    zv.z = __expf(zv.z - M); zv.w = __expf(zv.w - M);
    *(float4*)(z + v4 * 4) = zv;
    l += (zv.x + zv.y) + (zv.z + zv.w);
  }
#pragma unroll
  for (int msk = 1; msk < 64; msk <<= 1) l += __shfl_xor(l, msk, 64);
  __syncthreads();
  if ((threadIdx.x & 63) == 0) sred[threadIdx.x >> 6] = l;
  __syncthreads();
  float inv = 1.f / (sred[0] + sred[1] + sred[2] + sred[3]);
  u16* gp = g + (size_t)s * V_;
  for (int v4 = threadIdx.x; v4 < V_ / 4; v4 += 256) {
    float4 zv = *(float4*)(z + v4 * 4);
    ushort4 o;
    o.x = f2bf(zv.x * inv); o.y = f2bf(zv.y * inv);
    o.z = f2bf(zv.z * inv); o.w = f2bf(zv.w * inv);
    *(ushort4*)(gp + v4 * 4) = o;
  }
}

extern "C" void kernel_launch(void* const* d_in, const int* in_sizes, int n_in,
                              void* d_out, int out_size, void* d_ws, size_t ws_size,
                              hipStream_t stream) {
  const int*   ids        = (const int*)d_in[0];
  const float* u          = (const float*)d_in[1];
  const float* emb        = (const float*)d_in[2];
  const float* attn_scale = (const float*)d_in[3];
  const float* gu_scale   = (const float*)d_in[4];
  const float* dn_scale   = (const float*)d_in[5];
  const float* lora_A     = (const float*)d_in[6];
  const float* lora_B     = (const float*)d_in[7];
  const float* norm_w     = (const float*)d_in[8];
  const float* fnorm_w    = (const float*)d_in[9];
  const int*   attn_idx   = (const int*)d_in[10];
  const int*   gu_idx     = (const int*)d_in[11];
  const int*   dn_idx     = (const int*)d_in[12];

  float* out_se = (float*)d_out;
  float* out_lg = (float*)d_out + (size_t)S_ * D_;

  char* W = (char*)d_ws;
  float* h    = (float*)(W);
  u16*   xb   = (u16*)(W + ((size_t)16 << 20));
  u16*   qkvb = (u16*)(W + ((size_t)72 << 20));
  u16*   Vtb  = (u16*)(W + ((size_t)96 << 20));
  u16*   ob   = (u16*)(W + ((size_t)104 << 20));
  u16*   gub  = (u16*)(W + ((size_t)112 << 20));
  u16*   wdq  = (u16*)(W + ((size_t)176 << 20));
  float* Tl   = (float*)(W + ((size_t)240 << 20));
  u16*   embb = (u16*)(W);
  u16*   gsm  = (u16*)(W + ((size_t)125 << 20));
  u16*   embT = (u16*)(W);
  u16*   xbh  = (u16*)d_out;
  float* Pk   = (float*)(W + ((size_t)250 << 20));
  const bool big = ws_size >= ((size_t)314 << 20);
  const size_t ZS = (size_t)4 * 1024 * 1024;

  dim3 b256(256), b512(512);

  k_gather<<<dim3(S_ * D_ / 256), b256, 0, stream>>>(ids, emb, h);

  for (int l = 0; l < L_; ++l) {
    const int*   aidx = attn_idx + (size_t)l * 4 * D_ * D_;
    const float* ascl = attn_scale + (size_t)l * 4 * D_ * (D_ / 64);
    const float* lA   = lora_A + (size_t)l * 4 * R_ * D_;
    const float* lB   = lora_B + (size_t)l * 4 * D_ * R_;

    k_rmsnorm<<<dim3(S_), b256, 0, stream>>>(h, norm_w + (size_t)l * 2 * D_, xb);
    k_dequant<<<dim3(4 * D_ * D_ / 8 / 256), b256, 0, stream>>>(aidx, ascl, wdq, 11);
    k_gemm256<OUT_BF16><<<dim3(3 * D_ / 256, 8), b512, 0, stream>>>(
        xb, D_, wdq, D_, qkvb, 3 * D_, D_, 0);
    k_lora_down<<<dim3(S_), b256, 0, stream>>>(xb, lA, Tl, 3);
    k_lora_up_qkv<<<dim3(S_ * 3 * D_ / 8 / 256), b256, 0, stream>>>(qkvb, Tl, lB);
    k_vtrans<<<dim3(S_ / 64, H_), b256, 0, stream>>>(qkvb, Vtb);
    k_attn2<<<dim3(16, H_), b256, 0, stream>>>(qkvb, Vtb, ob);
    k_gemm256<OUT_F32_ACC><<<dim3(D_ / 256, 8), b512, 0, stream>>>(
        ob, D_, wdq + (size_t)3 * D_ * D_, D_, h, D_, D_, 0);
    k_lora_down<<<dim3(S_), b256, 0, stream>>>(ob, lA + (size_t)3 * R_ * D_, Tl, 1);
    k_lora_up<<<dim3(S_ * D_ / 256), b256, 0, stream>>>(h, D_, Tl, lB + (size_t)3 * D_ * R_, 1);

    k_rmsnorm<<<dim3(S_), b256, 0, stream>>>(h, norm_w + (size_t)l * 2 * D_ + D_, xb);
    k_dequant<<<dim3(2 * DFF_ * D_ / 8 / 256), b256, 0, stream>>>(
        gu_idx + (size_t)l * 2 * DFF_ * D_, gu_scale + (size_t)l * 2 * DFF_ * (D_ / 64), wdq, 11);
    k_gemm256<OUT_BF16><<<dim3(2 * DFF_ / 256, 8), b512, 0, stream>>>(
        xb, D_, wdq, D_, gub, 2 * DFF_, D_, 0);
    k_silumul<<<dim3(S_ * DFF_ / 4 / 256), b256, 0, stream>>>(gub);
    k_dequant<<<dim3(D_ * DFF_ / 8 / 256), b256, 0, stream>>>(
        dn_idx + (size_t)l * D_ * DFF_, dn_scale + (size_t)l * D_ * (DFF_ / 64), wdq, 13);
    if (big) {
      k_gemm256<OUT_F32><<<dim3(D_ / 256, 8, 4), b512, 0, stream>>>(
          gub, 2 * DFF_, wdq, DFF_, Pk, D_, DFF_ / 4, ZS);
      k_red<<<dim3(4096), b256, 0, stream>>>(Pk, h, 1);
    } else {
      k_gemm256<OUT_F32_ACC><<<dim3(D_ / 256, 8), b512, 0, stream>>>(
          gub, 2 * DFF_, wdq, DFF_, h, D_, DFF_, 0);
    }
  }

  k_rmsnorm<<<dim3(S_), b256, 0, stream>>>(h, fnorm_w, xbh);
  k_f2b<<<dim3(V_ * D_ / 8 / 256), b256, 0, stream>>>(emb, embb);
  k_gemm256<OUT_F32><<<dim3(V_ / 256, 8), b512, 0, stream>>>(
      xbh, D_, embb, D_, out_lg, V_, D_, 0);
  k_gumbel<<<dim3(S_), b256, 0, stream>>>(out_lg, u, gsm);
  k_transpose<<<dim3(V_ / 64, D_ / 64), b256, 0, stream>>>(emb, embT);
  if (big) {
    k_gemm256<OUT_F32><<<dim3(D_ / 256, 8, 4), b512, 0, stream>>>(
        gsm, V_, embT, V_, Pk, D_, V_ / 4, ZS);
    k_red<<<dim3(4096), b256, 0, stream>>>(Pk, out_se, 0);
  } else {
    k_gemm256<OUT_F32><<<dim3(D_ / 256, 8), b512, 0, stream>>>(
        gsm, V_, embT, V_, out_se, D_, V_, 0);
  }
}

// Round 12
// 2390.497 us; speedup vs baseline: 7.2559x; 1.0216x over previous
//
#include <hip/hip_runtime.h>
#include <hip/hip_bf16.h>

typedef unsigned short u16;
typedef unsigned int u32;
typedef __bf16 bf16t;
typedef bf16t bf16x8 __attribute__((ext_vector_type(8)));
typedef float f32x4 __attribute__((ext_vector_type(4)));

constexpr int S_   = 2048;
constexpr int D_   = 2048;
constexpr int H_   = 16;
constexpr int DH_  = 128;
constexpr int L_   = 2;
constexpr int DFF_ = 8192;
constexpr int V_   = 32000;
constexpr int R_   = 8;

#define MFMA16(a, b, c) __builtin_amdgcn_mfma_f32_16x16x32_bf16(a, b, c, 0, 0, 0)

__constant__ float c_nf4[16] = {
  -1.0f, -0.6961928009986877f, -0.5250730514526367f, -0.39491748809814453f,
  -0.28444138169288635f, -0.18477343022823334f, -0.09105003625154495f, 0.0f,
  0.07958029955625534f, 0.16093020141124725f, 0.24611230194568634f,
  0.33791524171829224f, 0.44070982933044434f, 0.5626170039176941f,
  0.7229568362236023f, 1.0f };

__device__ __forceinline__ u16 f2bf(float f) {
  union { float f; u32 u; } v; v.f = f;
  u32 r = v.u + 0x7fffu + ((v.u >> 16) & 1u);
  return (u16)(r >> 16);
}
__device__ __forceinline__ float bf2f(u16 h) {
  union { u32 u; float f; } v; v.u = ((u32)h) << 16; return v.f;
}

// ---------------- embedding gather ----------------
__global__ __launch_bounds__(256) void k_gather(const int* __restrict__ ids,
                                                const float* __restrict__ emb,
                                                float* __restrict__ h) {
  int t = blockIdx.x * 256 + threadIdx.x;
  int s = t >> 11;
  int d = t & 2047;
  h[t] = emb[(size_t)ids[s] * D_ + d];
}

// ---------------- rmsnorm f32 -> bf16 ----------------
__global__ __launch_bounds__(256) void k_rmsnorm(const float* __restrict__ in,
                                                 const float* __restrict__ w,
                                                 u16* __restrict__ out) {
  int s = blockIdx.x;
  const float* x = in + (size_t)s * D_;
  float ss = 0.f;
  for (int d = threadIdx.x; d < D_; d += 256) { float v = x[d]; ss += v * v; }
#pragma unroll
  for (int m = 1; m < 64; m <<= 1) ss += __shfl_xor(ss, m, 64);
  __shared__ float sh[4];
  if ((threadIdx.x & 63) == 0) sh[threadIdx.x >> 6] = ss;
  __syncthreads();
  ss = sh[0] + sh[1] + sh[2] + sh[3];
  float sc = rsqrtf(ss * (1.0f / D_) + 1e-6f);
  u16* o = out + (size_t)s * D_;
  for (int d = threadIdx.x; d < D_; d += 256) o[d] = f2bf(x[d] * sc * w[d]);
}

// ---------------- NF4 dequant ----------------
__global__ __launch_bounds__(256) void k_dequant(const int* __restrict__ idx,
                                                 const float* __restrict__ scale,
                                                 u16* __restrict__ out, int kshift) {
  size_t t = (size_t)blockIdx.x * 256 + threadIdx.x;
  size_t e = t * 8;
  int k = (int)(e & ((1u << kshift) - 1));
  size_t n = e >> kshift;
  float s = scale[(n << (kshift - 6)) + (k >> 6)];
  int4 i0 = *(const int4*)(idx + e);
  int4 i1 = *(const int4*)(idx + e + 4);
  uint4 o;
  o.x = (u32)f2bf(c_nf4[i0.x] * s) | ((u32)f2bf(c_nf4[i0.y] * s) << 16);
  o.y = (u32)f2bf(c_nf4[i0.z] * s) | ((u32)f2bf(c_nf4[i0.w] * s) << 16);
  o.z = (u32)f2bf(c_nf4[i1.x] * s) | ((u32)f2bf(c_nf4[i1.y] * s) << 16);
  o.w = (u32)f2bf(c_nf4[i1.z] * s) | ((u32)f2bf(c_nf4[i1.w] * s) << 16);
  *(uint4*)(out + e) = o;
}

// ---- fused emb prep: ONE read of emb f32 [V,D] -> embb bf16 [V,D] + embT bf16 [D,V] ----
__global__ __launch_bounds__(256) void k_embprep(const float* __restrict__ src,
                                                 u16* __restrict__ embb,
                                                 u16* __restrict__ embT) {
  __shared__ u16 tile[64][65];
  int v0 = blockIdx.x * 64, d0 = blockIdx.y * 64;
  int tid = threadIdx.x;
  int rr = tid >> 4, cc = (tid & 15) * 4;
#pragma unroll
  for (int j = 0; j < 4; ++j) {
    int r = j * 16 + rr;
    float4 f = *(const float4*)(src + (size_t)(v0 + r) * D_ + d0 + cc);
    u16 b0 = f2bf(f.x), b1 = f2bf(f.y), b2 = f2bf(f.z), b3 = f2bf(f.w);
    tile[r][cc + 0] = b0; tile[r][cc + 1] = b1;
    tile[r][cc + 2] = b2; tile[r][cc + 3] = b3;
    ushort4 wv; wv.x = b0; wv.y = b1; wv.z = b2; wv.w = b3;
    *(ushort4*)(embb + (size_t)(v0 + r) * D_ + d0 + cc) = wv;
  }
  __syncthreads();
#pragma unroll
  for (int j = 0; j < 4; ++j) {
    int r = j * 16 + rr;            // d-local
    ushort4 w;
    w.x = tile[cc + 0][r]; w.y = tile[cc + 1][r];
    w.z = tile[cc + 2][r]; w.w = tile[cc + 3][r];
    *(ushort4*)(embT + (size_t)(d0 + r) * V_ + v0 + cc) = w;
  }
}

// ======== 256x256 MFMA GEMM, fine-interleaved schedule (race-fixed) ========
// 512 thr = 8 waves (2M x 4N), BK=64, LDS 128 KiB double-buffered.
// KEY FIX vs round-10: output quadrants remapped to CONTIGUOUS row-halves
//   row = QR*128 + wr*64 + m*16 ; col = QC*128 + wc*32 + n*16
// so LOADA(0)/LOADB(0) read exactly rows 0-127 and LOADA(1)/LOADB(1) rows
// 128-255 -> staged halves == read-quadrant regions, no overlap races.
// Schedule per tile: p1{rdA0,B0; stg(t+1).A1; Q00} p2{rdB1; stg(t+2).B0; Q01}
// p3{rdA1; stg(t+2).A0; Q11} p4{stg(t+2).B1; Q10; vmcnt(6); bar}.
// FIFO: incoming 6 ((t+1).B0/A0/B1) + 8 issued, vmcnt(6) completes oldest 8
// = ALL of tile t+1. Tails: t+2>=NT -> vmcnt(0).
enum { OUT_F32 = 0, OUT_F32_ACC = 1, OUT_BF16 = 2 };

template<int OUTMODE>
__global__ __launch_bounds__(512, 2) void k_gemm256(const u16* __restrict__ A, int lda,
                                                    const u16* __restrict__ B, int ldb,
                                                    void* __restrict__ Cv, int ldc,
                                                    int Kc, size_t zstride) {
  __shared__ u16 As[2][256][64];
  __shared__ u16 Bs[2][256][64];
  const int tid = threadIdx.x;
  const int lane = tid & 63, w = tid >> 6;
  const int wr = w >> 2, wc = w & 3;
  const int g = (lane >> 4), l15 = lane & 15, sl7 = lane & 7;

  // XCD swizzle, N-major within chunk
  const int gx = gridDim.x, gy = gridDim.y;
  const int cpx = (gx * gy) >> 3;
  int d = blockIdx.y * gx + blockIdx.x;
  int swz = (d & 7) * cpx + (d >> 3);
  const int m0 = (swz % gy) * 256;
  const int n0 = (swz / gy) * 256;

  A += (size_t)blockIdx.z * Kc;
  B += (size_t)blockIdx.z * Kc;
  float* Cf = (float*)Cv + (size_t)blockIdx.z * zstride;

  const int NT = Kc >> 6;
  const int srow = w * 8 + (lane >> 3);
  const int sch  = (lane & 7) ^ (lane >> 3);

  auto stageA = [&](int half, int tile) {
    const u16* src = A + (size_t)(m0 + half * 128 + srow) * lda + tile * 64 + sch * 8;
    u16* dst = &As[tile & 1][half * 128 + w * 8][0];
#pragma unroll
    for (int rnd = 0; rnd < 2; ++rnd)
      __builtin_amdgcn_global_load_lds(
          (const __attribute__((address_space(1))) void*)(src + (size_t)rnd * 64 * lda),
          (__attribute__((address_space(3))) void*)(dst + rnd * 64 * 64), 16, 0, 0);
  };
  auto stageB = [&](int half, int tile) {
    const u16* src = B + (size_t)(n0 + half * 128 + srow) * ldb + tile * 64 + sch * 8;
    u16* dst = &Bs[tile & 1][half * 128 + w * 8][0];
#pragma unroll
    for (int rnd = 0; rnd < 2; ++rnd)
      __builtin_amdgcn_global_load_lds(
          (const __attribute__((address_space(1))) void*)(src + (size_t)rnd * 64 * ldb),
          (__attribute__((address_space(3))) void*)(dst + rnd * 64 * 64), 16, 0, 0);
  };

  f32x4 acc[8][4] = {};
  bf16x8 areg[4][2], breg[2][2][2];

  // prologue: tile0 full + tile1 {B0,A0,B1}; vmcnt(6) => tile0 fully landed
  stageB(0, 0); stageA(0, 0); stageB(1, 0); stageA(1, 0);
  if (NT > 1) {
    stageB(0, 1); stageA(0, 1); stageB(1, 1);
    asm volatile("s_waitcnt vmcnt(6)" ::: "memory");
  } else {
    asm volatile("s_waitcnt vmcnt(0)" ::: "memory");
  }
  __builtin_amdgcn_s_barrier();

// rows read by LOADA(QR): QR*128 + wr*64 + m*16 + l15  -> exactly rows [QR*128, QR*128+128)
#define LOADA(QR)                                                                   \
  _Pragma("unroll") for (int m = 0; m < 4; ++m)                                     \
    _Pragma("unroll") for (int kh = 0; kh < 2; ++kh) {                              \
      int hr = (QR) * 128 + wr * 64 + m * 16 + l15;                                 \
      areg[m][kh] = *(const bf16x8*)(abase + hr * 64 + ((((kh << 2) | g) ^ sl7) << 3)); \
    }
// rows read by LOADB(QC): QC*128 + wc*32 + n*16 + l15  -> exactly rows [QC*128, QC*128+128)
#define LOADB(QC)                                                                   \
  _Pragma("unroll") for (int n = 0; n < 2; ++n)                                     \
    _Pragma("unroll") for (int kh = 0; kh < 2; ++kh) {                              \
      int br = (QC) * 128 + wc * 32 + n * 16 + l15;                                 \
      breg[QC][n][kh] = *(const bf16x8*)(bbase + br * 64 + ((((kh << 2) | g) ^ sl7) << 3)); \
    }
#define QPHASE(QR, QC)                                                              \
  __builtin_amdgcn_s_setprio(1);                                                    \
  _Pragma("unroll") for (int m = 0; m < 4; ++m)                                     \
    _Pragma("unroll") for (int n = 0; n < 2; ++n)                                   \
      _Pragma("unroll") for (int kh = 0; kh < 2; ++kh)                              \
        acc[(QR) * 4 + m][(QC) * 2 + n] = __builtin_amdgcn_mfma_f32_16x16x32_bf16(  \
            areg[m][kh], breg[QC][n][kh], acc[(QR) * 4 + m][(QC) * 2 + n], 0, 0, 0); \
  __builtin_amdgcn_s_setprio(0);

  for (int t = 0; t < NT; ++t) {
    const u16* abase = &As[t & 1][0][0];
    const u16* bbase = &Bs[t & 1][0][0];
    // p1: Q00. stage (t+1).A1 -> As[(t+1)&1] rows 128-255, last read (t-1).p3.
    LOADA(0); LOADB(0);
    if (t + 1 < NT) stageA(1, t + 1);
    __builtin_amdgcn_s_barrier();
    asm volatile("s_waitcnt lgkmcnt(0)" ::: "memory");
    QPHASE(0, 0);
    __builtin_amdgcn_s_barrier();
    // p2: Q01. stage (t+2).B0 -> Bs[t&1] rows 0-127, last read t.p1 (done).
    LOADB(1);
    if (t + 2 < NT) stageB(0, t + 2);
    __builtin_amdgcn_s_barrier();
    asm volatile("s_waitcnt lgkmcnt(0)" ::: "memory");
    QPHASE(0, 1);
    __builtin_amdgcn_s_barrier();
    // p3: Q11. stage (t+2).A0 -> As[t&1] rows 0-127, last read t.p1.
    LOADA(1);
    if (t + 2 < NT) stageA(0, t + 2);
    __builtin_amdgcn_s_barrier();
    asm volatile("s_waitcnt lgkmcnt(0)" ::: "memory");
    QPHASE(1, 1);
    __builtin_amdgcn_s_barrier();
    // p4: Q10 (regs only). stage (t+2).B1 -> Bs[t&1] rows 128-255, last read t.p2.
    if (t + 2 < NT) stageB(1, t + 2);
    QPHASE(1, 0);
    if (t + 1 < NT) {
      if (t + 2 < NT) asm volatile("s_waitcnt vmcnt(6)" ::: "memory");
      else            asm volatile("s_waitcnt vmcnt(0)" ::: "memory");
    }
    __builtin_amdgcn_s_barrier();
  }
#undef LOADA
#undef LOADB
#undef QPHASE

  const int er = g * 4;
#pragma unroll
  for (int i = 0; i < 8; ++i)
#pragma unroll
    for (int j = 0; j < 4; ++j)
#pragma unroll
      for (int r = 0; r < 4; ++r) {
        int row = m0 + (i >> 2) * 128 + wr * 64 + (i & 3) * 16 + er + r;
        int col = n0 + (j >> 1) * 128 + wc * 32 + (j & 1) * 16 + l15;
        if (OUTMODE == OUT_BF16) {
          ((u16*)Cv)[(size_t)row * ldc + col] = f2bf(acc[i][j][r]);
        } else if (OUTMODE == OUT_F32_ACC) {
          Cf[(size_t)row * ldc + col] += acc[i][j][r];
        } else {
          Cf[(size_t)row * ldc + col] = acc[i][j][r];
        }
      }
}

// ---------------- split-K reduce ----------------
__global__ __launch_bounds__(256) void k_red(const float* __restrict__ P,
                                             float* __restrict__ dst, int accmode) {
  size_t i = ((size_t)blockIdx.x * 256 + threadIdx.x) * 4;
  const size_t n = (size_t)4 * 1024 * 1024;
  float4 a = *(const float4*)(P + i);
  float4 b = *(const float4*)(P + n + i);
  float4 c = *(const float4*)(P + 2 * n + i);
  float4 d = *(const float4*)(P + 3 * n + i);
  float4 r;
  r.x = (a.x + b.x) + (c.x + d.x);
  r.y = (a.y + b.y) + (c.y + d.y);
  r.z = (a.z + b.z) + (c.z + d.z);
  r.w = (a.w + b.w) + (c.w + d.w);
  if (accmode) {
    float4 o = *(const float4*)(dst + i);
    r.x += o.x; r.y += o.y; r.z += o.z; r.w += o.w;
  }
  *(float4*)(dst + i) = r;
}

// ---------------- LoRA ----------------
__global__ __launch_bounds__(256) void k_lora_down(const u16* __restrict__ X,
                                                   const float* __restrict__ A,
                                                   float* __restrict__ T, int nproj) {
  int s = blockIdx.x;
  int lane = threadIdx.x & 63, wv = threadIdx.x >> 6;
  const u16* x = X + (size_t)s * D_;
  for (int p = wv; p < nproj * R_; p += 4) {
    const float* a = A + (size_t)p * D_;
    float sum = 0.f;
    for (int d = lane; d < D_; d += 64) sum += bf2f(x[d]) * a[d];
#pragma unroll
    for (int m = 1; m < 64; m <<= 1) sum += __shfl_xor(sum, m, 64);
    if (lane == 0) T[(size_t)s * (nproj * R_) + p] = sum;
  }
}

__global__ __launch_bounds__(256) void k_lora_up(float* __restrict__ Y, int ystride,
                                                 const float* __restrict__ T,
                                                 const float* __restrict__ Bm, int nproj) {
  int t = blockIdx.x * 256 + threadIdx.x;
  int d = t & (D_ - 1);
  int si = t >> 11;
  int i = si % nproj;
  int s = si / nproj;
  const float* tp = T + ((size_t)s * nproj + i) * R_;
  const float* bp = Bm + ((size_t)i * D_ + d) * R_;
  float acc = 0.f;
#pragma unroll
  for (int r = 0; r < R_; r++) acc += tp[r] * bp[r];
  Y[(size_t)s * ystride + (size_t)i * D_ + d] += 2.0f * acc;
}

// ---- LoRA-up for qkv, bf16 in-place ----
__global__ __launch_bounds__(256) void k_lora_up_qkv(u16* __restrict__ qkvb,
                                                     const float* __restrict__ T,
                                                     const float* __restrict__ Bm) {
  size_t t = ((size_t)blockIdx.x * 256 + threadIdx.x) * 8;
  int c = (int)(t % 6144);
  int s = (int)(t / 6144);
  int i = c >> 11, dd = c & 2047;
  const float* tp = T + ((size_t)s * 3 + i) * R_;
  float tr[8];
#pragma unroll
  for (int r = 0; r < R_; ++r) tr[r] = tp[r];
  uint4 q = *(const uint4*)(qkvb + t);
  u16 qs[8] = {(u16)(q.x & 0xffff), (u16)(q.x >> 16), (u16)(q.y & 0xffff), (u16)(q.y >> 16),
               (u16)(q.z & 0xffff), (u16)(q.z >> 16), (u16)(q.w & 0xffff), (u16)(q.w >> 16)};
  u16 os[8];
#pragma unroll
  for (int j = 0; j < 8; ++j) {
    const float* bp = Bm + ((size_t)i * D_ + dd + j) * R_;
    float a = 0.f;
#pragma unroll
    for (int r = 0; r < R_; ++r) a += tr[r] * bp[r];
    os[j] = f2bf(bf2f(qs[j]) + 2.0f * a);
  }
  uint4 o;
  o.x = (u32)os[0] | ((u32)os[1] << 16);
  o.y = (u32)os[2] | ((u32)os[3] << 16);
  o.z = (u32)os[4] | ((u32)os[5] << 16);
  o.w = (u32)os[6] | ((u32)os[7] << 16);
  *(uint4*)(qkvb + t) = o;
}

// ---- per-head V transpose ----
__global__ __launch_bounds__(256) void k_vtrans(const u16* __restrict__ qkvb,
                                                u16* __restrict__ Vt) {
  __shared__ u16 t[64][136];
  int s0 = blockIdx.x * 64, hh = blockIdx.y;
  int tid = threadIdx.x;
#pragma unroll
  for (int it = 0; it < 4; ++it) {
    int e = it * 2048 + tid * 8;
    int sr = e >> 7, sc = e & 127;
    *(uint4*)&t[sr][sc] =
        *(const uint4*)(qkvb + (size_t)(s0 + sr) * 6144 + 4096 + hh * 128 + sc);
  }
  __syncthreads();
#pragma unroll
  for (int it = 0; it < 4; ++it) {
    int q = it * 256 + tid;
    int dh = q >> 3, sc = (q & 7) * 8;
    u16 e0 = t[sc + 0][dh], e1 = t[sc + 1][dh], e2 = t[sc + 2][dh], e3 = t[sc + 3][dh];
    u16 e4 = t[sc + 4][dh], e5 = t[sc + 5][dh], e6 = t[sc + 6][dh], e7 = t[sc + 7][dh];
    uint4 o;
    o.x = (u32)e0 | ((u32)e1 << 16);
    o.y = (u32)e2 | ((u32)e3 << 16);
    o.z = (u32)e4 | ((u32)e5 << 16);
    o.w = (u32)e6 | ((u32)e7 << 16);
    *(uint4*)(Vt + ((size_t)hh * DH_ + dh) * S_ + s0 + sc) = o;
  }
}

// ======== MFMA flash attention v2 ========
__global__ __launch_bounds__(256) void k_attn2(const u16* __restrict__ qkvb,
                                               const u16* __restrict__ Vt,
                                               u16* __restrict__ out) {
  __shared__ u16 Ks[2][64 * 128];
  __shared__ u16 VTs[2][128 * 64];
  __shared__ u16 PT[4][64 * 16];
  const int tid = threadIdx.x;
  const int lane = tid & 63, w = tid >> 6;
  const int g = lane >> 4, l4 = lane & 15;
  const int p = blockIdx.x;
  const int hh = blockIdx.y;
  const int ld = 6144;
  const float rs = 0.08838834764831845f;
  const int qa0 = p * 64, qb0 = (31 - p) * 64;
  const int ntb = 32 - p;
  char* pt_w = (char*)&PT[w][0];

  const int qga = qa0 + w * 16 + l4;
  const int qgb = qb0 + w * 16 + l4;

  bf16x8 qfa[4], qfb[4];
#pragma unroll
  for (int kh = 0; kh < 4; ++kh) {
    qfa[kh] = *(const bf16x8*)(qkvb + (size_t)qga * ld + hh * DH_ + kh * 32 + g * 8);
    qfb[kh] = *(const bf16x8*)(qkvb + (size_t)qgb * ld + hh * DH_ + kh * 32 + g * 8);
  }

  float ma = -3.0e38f, la = 0.f, mb = -3.0e38f, lb = 0.f;
  f32x4 acc_a[8] = {}, acc_b[8] = {};
  bf16x8 pba[2], pbb[2];

  auto stage = [&](int buf, int kt) {
    const int kv0 = kt * 64;
#pragma unroll
    for (int i = 0; i < 4; ++i) {
      int rl = (w * 4 + i) * 4 + (lane >> 4);
      int cs = (lane & 15) ^ ((rl & 7) ^ (((rl >> 3) & 3) << 1));
      __builtin_amdgcn_global_load_lds(
          (const __attribute__((address_space(1))) void*)(
              qkvb + (size_t)(kv0 + rl) * ld + 2048 + hh * DH_ + cs * 8),
          (__attribute__((address_space(3))) void*)(&Ks[buf][(w * 4 + i) * 512]), 16, 0, 0);
    }
#pragma unroll
    for (int i = 0; i < 4; ++i) {
      int dh = (w * 4 + i) * 8 + (lane >> 3);
      int cs = (lane & 7) ^ (dh & 7);
      __builtin_amdgcn_global_load_lds(
          (const __attribute__((address_space(1))) void*)(
              Vt + ((size_t)hh * DH_ + dh) * S_ + kv0 + cs * 8),
          (__attribute__((address_space(3))) void*)(&VTs[buf][(w * 4 + i) * 512]), 16, 0, 0);
    }
  };

  auto softpb = [&](f32x4* sv, float& m, float& l, f32x4* acc, int qg, bool diag,
                    int kv0, bf16x8* pb) {
    float pv[16];
    float tmax = -3.0e38f;
#pragma unroll
    for (int kb = 0; kb < 4; ++kb)
#pragma unroll
      for (int r = 0; r < 4; ++r) {
        float s = sv[kb][r] * rs;
        if (diag) {
          int kglob = kv0 + kb * 16 + g * 4 + r;
          if (kglob > qg) s = -1.0e30f;
        }
        pv[kb * 4 + r] = s;
        tmax = fmaxf(tmax, s);
      }
    tmax = fmaxf(tmax, __shfl_xor(tmax, 16, 64));
    tmax = fmaxf(tmax, __shfl_xor(tmax, 32, 64));
    float mn = fmaxf(m, tmax);
    float corr = __expf(m - mn);
    m = mn;
    float ps = 0.f;
#pragma unroll
    for (int i = 0; i < 16; ++i) { pv[i] = __expf(pv[i] - mn); ps += pv[i]; }
    ps += __shfl_xor(ps, 16, 64);
    ps += __shfl_xor(ps, 32, 64);
    l = l * corr + ps;
#pragma unroll
    for (int f = 0; f < 8; ++f) {
      acc[f][0] *= corr; acc[f][1] *= corr; acc[f][2] *= corr; acc[f][3] *= corr;
    }
#pragma unroll
    for (int kb = 0; kb < 4; ++kb)
#pragma unroll
      for (int r = 0; r < 4; ++r) {
        int key = kb * 16 + g * 4 + r;
        int byte = (key * 32 + l4 * 2) ^ (((key >> 3) & 3) << 5);
        *(u16*)(pt_w + byte) = f2bf(pv[kb * 4 + r]);
      }
#pragma unroll
    for (int ks = 0; ks < 2; ++ks) {
      union { bf16x8 v; u16 s[8]; } ub;
#pragma unroll
      for (int j = 0; j < 8; ++j) {
        int key = ks * 32 + g * 8 + j;
        int byte = (key * 32 + l4 * 2) ^ (((key >> 3) & 3) << 5);
        ub.s[j] = *(const u16*)(pt_w + byte);
      }
      pb[ks] = ub.v;
    }
  };

  stage(0, 0);
  asm volatile("s_waitcnt vmcnt(0)" ::: "memory");
  __syncthreads();

  for (int kt = 0; kt < ntb; ++kt) {
    const int kv0 = kt * 64;
    const int buf = kt & 1;
    if (kt + 1 < ntb) stage(buf ^ 1, kt + 1);

    const char* kb_base = (const char*)&Ks[buf][0];
    const char* vb_base = (const char*)&VTs[buf][0];
    const bool doa = (kt <= p);

    f32x4 sa[4] = {}, sb[4] = {};
#pragma unroll
    for (int kb = 0; kb < 4; ++kb) {
#pragma unroll
      for (int kh = 0; kh < 4; ++kh) {
        int key = kb * 16 + l4;
        int ch = (kh * 4 + g) ^ ((key & 7) ^ (((key >> 3) & 3) << 1));
        bf16x8 af = *(const bf16x8*)(kb_base + key * 256 + ch * 16);
        if (doa) sa[kb] = MFMA16(af, qfa[kh], sa[kb]);
        sb[kb] = MFMA16(af, qfb[kh], sb[kb]);
      }
    }

    if (doa) softpb(sa, ma, la, acc_a, qga, kt == p, kv0, pba);
    softpb(sb, mb, lb, acc_b, qgb, kt == ntb - 1, kv0, pbb);

#pragma unroll
    for (int f = 0; f < 8; ++f) {
#pragma unroll
      for (int ks = 0; ks < 2; ++ks) {
        int dh = f * 16 + l4;
        int ch = (ks * 4 + g) ^ (dh & 7);
        bf16x8 va = *(const bf16x8*)(vb_base + dh * 128 + ch * 16);
        if (doa) acc_a[f] = MFMA16(va, pba[ks], acc_a[f]);
        acc_b[f] = MFMA16(va, pbb[ks], acc_b[f]);
      }
    }

    if (kt + 1 < ntb) {
      asm volatile("s_waitcnt vmcnt(0)" ::: "memory");
      __syncthreads();
    }
  }

  float inva = 1.f / la, invb = 1.f / lb;
  u16* opa = out + (size_t)qga * D_ + hh * DH_;
  u16* opb = out + (size_t)qgb * D_ + hh * DH_;
#pragma unroll
  for (int f = 0; f < 8; ++f)
#pragma unroll
    for (int r = 0; r < 4; ++r) {
      opa[f * 16 + g * 4 + r] = f2bf(acc_a[f][r] * inva);
      opb[f * 16 + g * 4 + r] = f2bf(acc_b[f][r] * invb);
    }
}

// ---------------- silu(gate)*up ----------------
__global__ __launch_bounds__(256) void k_silumul(u16* __restrict__ gu) {
  size_t i = ((size_t)blockIdx.x * 256 + threadIdx.x) * 4;
  int s = (int)(i >> 13);
  int f = (int)(i & 8191);
  u16* gp = gu + (size_t)s * (2 * DFF_) + f;
  ushort4 gt = *(ushort4*)gp;
  ushort4 up = *(ushort4*)(gp + DFF_);
  float g0 = bf2f(gt.x), g1 = bf2f(gt.y), g2 = bf2f(gt.z), g3 = bf2f(gt.w);
  float u0 = bf2f(up.x), u1 = bf2f(up.y), u2 = bf2f(up.z), u3 = bf2f(up.w);
  ushort4 o;
  o.x = f2bf(g0 / (1.f + __expf(-g0)) * u0);
  o.y = f2bf(g1 / (1.f + __expf(-g1)) * u1);
  o.z = f2bf(g2 / (1.f + __expf(-g2)) * u2);
  o.w = f2bf(g3 / (1.f + __expf(-g3)) * u3);
  *(ushort4*)gp = o;
}

// ---------------- gumbel softmax, ONE-PASS ----------------
__global__ __launch_bounds__(256) void k_gumbel(const float* __restrict__ logits,
                                                const float* __restrict__ u,
                                                u16* __restrict__ g) {
  __shared__ float z[V_];
  __shared__ float sred[4];
  int s = blockIdx.x;
  const float* lp = logits + (size_t)s * V_;
  const float* up = u + (size_t)s * V_;
  float m = -3.0e38f;
  for (int v4 = threadIdx.x; v4 < V_ / 4; v4 += 256) {
    float4 lv = *(const float4*)(lp + v4 * 4);
    float4 uv = *(const float4*)(up + v4 * 4);
    float z0 = lv.x - __logf(-__logf(uv.x + 1e-10f) + 1e-10f);
    float z1 = lv.y - __logf(-__logf(uv.y + 1e-10f) + 1e-10f);
    float z2 = lv.z - __logf(-__logf(uv.z + 1e-10f) + 1e-10f);
    float z3 = lv.w - __logf(-__logf(uv.w + 1e-10f) + 1e-10f);
    *(float4*)(z + v4 * 4) = make_float4(z0, z1, z2, z3);
    m = fmaxf(fmaxf(fmaxf(m, z0), fmaxf(z1, z2)), z3);
  }
#pragma unroll
  for (int msk = 1; msk < 64; msk <<= 1) m = fmaxf(m, __shfl_xor(m, msk, 64));
  if ((threadIdx.x & 63) == 0) sred[threadIdx.x >> 6] = m;
  __syncthreads();
  float M = fmaxf(fmaxf(sred[0], sred[1]), fmaxf(sred[2], sred[3]));
  float l = 0.f;
  for (int v4 = threadIdx.x; v4 < V_ / 4; v4 += 256) {
    float4 zv = *(float4*)(z + v4 * 4);
    zv.x = __expf(zv.x - M); zv.y = __expf(zv.y - M);
    zv.z = __expf(zv.z - M); zv.w = __expf(zv.w - M);
    *(float4*)(z + v4 * 4) = zv;
    l += (zv.x + zv.y) + (zv.z + zv.w);
  }
#pragma unroll
  for (int msk = 1; msk < 64; msk <<= 1) l += __shfl_xor(l, msk, 64);
  __syncthreads();
  if ((threadIdx.x & 63) == 0) sred[threadIdx.x >> 6] = l;
  __syncthreads();
  float inv = 1.f / (sred[0] + sred[1] + sred[2] + sred[3]);
  u16* gp = g + (size_t)s * V_;
  for (int v4 = threadIdx.x; v4 < V_ / 4; v4 += 256) {
    float4 zv = *(float4*)(z + v4 * 4);
    ushort4 o;
    o.x = f2bf(zv.x * inv); o.y = f2bf(zv.y * inv);
    o.z = f2bf(zv.z * inv); o.w = f2bf(zv.w * inv);
    *(ushort4*)(gp + v4 * 4) = o;
  }
}

extern "C" void kernel_launch(void* const* d_in, const int* in_sizes, int n_in,
                              void* d_out, int out_size, void* d_ws, size_t ws_size,
                              hipStream_t stream) {
  const int*   ids        = (const int*)d_in[0];
  const float* u          = (const float*)d_in[1];
  const float* emb        = (const float*)d_in[2];
  const float* attn_scale = (const float*)d_in[3];
  const float* gu_scale   = (const float*)d_in[4];
  const float* dn_scale   = (const float*)d_in[5];
  const float* lora_A     = (const float*)d_in[6];
  const float* lora_B     = (const float*)d_in[7];
  const float* norm_w     = (const float*)d_in[8];
  const float* fnorm_w    = (const float*)d_in[9];
  const int*   attn_idx   = (const int*)d_in[10];
  const int*   gu_idx     = (const int*)d_in[11];
  const int*   dn_idx     = (const int*)d_in[12];

  float* out_se = (float*)d_out;
  float* out_lg = (float*)d_out + (size_t)S_ * D_;

  char* W = (char*)d_ws;
  float* h    = (float*)(W);                          // 16 MiB (layer phase)
  u16*   xb   = (u16*)(W + ((size_t)16 << 20));       // 8 MiB
  u16*   qkvb = (u16*)(W + ((size_t)72 << 20));       // 24 MiB
  u16*   Vtb  = (u16*)(W + ((size_t)96 << 20));       // 8 MiB
  u16*   ob   = (u16*)(W + ((size_t)104 << 20));      // 8 MiB
  u16*   gub  = (u16*)(W + ((size_t)112 << 20));      // 64 MiB
  u16*   wdq  = (u16*)(W + ((size_t)176 << 20));      // 64 MiB
  float* Tl   = (float*)(W + ((size_t)240 << 20));    // 192 KiB
  // head phase: embb dies after logits; gsm overwrites it; embT lives at W[125,250)
  u16*   embb = (u16*)(W);                            // 125 MiB
  u16*   gsm  = (u16*)(W);                            // 125 MiB (after logits GEMM)
  u16*   embT = (u16*)(W + ((size_t)125 << 20));      // 125 MiB
  u16*   xbh  = (u16*)d_out;                          // final-norm out, parked in out_se
  float* Pk   = (float*)(W + ((size_t)250 << 20));    // 64 MiB split-K partials
  const bool big = ws_size >= ((size_t)314 << 20);
  const size_t ZS = (size_t)4 * 1024 * 1024;

  dim3 b256(256), b512(512);

  k_gather<<<dim3(S_ * D_ / 256), b256, 0, stream>>>(ids, emb, h);

  for (int l = 0; l < L_; ++l) {
    const int*   aidx = attn_idx + (size_t)l * 4 * D_ * D_;
    const float* ascl = attn_scale + (size_t)l * 4 * D_ * (D_ / 64);
    const float* lA   = lora_A + (size_t)l * 4 * R_ * D_;
    const float* lB   = lora_B + (size_t)l * 4 * D_ * R_;

    k_rmsnorm<<<dim3(S_), b256, 0, stream>>>(h, norm_w + (size_t)l * 2 * D_, xb);
    k_dequant<<<dim3(4 * D_ * D_ / 8 / 256), b256, 0, stream>>>(aidx, ascl, wdq, 11);
    k_gemm256<OUT_BF16><<<dim3(3 * D_ / 256, 8), b512, 0, stream>>>(
        xb, D_, wdq, D_, qkvb, 3 * D_, D_, 0);
    k_lora_down<<<dim3(S_), b256, 0, stream>>>(xb, lA, Tl, 3);
    k_lora_up_qkv<<<dim3(S_ * 3 * D_ / 8 / 256), b256, 0, stream>>>(qkvb, Tl, lB);
    k_vtrans<<<dim3(S_ / 64, H_), b256, 0, stream>>>(qkvb, Vtb);
    k_attn2<<<dim3(16, H_), b256, 0, stream>>>(qkvb, Vtb, ob);
    if (big) {
      k_gemm256<OUT_F32><<<dim3(D_ / 256, 8, 4), b512, 0, stream>>>(
          ob, D_, wdq + (size_t)3 * D_ * D_, D_, Pk, D_, D_ / 4, ZS);
      k_red<<<dim3(4096), b256, 0, stream>>>(Pk, h, 1);
    } else {
      k_gemm256<OUT_F32_ACC><<<dim3(D_ / 256, 8), b512, 0, stream>>>(
          ob, D_, wdq + (size_t)3 * D_ * D_, D_, h, D_, D_, 0);
    }
    k_lora_down<<<dim3(S_), b256, 0, stream>>>(ob, lA + (size_t)3 * R_ * D_, Tl, 1);
    k_lora_up<<<dim3(S_ * D_ / 256), b256, 0, stream>>>(h, D_, Tl, lB + (size_t)3 * D_ * R_, 1);

    k_rmsnorm<<<dim3(S_), b256, 0, stream>>>(h, norm_w + (size_t)l * 2 * D_ + D_, xb);
    k_dequant<<<dim3(2 * DFF_ * D_ / 8 / 256), b256, 0, stream>>>(
        gu_idx + (size_t)l * 2 * DFF_ * D_, gu_scale + (size_t)l * 2 * DFF_ * (D_ / 64), wdq, 11);
    k_gemm256<OUT_BF16><<<dim3(2 * DFF_ / 256, 8), b512, 0, stream>>>(
        xb, D_, wdq, D_, gub, 2 * DFF_, D_, 0);
    k_silumul<<<dim3(S_ * DFF_ / 4 / 256), b256, 0, stream>>>(gub);
    k_dequant<<<dim3(D_ * DFF_ / 8 / 256), b256, 0, stream>>>(
        dn_idx + (size_t)l * D_ * DFF_, dn_scale + (size_t)l * D_ * (DFF_ / 64), wdq, 13);
    if (big) {
      k_gemm256<OUT_F32><<<dim3(D_ / 256, 8, 4), b512, 0, stream>>>(
          gub, 2 * DFF_, wdq, DFF_, Pk, D_, DFF_ / 4, ZS);
      k_red<<<dim3(4096), b256, 0, stream>>>(Pk, h, 1);
    } else {
      k_gemm256<OUT_F32_ACC><<<dim3(D_ / 256, 8), b512, 0, stream>>>(
          gub, 2 * DFF_, wdq, DFF_, h, D_, DFF_, 0);
    }
  }

  // ---- head ----
  k_rmsnorm<<<dim3(S_), b256, 0, stream>>>(h, fnorm_w, xbh);   // h read before embprep clobbers W[0,..)
  k_embprep<<<dim3(V_ / 64, D_ / 64), b256, 0, stream>>>(emb, embb, embT);
  k_gemm256<OUT_F32><<<dim3(V_ / 256, 8), b512, 0, stream>>>(
      xbh, D_, embb, D_, out_lg, V_, D_, 0);
  k_gumbel<<<dim3(S_), b256, 0, stream>>>(out_lg, u, gsm);     // overwrites dead embb region
  if (big) {
    k_gemm256<OUT_F32><<<dim3(D_ / 256, 8, 4), b512, 0, stream>>>(
        gsm, V_, embT, V_, Pk, D_, V_ / 4, ZS);
    k_red<<<dim3(4096), b256, 0, stream>>>(Pk, out_se, 0);
  } else {
    k_gemm256<OUT_F32><<<dim3(D_ / 256, 8), b512, 0, stream>>>(
        gsm, V_, embT, V_, out_se, D_, V_, 0);
  }
}

// Round 13
// 2346.168 us; speedup vs baseline: 7.3930x; 1.0189x over previous
//
#include <hip/hip_runtime.h>
#include <hip/hip_bf16.h>

typedef unsigned short u16;
typedef unsigned int u32;
typedef __bf16 bf16t;
typedef bf16t bf16x8 __attribute__((ext_vector_type(8)));
typedef float f32x4 __attribute__((ext_vector_type(4)));

constexpr int S_   = 2048;
constexpr int D_   = 2048;
constexpr int H_   = 16;
constexpr int DH_  = 128;
constexpr int L_   = 2;
constexpr int DFF_ = 8192;
constexpr int V_   = 32000;
constexpr int R_   = 8;

#define MFMA16(a, b, c) __builtin_amdgcn_mfma_f32_16x16x32_bf16(a, b, c, 0, 0, 0)

__constant__ float c_nf4[16] = {
  -1.0f, -0.6961928009986877f, -0.5250730514526367f, -0.39491748809814453f,
  -0.28444138169288635f, -0.18477343022823334f, -0.09105003625154495f, 0.0f,
  0.07958029955625534f, 0.16093020141124725f, 0.24611230194568634f,
  0.33791524171829224f, 0.44070982933044434f, 0.5626170039176941f,
  0.7229568362236023f, 1.0f };

__device__ __forceinline__ u16 f2bf(float f) {
  union { float f; u32 u; } v; v.f = f;
  u32 r = v.u + 0x7fffu + ((v.u >> 16) & 1u);
  return (u16)(r >> 16);
}
__device__ __forceinline__ float bf2f(u16 h) {
  union { u32 u; float f; } v; v.u = ((u32)h) << 16; return v.f;
}

// ---------------- embedding gather ----------------
__global__ __launch_bounds__(256) void k_gather(const int* __restrict__ ids,
                                                const float* __restrict__ emb,
                                                float* __restrict__ h) {
  int t = blockIdx.x * 256 + threadIdx.x;
  int s = t >> 11;
  int d = t & 2047;
  h[t] = emb[(size_t)ids[s] * D_ + d];
}

// ---------------- rmsnorm f32 -> bf16 ----------------
__global__ __launch_bounds__(256) void k_rmsnorm(const float* __restrict__ in,
                                                 const float* __restrict__ w,
                                                 u16* __restrict__ out) {
  int s = blockIdx.x;
  const float* x = in + (size_t)s * D_;
  float ss = 0.f;
  for (int d = threadIdx.x; d < D_; d += 256) { float v = x[d]; ss += v * v; }
#pragma unroll
  for (int m = 1; m < 64; m <<= 1) ss += __shfl_xor(ss, m, 64);
  __shared__ float sh[4];
  if ((threadIdx.x & 63) == 0) sh[threadIdx.x >> 6] = ss;
  __syncthreads();
  ss = sh[0] + sh[1] + sh[2] + sh[3];
  float sc = rsqrtf(ss * (1.0f / D_) + 1e-6f);
  u16* o = out + (size_t)s * D_;
  for (int d = threadIdx.x; d < D_; d += 256) o[d] = f2bf(x[d] * sc * w[d]);
}

// ---------------- NF4 dequant ----------------
__global__ __launch_bounds__(256) void k_dequant(const int* __restrict__ idx,
                                                 const float* __restrict__ scale,
                                                 u16* __restrict__ out, int kshift) {
  size_t t = (size_t)blockIdx.x * 256 + threadIdx.x;
  size_t e = t * 8;
  int k = (int)(e & ((1u << kshift) - 1));
  size_t n = e >> kshift;
  float s = scale[(n << (kshift - 6)) + (k >> 6)];
  int4 i0 = *(const int4*)(idx + e);
  int4 i1 = *(const int4*)(idx + e + 4);
  uint4 o;
  o.x = (u32)f2bf(c_nf4[i0.x] * s) | ((u32)f2bf(c_nf4[i0.y] * s) << 16);
  o.y = (u32)f2bf(c_nf4[i0.z] * s) | ((u32)f2bf(c_nf4[i0.w] * s) << 16);
  o.z = (u32)f2bf(c_nf4[i1.x] * s) | ((u32)f2bf(c_nf4[i1.y] * s) << 16);
  o.w = (u32)f2bf(c_nf4[i1.z] * s) | ((u32)f2bf(c_nf4[i1.w] * s) << 16);
  *(uint4*)(out + e) = o;
}

// ---- fused emb prep: ONE read of emb f32 [V,D] -> embb bf16 [V,D] + embT bf16 [D,V] ----
__global__ __launch_bounds__(256) void k_embprep(const float* __restrict__ src,
                                                 u16* __restrict__ embb,
                                                 u16* __restrict__ embT) {
  __shared__ u16 tile[64][65];
  int v0 = blockIdx.x * 64, d0 = blockIdx.y * 64;
  int tid = threadIdx.x;
  int rr = tid >> 4, cc = (tid & 15) * 4;
#pragma unroll
  for (int j = 0; j < 4; ++j) {
    int r = j * 16 + rr;
    float4 f = *(const float4*)(src + (size_t)(v0 + r) * D_ + d0 + cc);
    u16 b0 = f2bf(f.x), b1 = f2bf(f.y), b2 = f2bf(f.z), b3 = f2bf(f.w);
    tile[r][cc + 0] = b0; tile[r][cc + 1] = b1;
    tile[r][cc + 2] = b2; tile[r][cc + 3] = b3;
    ushort4 wv; wv.x = b0; wv.y = b1; wv.z = b2; wv.w = b3;
    *(ushort4*)(embb + (size_t)(v0 + r) * D_ + d0 + cc) = wv;
  }
  __syncthreads();
#pragma unroll
  for (int j = 0; j < 4; ++j) {
    int r = j * 16 + rr;            // d-local
    ushort4 w;
    w.x = tile[cc + 0][r]; w.y = tile[cc + 1][r];
    w.z = tile[cc + 2][r]; w.w = tile[cc + 3][r];
    *(ushort4*)(embT + (size_t)(d0 + r) * V_ + v0 + cc) = w;
  }
}

// ======== 256x256 pipelined MFMA GEMM (round-9 schedule, measured-best) ========
// 512 thr = 8 waves (2M x 4N), BK=64, LDS 128 KiB double-buffered.
// Burst staging: tile t+2's B halves at p3, A halves at p4; boundary vmcnt(8).
enum { OUT_F32 = 0, OUT_F32_ACC = 1, OUT_BF16 = 2 };

template<int OUTMODE>
__global__ __launch_bounds__(512, 2) void k_gemm256(const u16* __restrict__ A, int lda,
                                                    const u16* __restrict__ B, int ldb,
                                                    void* __restrict__ Cv, int ldc,
                                                    int Kc, size_t zstride) {
  __shared__ u16 As[2][256][64];
  __shared__ u16 Bs[2][256][64];
  const int tid = threadIdx.x;
  const int lane = tid & 63, w = tid >> 6;
  const int wr = w >> 2, wc = w & 3;
  const int g = (lane >> 4), l15 = lane & 15, sl7 = lane & 7;

  // XCD swizzle, N-major within chunk
  const int gx = gridDim.x, gy = gridDim.y;
  const int cpx = (gx * gy) >> 3;
  int d = blockIdx.y * gx + blockIdx.x;
  int swz = (d & 7) * cpx + (d >> 3);
  const int m0 = (swz % gy) * 256;
  const int n0 = (swz / gy) * 256;

  A += (size_t)blockIdx.z * Kc;
  B += (size_t)blockIdx.z * Kc;
  float* Cf = (float*)Cv + (size_t)blockIdx.z * zstride;

  const int NT = Kc >> 6;
  const int srow = w * 8 + (lane >> 3);
  const int sch  = (lane & 7) ^ (lane >> 3);

  auto stageA = [&](int half, int tile) {
    const u16* src = A + (size_t)(m0 + half * 128 + srow) * lda + tile * 64 + sch * 8;
    u16* dst = &As[tile & 1][half * 128 + w * 8][0];
#pragma unroll
    for (int rnd = 0; rnd < 2; ++rnd)
      __builtin_amdgcn_global_load_lds(
          (const __attribute__((address_space(1))) void*)(src + (size_t)rnd * 64 * lda),
          (__attribute__((address_space(3))) void*)(dst + rnd * 64 * 64), 16, 0, 0);
  };
  auto stageB = [&](int half, int tile) {
    const u16* src = B + (size_t)(n0 + half * 128 + srow) * ldb + tile * 64 + sch * 8;
    u16* dst = &Bs[tile & 1][half * 128 + w * 8][0];
#pragma unroll
    for (int rnd = 0; rnd < 2; ++rnd)
      __builtin_amdgcn_global_load_lds(
          (const __attribute__((address_space(1))) void*)(src + (size_t)rnd * 64 * ldb),
          (__attribute__((address_space(3))) void*)(dst + rnd * 64 * 64), 16, 0, 0);
  };

  f32x4 acc[8][4] = {};
  bf16x8 areg[4][2], breg[2][2][2];

  stageB(0, 0); stageB(1, 0); stageA(0, 0); stageA(1, 0);
  if (NT > 1) {
    stageB(0, 1); stageB(1, 1); stageA(0, 1); stageA(1, 1);
    asm volatile("s_waitcnt vmcnt(8)" ::: "memory");
  } else {
    asm volatile("s_waitcnt vmcnt(0)" ::: "memory");
  }
  __builtin_amdgcn_s_barrier();

#define LOADA(QR)                                                                   \
  _Pragma("unroll") for (int m = 0; m < 4; ++m)                                     \
    _Pragma("unroll") for (int kh = 0; kh < 2; ++kh) {                              \
      int hr = wr * 128 + (QR) * 64 + m * 16 + l15;                                 \
      areg[m][kh] = *(const bf16x8*)(abase + hr * 64 + ((((kh << 2) | g) ^ sl7) << 3)); \
    }
#define LOADB(QC)                                                                   \
  _Pragma("unroll") for (int n = 0; n < 2; ++n)                                     \
    _Pragma("unroll") for (int kh = 0; kh < 2; ++kh) {                              \
      int br = wc * 64 + (QC) * 32 + n * 16 + l15;                                  \
      breg[QC][n][kh] = *(const bf16x8*)(bbase + br * 64 + ((((kh << 2) | g) ^ sl7) << 3)); \
    }
#define QPHASE(QR, QC)                                                              \
  __builtin_amdgcn_s_setprio(1);                                                    \
  _Pragma("unroll") for (int m = 0; m < 4; ++m)                                     \
    _Pragma("unroll") for (int n = 0; n < 2; ++n)                                   \
      _Pragma("unroll") for (int kh = 0; kh < 2; ++kh)                              \
        acc[(QR) * 4 + m][(QC) * 2 + n] = __builtin_amdgcn_mfma_f32_16x16x32_bf16(  \
            areg[m][kh], breg[QC][n][kh], acc[(QR) * 4 + m][(QC) * 2 + n], 0, 0, 0); \
  __builtin_amdgcn_s_setprio(0);

  for (int t = 0; t < NT; ++t) {
    const u16* abase = &As[t & 1][0][0];
    const u16* bbase = &Bs[t & 1][0][0];
    LOADA(0); LOADB(0);
    __builtin_amdgcn_s_barrier();
    asm volatile("s_waitcnt lgkmcnt(0)" ::: "memory");
    QPHASE(0, 0);
    __builtin_amdgcn_s_barrier();
    LOADB(1);
    __builtin_amdgcn_s_barrier();
    asm volatile("s_waitcnt lgkmcnt(0)" ::: "memory");
    QPHASE(0, 1);
    __builtin_amdgcn_s_barrier();
    LOADA(1);
    if (t + 2 < NT) { stageB(0, t + 2); stageB(1, t + 2); }
    __builtin_amdgcn_s_barrier();
    asm volatile("s_waitcnt lgkmcnt(0)" ::: "memory");
    QPHASE(1, 1);
    __builtin_amdgcn_s_barrier();
    if (t + 2 < NT) { stageA(0, t + 2); stageA(1, t + 2); }
    QPHASE(1, 0);
    if (t + 1 < NT) {
      if (t + 2 < NT) asm volatile("s_waitcnt vmcnt(8)" ::: "memory");
      else            asm volatile("s_waitcnt vmcnt(0)" ::: "memory");
    }
    __builtin_amdgcn_s_barrier();
  }
#undef LOADA
#undef LOADB
#undef QPHASE

  const int er = g * 4;
#pragma unroll
  for (int i = 0; i < 8; ++i)
#pragma unroll
    for (int j = 0; j < 4; ++j)
#pragma unroll
      for (int r = 0; r < 4; ++r) {
        int row = m0 + wr * 128 + i * 16 + er + r;
        int col = n0 + wc * 64 + j * 16 + l15;
        if (OUTMODE == OUT_BF16) {
          ((u16*)Cv)[(size_t)row * ldc + col] = f2bf(acc[i][j][r]);
        } else if (OUTMODE == OUT_F32_ACC) {
          Cf[(size_t)row * ldc + col] += acc[i][j][r];
        } else {
          Cf[(size_t)row * ldc + col] = acc[i][j][r];
        }
      }
}

// ---------------- split-K reduce ----------------
__global__ __launch_bounds__(256) void k_red(const float* __restrict__ P,
                                             float* __restrict__ dst, int accmode) {
  size_t i = ((size_t)blockIdx.x * 256 + threadIdx.x) * 4;
  const size_t n = (size_t)4 * 1024 * 1024;
  float4 a = *(const float4*)(P + i);
  float4 b = *(const float4*)(P + n + i);
  float4 c = *(const float4*)(P + 2 * n + i);
  float4 d = *(const float4*)(P + 3 * n + i);
  float4 r;
  r.x = (a.x + b.x) + (c.x + d.x);
  r.y = (a.y + b.y) + (c.y + d.y);
  r.z = (a.z + b.z) + (c.z + d.z);
  r.w = (a.w + b.w) + (c.w + d.w);
  if (accmode) {
    float4 o = *(const float4*)(dst + i);
    r.x += o.x; r.y += o.y; r.z += o.z; r.w += o.w;
  }
  *(float4*)(dst + i) = r;
}

// ---------------- LoRA ----------------
__global__ __launch_bounds__(256) void k_lora_down(const u16* __restrict__ X,
                                                   const float* __restrict__ A,
                                                   float* __restrict__ T, int nproj) {
  int s = blockIdx.x;
  int lane = threadIdx.x & 63, wv = threadIdx.x >> 6;
  const u16* x = X + (size_t)s * D_;
  for (int p = wv; p < nproj * R_; p += 4) {
    const float* a = A + (size_t)p * D_;
    float sum = 0.f;
    for (int d = lane; d < D_; d += 64) sum += bf2f(x[d]) * a[d];
#pragma unroll
    for (int m = 1; m < 64; m <<= 1) sum += __shfl_xor(sum, m, 64);
    if (lane == 0) T[(size_t)s * (nproj * R_) + p] = sum;
  }
}

__global__ __launch_bounds__(256) void k_lora_up(float* __restrict__ Y, int ystride,
                                                 const float* __restrict__ T,
                                                 const float* __restrict__ Bm, int nproj) {
  int t = blockIdx.x * 256 + threadIdx.x;
  int d = t & (D_ - 1);
  int si = t >> 11;
  int i = si % nproj;
  int s = si / nproj;
  const float* tp = T + ((size_t)s * nproj + i) * R_;
  const float* bp = Bm + ((size_t)i * D_ + d) * R_;
  float acc = 0.f;
#pragma unroll
  for (int r = 0; r < R_; r++) acc += tp[r] * bp[r];
  Y[(size_t)s * ystride + (size_t)i * D_ + d] += 2.0f * acc;
}

// ---- LoRA-up for qkv, bf16 in-place ----
__global__ __launch_bounds__(256) void k_lora_up_qkv(u16* __restrict__ qkvb,
                                                     const float* __restrict__ T,
                                                     const float* __restrict__ Bm) {
  size_t t = ((size_t)blockIdx.x * 256 + threadIdx.x) * 8;
  int c = (int)(t % 6144);
  int s = (int)(t / 6144);
  int i = c >> 11, dd = c & 2047;
  const float* tp = T + ((size_t)s * 3 + i) * R_;
  float tr[8];
#pragma unroll
  for (int r = 0; r < R_; ++r) tr[r] = tp[r];
  uint4 q = *(const uint4*)(qkvb + t);
  u16 qs[8] = {(u16)(q.x & 0xffff), (u16)(q.x >> 16), (u16)(q.y & 0xffff), (u16)(q.y >> 16),
               (u16)(q.z & 0xffff), (u16)(q.z >> 16), (u16)(q.w & 0xffff), (u16)(q.w >> 16)};
  u16 os[8];
#pragma unroll
  for (int j = 0; j < 8; ++j) {
    const float* bp = Bm + ((size_t)i * D_ + dd + j) * R_;
    float a = 0.f;
#pragma unroll
    for (int r = 0; r < R_; ++r) a += tr[r] * bp[r];
    os[j] = f2bf(bf2f(qs[j]) + 2.0f * a);
  }
  uint4 o;
  o.x = (u32)os[0] | ((u32)os[1] << 16);
  o.y = (u32)os[2] | ((u32)os[3] << 16);
  o.z = (u32)os[4] | ((u32)os[5] << 16);
  o.w = (u32)os[6] | ((u32)os[7] << 16);
  *(uint4*)(qkvb + t) = o;
}

// ---- per-head V transpose ----
__global__ __launch_bounds__(256) void k_vtrans(const u16* __restrict__ qkvb,
                                                u16* __restrict__ Vt) {
  __shared__ u16 t[64][136];
  int s0 = blockIdx.x * 64, hh = blockIdx.y;
  int tid = threadIdx.x;
#pragma unroll
  for (int it = 0; it < 4; ++it) {
    int e = it * 2048 + tid * 8;
    int sr = e >> 7, sc = e & 127;
    *(uint4*)&t[sr][sc] =
        *(const uint4*)(qkvb + (size_t)(s0 + sr) * 6144 + 4096 + hh * 128 + sc);
  }
  __syncthreads();
#pragma unroll
  for (int it = 0; it < 4; ++it) {
    int q = it * 256 + tid;
    int dh = q >> 3, sc = (q & 7) * 8;
    u16 e0 = t[sc + 0][dh], e1 = t[sc + 1][dh], e2 = t[sc + 2][dh], e3 = t[sc + 3][dh];
    u16 e4 = t[sc + 4][dh], e5 = t[sc + 5][dh], e6 = t[sc + 6][dh], e7 = t[sc + 7][dh];
    uint4 o;
    o.x = (u32)e0 | ((u32)e1 << 16);
    o.y = (u32)e2 | ((u32)e3 << 16);
    o.z = (u32)e4 | ((u32)e5 << 16);
    o.w = (u32)e6 | ((u32)e7 << 16);
    *(uint4*)(Vt + ((size_t)hh * DH_ + dh) * S_ + s0 + sc) = o;
  }
}

// ======== MFMA flash attention v2 ========
__global__ __launch_bounds__(256) void k_attn2(const u16* __restrict__ qkvb,
                                               const u16* __restrict__ Vt,
                                               u16* __restrict__ out) {
  __shared__ u16 Ks[2][64 * 128];
  __shared__ u16 VTs[2][128 * 64];
  __shared__ u16 PT[4][64 * 16];
  const int tid = threadIdx.x;
  const int lane = tid & 63, w = tid >> 6;
  const int g = lane >> 4, l4 = lane & 15;
  const int p = blockIdx.x;
  const int hh = blockIdx.y;
  const int ld = 6144;
  const float rs = 0.08838834764831845f;
  const int qa0 = p * 64, qb0 = (31 - p) * 64;
  const int ntb = 32 - p;
  char* pt_w = (char*)&PT[w][0];

  const int qga = qa0 + w * 16 + l4;
  const int qgb = qb0 + w * 16 + l4;

  bf16x8 qfa[4], qfb[4];
#pragma unroll
  for (int kh = 0; kh < 4; ++kh) {
    qfa[kh] = *(const bf16x8*)(qkvb + (size_t)qga * ld + hh * DH_ + kh * 32 + g * 8);
    qfb[kh] = *(const bf16x8*)(qkvb + (size_t)qgb * ld + hh * DH_ + kh * 32 + g * 8);
  }

  float ma = -3.0e38f, la = 0.f, mb = -3.0e38f, lb = 0.f;
  f32x4 acc_a[8] = {}, acc_b[8] = {};
  bf16x8 pba[2], pbb[2];

  auto stage = [&](int buf, int kt) {
    const int kv0 = kt * 64;
#pragma unroll
    for (int i = 0; i < 4; ++i) {
      int rl = (w * 4 + i) * 4 + (lane >> 4);
      int cs = (lane & 15) ^ ((rl & 7) ^ (((rl >> 3) & 3) << 1));
      __builtin_amdgcn_global_load_lds(
          (const __attribute__((address_space(1))) void*)(
              qkvb + (size_t)(kv0 + rl) * ld + 2048 + hh * DH_ + cs * 8),
          (__attribute__((address_space(3))) void*)(&Ks[buf][(w * 4 + i) * 512]), 16, 0, 0);
    }
#pragma unroll
    for (int i = 0; i < 4; ++i) {
      int dh = (w * 4 + i) * 8 + (lane >> 3);
      int cs = (lane & 7) ^ (dh & 7);
      __builtin_amdgcn_global_load_lds(
          (const __attribute__((address_space(1))) void*)(
              Vt + ((size_t)hh * DH_ + dh) * S_ + kv0 + cs * 8),
          (__attribute__((address_space(3))) void*)(&VTs[buf][(w * 4 + i) * 512]), 16, 0, 0);
    }
  };

  auto softpb = [&](f32x4* sv, float& m, float& l, f32x4* acc, int qg, bool diag,
                    int kv0, bf16x8* pb) {
    float pv[16];
    float tmax = -3.0e38f;
#pragma unroll
    for (int kb = 0; kb < 4; ++kb)
#pragma unroll
      for (int r = 0; r < 4; ++r) {
        float s = sv[kb][r] * rs;
        if (diag) {
          int kglob = kv0 + kb * 16 + g * 4 + r;
          if (kglob > qg) s = -1.0e30f;
        }
        pv[kb * 4 + r] = s;
        tmax = fmaxf(tmax, s);
      }
    tmax = fmaxf(tmax, __shfl_xor(tmax, 16, 64));
    tmax = fmaxf(tmax, __shfl_xor(tmax, 32, 64));
    float mn = fmaxf(m, tmax);
    float corr = __expf(m - mn);
    m = mn;
    float ps = 0.f;
#pragma unroll
    for (int i = 0; i < 16; ++i) { pv[i] = __expf(pv[i] - mn); ps += pv[i]; }
    ps += __shfl_xor(ps, 16, 64);
    ps += __shfl_xor(ps, 32, 64);
    l = l * corr + ps;
#pragma unroll
    for (int f = 0; f < 8; ++f) {
      acc[f][0] *= corr; acc[f][1] *= corr; acc[f][2] *= corr; acc[f][3] *= corr;
    }
#pragma unroll
    for (int kb = 0; kb < 4; ++kb)
#pragma unroll
      for (int r = 0; r < 4; ++r) {
        int key = kb * 16 + g * 4 + r;
        int byte = (key * 32 + l4 * 2) ^ (((key >> 3) & 3) << 5);
        *(u16*)(pt_w + byte) = f2bf(pv[kb * 4 + r]);
      }
#pragma unroll
    for (int ks = 0; ks < 2; ++ks) {
      union { bf16x8 v; u16 s[8]; } ub;
#pragma unroll
      for (int j = 0; j < 8; ++j) {
        int key = ks * 32 + g * 8 + j;
        int byte = (key * 32 + l4 * 2) ^ (((key >> 3) & 3) << 5);
        ub.s[j] = *(const u16*)(pt_w + byte);
      }
      pb[ks] = ub.v;
    }
  };

  stage(0, 0);
  asm volatile("s_waitcnt vmcnt(0)" ::: "memory");
  __syncthreads();

  for (int kt = 0; kt < ntb; ++kt) {
    const int kv0 = kt * 64;
    const int buf = kt & 1;
    if (kt + 1 < ntb) stage(buf ^ 1, kt + 1);

    const char* kb_base = (const char*)&Ks[buf][0];
    const char* vb_base = (const char*)&VTs[buf][0];
    const bool doa = (kt <= p);

    f32x4 sa[4] = {}, sb[4] = {};
#pragma unroll
    for (int kb = 0; kb < 4; ++kb) {
#pragma unroll
      for (int kh = 0; kh < 4; ++kh) {
        int key = kb * 16 + l4;
        int ch = (kh * 4 + g) ^ ((key & 7) ^ (((key >> 3) & 3) << 1));
        bf16x8 af = *(const bf16x8*)(kb_base + key * 256 + ch * 16);
        if (doa) sa[kb] = MFMA16(af, qfa[kh], sa[kb]);
        sb[kb] = MFMA16(af, qfb[kh], sb[kb]);
      }
    }

    if (doa) softpb(sa, ma, la, acc_a, qga, kt == p, kv0, pba);
    softpb(sb, mb, lb, acc_b, qgb, kt == ntb - 1, kv0, pbb);

#pragma unroll
    for (int f = 0; f < 8; ++f) {
#pragma unroll
      for (int ks = 0; ks < 2; ++ks) {
        int dh = f * 16 + l4;
        int ch = (ks * 4 + g) ^ (dh & 7);
        bf16x8 va = *(const bf16x8*)(vb_base + dh * 128 + ch * 16);
        if (doa) acc_a[f] = MFMA16(va, pba[ks], acc_a[f]);
        acc_b[f] = MFMA16(va, pbb[ks], acc_b[f]);
      }
    }

    if (kt + 1 < ntb) {
      asm volatile("s_waitcnt vmcnt(0)" ::: "memory");
      __syncthreads();
    }
  }

  float inva = 1.f / la, invb = 1.f / lb;
  u16* opa = out + (size_t)qga * D_ + hh * DH_;
  u16* opb = out + (size_t)qgb * D_ + hh * DH_;
#pragma unroll
  for (int f = 0; f < 8; ++f)
#pragma unroll
    for (int r = 0; r < 4; ++r) {
      opa[f * 16 + g * 4 + r] = f2bf(acc_a[f][r] * inva);
      opb[f * 16 + g * 4 + r] = f2bf(acc_b[f][r] * invb);
    }
}

// ---------------- silu(gate)*up ----------------
__global__ __launch_bounds__(256) void k_silumul(u16* __restrict__ gu) {
  size_t i = ((size_t)blockIdx.x * 256 + threadIdx.x) * 4;
  int s = (int)(i >> 13);
  int f = (int)(i & 8191);
  u16* gp = gu + (size_t)s * (2 * DFF_) + f;
  ushort4 gt = *(ushort4*)gp;
  ushort4 up = *(ushort4*)(gp + DFF_);
  float g0 = bf2f(gt.x), g1 = bf2f(gt.y), g2 = bf2f(gt.z), g3 = bf2f(gt.w);
  float u0 = bf2f(up.x), u1 = bf2f(up.y), u2 = bf2f(up.z), u3 = bf2f(up.w);
  ushort4 o;
  o.x = f2bf(g0 / (1.f + __expf(-g0)) * u0);
  o.y = f2bf(g1 / (1.f + __expf(-g1)) * u1);
  o.z = f2bf(g2 / (1.f + __expf(-g2)) * u2);
  o.w = f2bf(g3 / (1.f + __expf(-g3)) * u3);
  *(ushort4*)gp = o;
}

// ---------------- gumbel softmax, ONE-PASS ----------------
__global__ __launch_bounds__(256) void k_gumbel(const float* __restrict__ logits,
                                                const float* __restrict__ u,
                                                u16* __restrict__ g) {
  __shared__ float z[V_];
  __shared__ float sred[4];
  int s = blockIdx.x;
  const float* lp = logits + (size_t)s * V_;
  const float* up = u + (size_t)s * V_;
  float m = -3.0e38f;
  for (int v4 = threadIdx.x; v4 < V_ / 4; v4 += 256) {
    float4 lv = *(const float4*)(lp + v4 * 4);
    float4 uv = *(const float4*)(up + v4 * 4);
    float z0 = lv.x - __logf(-__logf(uv.x + 1e-10f) + 1e-10f);
    float z1 = lv.y - __logf(-__logf(uv.y + 1e-10f) + 1e-10f);
    float z2 = lv.z - __logf(-__logf(uv.z + 1e-10f) + 1e-10f);
    float z3 = lv.w - __logf(-__logf(uv.w + 1e-10f) + 1e-10f);
    *(float4*)(z + v4 * 4) = make_float4(z0, z1, z2, z3);
    m = fmaxf(fmaxf(fmaxf(m, z0), fmaxf(z1, z2)), z3);
  }
#pragma unroll
  for (int msk = 1; msk < 64; msk <<= 1) m = fmaxf(m, __shfl_xor(m, msk, 64));
  if ((threadIdx.x & 63) == 0) sred[threadIdx.x >> 6] = m;
  __syncthreads();
  float M = fmaxf(fmaxf(sred[0], sred[1]), fmaxf(sred[2], sred[3]));
  float l = 0.f;
  for (int v4 = threadIdx.x; v4 < V_ / 4; v4 += 256) {
    float4 zv = *(float4*)(z + v4 * 4);
    zv.x = __expf(zv.x - M); zv.y = __expf(zv.y - M);
    zv.z = __expf(zv.z - M); zv.w = __expf(zv.w - M);
    *(float4*)(z + v4 * 4) = zv;
    l += (zv.x + zv.y) + (zv.z + zv.w);
  }
#pragma unroll
  for (int msk = 1; msk < 64; msk <<= 1) l += __shfl_xor(l, msk, 64);
  __syncthreads();
  if ((threadIdx.x & 63) == 0) sred[threadIdx.x >> 6] = l;
  __syncthreads();
  float inv = 1.f / (sred[0] + sred[1] + sred[2] + sred[3]);
  u16* gp = g + (size_t)s * V_;
  for (int v4 = threadIdx.x; v4 < V_ / 4; v4 += 256) {
    float4 zv = *(float4*)(z + v4 * 4);
    ushort4 o;
    o.x = f2bf(zv.x * inv); o.y = f2bf(zv.y * inv);
    o.z = f2bf(zv.z * inv); o.w = f2bf(zv.w * inv);
    *(ushort4*)(gp + v4 * 4) = o;
  }
}

extern "C" void kernel_launch(void* const* d_in, const int* in_sizes, int n_in,
                              void* d_out, int out_size, void* d_ws, size_t ws_size,
                              hipStream_t stream) {
  const int*   ids        = (const int*)d_in[0];
  const float* u          = (const float*)d_in[1];
  const float* emb        = (const float*)d_in[2];
  const float* attn_scale = (const float*)d_in[3];
  const float* gu_scale   = (const float*)d_in[4];
  const float* dn_scale   = (const float*)d_in[5];
  const float* lora_A     = (const float*)d_in[6];
  const float* lora_B     = (const float*)d_in[7];
  const float* norm_w     = (const float*)d_in[8];
  const float* fnorm_w    = (const float*)d_in[9];
  const int*   attn_idx   = (const int*)d_in[10];
  const int*   gu_idx     = (const int*)d_in[11];
  const int*   dn_idx     = (const int*)d_in[12];

  float* out_se = (float*)d_out;
  float* out_lg = (float*)d_out + (size_t)S_ * D_;

  char* W = (char*)d_ws;
  float* h    = (float*)(W);                          // 16 MiB (layer phase)
  u16*   xb   = (u16*)(W + ((size_t)16 << 20));       // 8 MiB
  u16*   qkvb = (u16*)(W + ((size_t)72 << 20));       // 24 MiB
  u16*   Vtb  = (u16*)(W + ((size_t)96 << 20));       // 8 MiB
  u16*   ob   = (u16*)(W + ((size_t)104 << 20));      // 8 MiB
  u16*   gub  = (u16*)(W + ((size_t)112 << 20));      // 64 MiB
  u16*   wdq  = (u16*)(W + ((size_t)176 << 20));      // 64 MiB
  float* Tl   = (float*)(W + ((size_t)240 << 20));    // 192 KiB
  // head phase: embb dies after logits; gsm overwrites it; embT lives at W[125,250)
  u16*   embb = (u16*)(W);                            // 125 MiB
  u16*   gsm  = (u16*)(W);                            // 125 MiB (after logits GEMM)
  u16*   embT = (u16*)(W + ((size_t)125 << 20));      // 125 MiB
  u16*   xbh  = (u16*)d_out;                          // final-norm out, parked in out_se
  float* Pk   = (float*)(W + ((size_t)250 << 20));    // 64 MiB split-K partials
  const bool big = ws_size >= ((size_t)314 << 20);
  const size_t ZS = (size_t)4 * 1024 * 1024;

  dim3 b256(256), b512(512);

  k_gather<<<dim3(S_ * D_ / 256), b256, 0, stream>>>(ids, emb, h);

  for (int l = 0; l < L_; ++l) {
    const int*   aidx = attn_idx + (size_t)l * 4 * D_ * D_;
    const float* ascl = attn_scale + (size_t)l * 4 * D_ * (D_ / 64);
    const float* lA   = lora_A + (size_t)l * 4 * R_ * D_;
    const float* lB   = lora_B + (size_t)l * 4 * D_ * R_;

    k_rmsnorm<<<dim3(S_), b256, 0, stream>>>(h, norm_w + (size_t)l * 2 * D_, xb);
    k_dequant<<<dim3(4 * D_ * D_ / 8 / 256), b256, 0, stream>>>(aidx, ascl, wdq, 11);
    k_gemm256<OUT_BF16><<<dim3(3 * D_ / 256, 8), b512, 0, stream>>>(
        xb, D_, wdq, D_, qkvb, 3 * D_, D_, 0);
    k_lora_down<<<dim3(S_), b256, 0, stream>>>(xb, lA, Tl, 3);
    k_lora_up_qkv<<<dim3(S_ * 3 * D_ / 8 / 256), b256, 0, stream>>>(qkvb, Tl, lB);
    k_vtrans<<<dim3(S_ / 64, H_), b256, 0, stream>>>(qkvb, Vtb);
    k_attn2<<<dim3(16, H_), b256, 0, stream>>>(qkvb, Vtb, ob);
    if (big) {
      k_gemm256<OUT_F32><<<dim3(D_ / 256, 8, 4), b512, 0, stream>>>(
          ob, D_, wdq + (size_t)3 * D_ * D_, D_, Pk, D_, D_ / 4, ZS);
      k_red<<<dim3(4096), b256, 0, stream>>>(Pk, h, 1);
    } else {
      k_gemm256<OUT_F32_ACC><<<dim3(D_ / 256, 8), b512, 0, stream>>>(
          ob, D_, wdq + (size_t)3 * D_ * D_, D_, h, D_, D_, 0);
    }
    k_lora_down<<<dim3(S_), b256, 0, stream>>>(ob, lA + (size_t)3 * R_ * D_, Tl, 1);
    k_lora_up<<<dim3(S_ * D_ / 256), b256, 0, stream>>>(h, D_, Tl, lB + (size_t)3 * D_ * R_, 1);

    k_rmsnorm<<<dim3(S_), b256, 0, stream>>>(h, norm_w + (size_t)l * 2 * D_ + D_, xb);
    k_dequant<<<dim3(2 * DFF_ * D_ / 8 / 256), b256, 0, stream>>>(
        gu_idx + (size_t)l * 2 * DFF_ * D_, gu_scale + (size_t)l * 2 * DFF_ * (D_ / 64), wdq, 11);
    k_gemm256<OUT_BF16><<<dim3(2 * DFF_ / 256, 8), b512, 0, stream>>>(
        xb, D_, wdq, D_, gub, 2 * DFF_, D_, 0);
    k_silumul<<<dim3(S_ * DFF_ / 4 / 256), b256, 0, stream>>>(gub);
    k_dequant<<<dim3(D_ * DFF_ / 8 / 256), b256, 0, stream>>>(
        dn_idx + (size_t)l * D_ * DFF_, dn_scale + (size_t)l * D_ * (DFF_ / 64), wdq, 13);
    if (big) {
      k_gemm256<OUT_F32><<<dim3(D_ / 256, 8, 4), b512, 0, stream>>>(
          gub, 2 * DFF_, wdq, DFF_, Pk, D_, DFF_ / 4, ZS);
      k_red<<<dim3(4096), b256, 0, stream>>>(Pk, h, 1);
    } else {
      k_gemm256<OUT_F32_ACC><<<dim3(D_ / 256, 8), b512, 0, stream>>>(
          gub, 2 * DFF_, wdq, DFF_, h, D_, DFF_, 0);
    }
  }

  // ---- head ----
  k_rmsnorm<<<dim3(S_), b256, 0, stream>>>(h, fnorm_w, xbh);   // h read before embprep clobbers W[0,..)
  k_embprep<<<dim3(V_ / 64, D_ / 64), b256, 0, stream>>>(emb, embb, embT);
  k_gemm256<OUT_F32><<<dim3(V_ / 256, 8), b512, 0, stream>>>(
      xbh, D_, embb, D_, out_lg, V_, D_, 0);
  k_gumbel<<<dim3(S_), b256, 0, stream>>>(out_lg, u, gsm);     // overwrites dead embb region
  if (big) {
    k_gemm256<OUT_F32><<<dim3(D_ / 256, 8, 4), b512, 0, stream>>>(
        gsm, V_, embT, V_, Pk, D_, V_ / 4, ZS);
    k_red<<<dim3(4096), b256, 0, stream>>>(Pk, out_se, 0);
  } else {
    k_gemm256<OUT_F32><<<dim3(D_ / 256, 8), b512, 0, stream>>>(
        gsm, V_, embT, V_, out_se, D_, V_, 0);
  }
}

// Round 14
// 2336.996 us; speedup vs baseline: 7.4220x; 1.0039x over previous
//
#include <hip/hip_runtime.h>
#include <hip/hip_bf16.h>

typedef unsigned short u16;
typedef unsigned int u32;
typedef __bf16 bf16t;
typedef bf16t bf16x8 __attribute__((ext_vector_type(8)));
typedef float f32x4 __attribute__((ext_vector_type(4)));

constexpr int S_   = 2048;
constexpr int D_   = 2048;
constexpr int H_   = 16;
constexpr int DH_  = 128;
constexpr int L_   = 2;
constexpr int DFF_ = 8192;
constexpr int V_   = 32000;
constexpr int R_   = 8;

#define MFMA16(a, b, c) __builtin_amdgcn_mfma_f32_16x16x32_bf16(a, b, c, 0, 0, 0)

__constant__ float c_nf4[16] = {
  -1.0f, -0.6961928009986877f, -0.5250730514526367f, -0.39491748809814453f,
  -0.28444138169288635f, -0.18477343022823334f, -0.09105003625154495f, 0.0f,
  0.07958029955625534f, 0.16093020141124725f, 0.24611230194568634f,
  0.33791524171829224f, 0.44070982933044434f, 0.5626170039176941f,
  0.7229568362236023f, 1.0f };

__device__ __forceinline__ u16 f2bf(float f) {
  union { float f; u32 u; } v; v.f = f;
  u32 r = v.u + 0x7fffu + ((v.u >> 16) & 1u);
  return (u16)(r >> 16);
}
__device__ __forceinline__ float bf2f(u16 h) {
  union { u32 u; float f; } v; v.u = ((u32)h) << 16; return v.f;
}

// ---------------- embedding gather ----------------
__global__ __launch_bounds__(256) void k_gather(const int* __restrict__ ids,
                                                const float* __restrict__ emb,
                                                float* __restrict__ h) {
  int t = blockIdx.x * 256 + threadIdx.x;
  int s = t >> 11;
  int d = t & 2047;
  h[t] = emb[(size_t)ids[s] * D_ + d];
}

// ---------------- rmsnorm f32 -> bf16 ----------------
__global__ __launch_bounds__(256) void k_rmsnorm(const float* __restrict__ in,
                                                 const float* __restrict__ w,
                                                 u16* __restrict__ out) {
  int s = blockIdx.x;
  const float* x = in + (size_t)s * D_;
  float ss = 0.f;
  for (int d = threadIdx.x; d < D_; d += 256) { float v = x[d]; ss += v * v; }
#pragma unroll
  for (int m = 1; m < 64; m <<= 1) ss += __shfl_xor(ss, m, 64);
  __shared__ float sh[4];
  if ((threadIdx.x & 63) == 0) sh[threadIdx.x >> 6] = ss;
  __syncthreads();
  ss = sh[0] + sh[1] + sh[2] + sh[3];
  float sc = rsqrtf(ss * (1.0f / D_) + 1e-6f);
  u16* o = out + (size_t)s * D_;
  for (int d = threadIdx.x; d < D_; d += 256) o[d] = f2bf(x[d] * sc * w[d]);
}

// ---------------- NF4 dequant ----------------
__global__ __launch_bounds__(256) void k_dequant(const int* __restrict__ idx,
                                                 const float* __restrict__ scale,
                                                 u16* __restrict__ out, int kshift) {
  size_t t = (size_t)blockIdx.x * 256 + threadIdx.x;
  size_t e = t * 8;
  int k = (int)(e & ((1u << kshift) - 1));
  size_t n = e >> kshift;
  float s = scale[(n << (kshift - 6)) + (k >> 6)];
  int4 i0 = *(const int4*)(idx + e);
  int4 i1 = *(const int4*)(idx + e + 4);
  uint4 o;
  o.x = (u32)f2bf(c_nf4[i0.x] * s) | ((u32)f2bf(c_nf4[i0.y] * s) << 16);
  o.y = (u32)f2bf(c_nf4[i0.z] * s) | ((u32)f2bf(c_nf4[i0.w] * s) << 16);
  o.z = (u32)f2bf(c_nf4[i1.x] * s) | ((u32)f2bf(c_nf4[i1.y] * s) << 16);
  o.w = (u32)f2bf(c_nf4[i1.z] * s) | ((u32)f2bf(c_nf4[i1.w] * s) << 16);
  *(uint4*)(out + e) = o;
}

// ---- fused emb prep: ONE read of emb f32 [V,D] -> embb bf16 [V,D] + embT bf16 [D,V] ----
__global__ __launch_bounds__(256) void k_embprep(const float* __restrict__ src,
                                                 u16* __restrict__ embb,
                                                 u16* __restrict__ embT) {
  __shared__ u16 tile[64][65];
  int v0 = blockIdx.x * 64, d0 = blockIdx.y * 64;
  int tid = threadIdx.x;
  int rr = tid >> 4, cc = (tid & 15) * 4;
#pragma unroll
  for (int j = 0; j < 4; ++j) {
    int r = j * 16 + rr;
    float4 f = *(const float4*)(src + (size_t)(v0 + r) * D_ + d0 + cc);
    u16 b0 = f2bf(f.x), b1 = f2bf(f.y), b2 = f2bf(f.z), b3 = f2bf(f.w);
    tile[r][cc + 0] = b0; tile[r][cc + 1] = b1;
    tile[r][cc + 2] = b2; tile[r][cc + 3] = b3;
    ushort4 wv; wv.x = b0; wv.y = b1; wv.z = b2; wv.w = b3;
    *(ushort4*)(embb + (size_t)(v0 + r) * D_ + d0 + cc) = wv;
  }
  __syncthreads();
#pragma unroll
  for (int j = 0; j < 4; ++j) {
    int r = j * 16 + rr;            // d-local
    ushort4 w;
    w.x = tile[cc + 0][r]; w.y = tile[cc + 1][r];
    w.z = tile[cc + 2][r]; w.w = tile[cc + 3][r];
    *(ushort4*)(embT + (size_t)(d0 + r) * V_ + v0 + cc) = w;
  }
}

// ======== 256x256 pipelined MFMA GEMM (round-9 schedule, measured-best) ========
enum { OUT_F32 = 0, OUT_F32_ACC = 1, OUT_BF16 = 2 };

template<int OUTMODE>
__global__ __launch_bounds__(512, 2) void k_gemm256(const u16* __restrict__ A, int lda,
                                                    const u16* __restrict__ B, int ldb,
                                                    void* __restrict__ Cv, int ldc,
                                                    int Kc, size_t zstride) {
  __shared__ u16 As[2][256][64];
  __shared__ u16 Bs[2][256][64];
  const int tid = threadIdx.x;
  const int lane = tid & 63, w = tid >> 6;
  const int wr = w >> 2, wc = w & 3;
  const int g = (lane >> 4), l15 = lane & 15, sl7 = lane & 7;

  const int gx = gridDim.x, gy = gridDim.y;
  const int cpx = (gx * gy) >> 3;
  int d = blockIdx.y * gx + blockIdx.x;
  int swz = (d & 7) * cpx + (d >> 3);
  const int m0 = (swz % gy) * 256;
  const int n0 = (swz / gy) * 256;

  A += (size_t)blockIdx.z * Kc;
  B += (size_t)blockIdx.z * Kc;
  float* Cf = (float*)Cv + (size_t)blockIdx.z * zstride;

  const int NT = Kc >> 6;
  const int srow = w * 8 + (lane >> 3);
  const int sch  = (lane & 7) ^ (lane >> 3);

  auto stageA = [&](int half, int tile) {
    const u16* src = A + (size_t)(m0 + half * 128 + srow) * lda + tile * 64 + sch * 8;
    u16* dst = &As[tile & 1][half * 128 + w * 8][0];
#pragma unroll
    for (int rnd = 0; rnd < 2; ++rnd)
      __builtin_amdgcn_global_load_lds(
          (const __attribute__((address_space(1))) void*)(src + (size_t)rnd * 64 * lda),
          (__attribute__((address_space(3))) void*)(dst + rnd * 64 * 64), 16, 0, 0);
  };
  auto stageB = [&](int half, int tile) {
    const u16* src = B + (size_t)(n0 + half * 128 + srow) * ldb + tile * 64 + sch * 8;
    u16* dst = &Bs[tile & 1][half * 128 + w * 8][0];
#pragma unroll
    for (int rnd = 0; rnd < 2; ++rnd)
      __builtin_amdgcn_global_load_lds(
          (const __attribute__((address_space(1))) void*)(src + (size_t)rnd * 64 * ldb),
          (__attribute__((address_space(3))) void*)(dst + rnd * 64 * 64), 16, 0, 0);
  };

  f32x4 acc[8][4] = {};
  bf16x8 areg[4][2], breg[2][2][2];

  stageB(0, 0); stageB(1, 0); stageA(0, 0); stageA(1, 0);
  if (NT > 1) {
    stageB(0, 1); stageB(1, 1); stageA(0, 1); stageA(1, 1);
    asm volatile("s_waitcnt vmcnt(8)" ::: "memory");
  } else {
    asm volatile("s_waitcnt vmcnt(0)" ::: "memory");
  }
  __builtin_amdgcn_s_barrier();

#define LOADA(QR)                                                                   \
  _Pragma("unroll") for (int m = 0; m < 4; ++m)                                     \
    _Pragma("unroll") for (int kh = 0; kh < 2; ++kh) {                              \
      int hr = wr * 128 + (QR) * 64 + m * 16 + l15;                                 \
      areg[m][kh] = *(const bf16x8*)(abase + hr * 64 + ((((kh << 2) | g) ^ sl7) << 3)); \
    }
#define LOADB(QC)                                                                   \
  _Pragma("unroll") for (int n = 0; n < 2; ++n)                                     \
    _Pragma("unroll") for (int kh = 0; kh < 2; ++kh) {                              \
      int br = wc * 64 + (QC) * 32 + n * 16 + l15;                                  \
      breg[QC][n][kh] = *(const bf16x8*)(bbase + br * 64 + ((((kh << 2) | g) ^ sl7) << 3)); \
    }
#define QPHASE(QR, QC)                                                              \
  __builtin_amdgcn_s_setprio(1);                                                    \
  _Pragma("unroll") for (int m = 0; m < 4; ++m)                                     \
    _Pragma("unroll") for (int n = 0; n < 2; ++n)                                   \
      _Pragma("unroll") for (int kh = 0; kh < 2; ++kh)                              \
        acc[(QR) * 4 + m][(QC) * 2 + n] = __builtin_amdgcn_mfma_f32_16x16x32_bf16(  \
            areg[m][kh], breg[QC][n][kh], acc[(QR) * 4 + m][(QC) * 2 + n], 0, 0, 0); \
  __builtin_amdgcn_s_setprio(0);

  for (int t = 0; t < NT; ++t) {
    const u16* abase = &As[t & 1][0][0];
    const u16* bbase = &Bs[t & 1][0][0];
    LOADA(0); LOADB(0);
    __builtin_amdgcn_s_barrier();
    asm volatile("s_waitcnt lgkmcnt(0)" ::: "memory");
    QPHASE(0, 0);
    __builtin_amdgcn_s_barrier();
    LOADB(1);
    __builtin_amdgcn_s_barrier();
    asm volatile("s_waitcnt lgkmcnt(0)" ::: "memory");
    QPHASE(0, 1);
    __builtin_amdgcn_s_barrier();
    LOADA(1);
    if (t + 2 < NT) { stageB(0, t + 2); stageB(1, t + 2); }
    __builtin_amdgcn_s_barrier();
    asm volatile("s_waitcnt lgkmcnt(0)" ::: "memory");
    QPHASE(1, 1);
    __builtin_amdgcn_s_barrier();
    if (t + 2 < NT) { stageA(0, t + 2); stageA(1, t + 2); }
    QPHASE(1, 0);
    if (t + 1 < NT) {
      if (t + 2 < NT) asm volatile("s_waitcnt vmcnt(8)" ::: "memory");
      else            asm volatile("s_waitcnt vmcnt(0)" ::: "memory");
    }
    __builtin_amdgcn_s_barrier();
  }
#undef LOADA
#undef LOADB
#undef QPHASE

  const int er = g * 4;
#pragma unroll
  for (int i = 0; i < 8; ++i)
#pragma unroll
    for (int j = 0; j < 4; ++j)
#pragma unroll
      for (int r = 0; r < 4; ++r) {
        int row = m0 + wr * 128 + i * 16 + er + r;
        int col = n0 + wc * 64 + j * 16 + l15;
        if (OUTMODE == OUT_BF16) {
          ((u16*)Cv)[(size_t)row * ldc + col] = f2bf(acc[i][j][r]);
        } else if (OUTMODE == OUT_F32_ACC) {
          Cf[(size_t)row * ldc + col] += acc[i][j][r];
        } else {
          Cf[(size_t)row * ldc + col] = acc[i][j][r];
        }
      }
}

// ---------------- split-K reduce ----------------
__global__ __launch_bounds__(256) void k_red(const float* __restrict__ P,
                                             float* __restrict__ dst, int accmode) {
  size_t i = ((size_t)blockIdx.x * 256 + threadIdx.x) * 4;
  const size_t n = (size_t)4 * 1024 * 1024;
  float4 a = *(const float4*)(P + i);
  float4 b = *(const float4*)(P + n + i);
  float4 c = *(const float4*)(P + 2 * n + i);
  float4 d = *(const float4*)(P + 3 * n + i);
  float4 r;
  r.x = (a.x + b.x) + (c.x + d.x);
  r.y = (a.y + b.y) + (c.y + d.y);
  r.z = (a.z + b.z) + (c.z + d.z);
  r.w = (a.w + b.w) + (c.w + d.w);
  if (accmode) {
    float4 o = *(const float4*)(dst + i);
    r.x += o.x; r.y += o.y; r.z += o.z; r.w += o.w;
  }
  *(float4*)(dst + i) = r;
}

// ---------------- LoRA ----------------
__global__ __launch_bounds__(256) void k_lora_down(const u16* __restrict__ X,
                                                   const float* __restrict__ A,
                                                   float* __restrict__ T, int nproj) {
  int s = blockIdx.x;
  int lane = threadIdx.x & 63, wv = threadIdx.x >> 6;
  const u16* x = X + (size_t)s * D_;
  for (int p = wv; p < nproj * R_; p += 4) {
    const float* a = A + (size_t)p * D_;
    float sum = 0.f;
    for (int d = lane; d < D_; d += 64) sum += bf2f(x[d]) * a[d];
#pragma unroll
    for (int m = 1; m < 64; m <<= 1) sum += __shfl_xor(sum, m, 64);
    if (lane == 0) T[(size_t)s * (nproj * R_) + p] = sum;
  }
}

__global__ __launch_bounds__(256) void k_lora_up(float* __restrict__ Y, int ystride,
                                                 const float* __restrict__ T,
                                                 const float* __restrict__ Bm, int nproj) {
  int t = blockIdx.x * 256 + threadIdx.x;
  int d = t & (D_ - 1);
  int si = t >> 11;
  int i = si % nproj;
  int s = si / nproj;
  const float* tp = T + ((size_t)s * nproj + i) * R_;
  const float* bp = Bm + ((size_t)i * D_ + d) * R_;
  float acc = 0.f;
#pragma unroll
  for (int r = 0; r < R_; r++) acc += tp[r] * bp[r];
  Y[(size_t)s * ystride + (size_t)i * D_ + d] += 2.0f * acc;
}

// ---- LoRA-up for qkv, bf16 in-place ----
__global__ __launch_bounds__(256) void k_lora_up_qkv(u16* __restrict__ qkvb,
                                                     const float* __restrict__ T,
                                                     const float* __restrict__ Bm) {
  size_t t = ((size_t)blockIdx.x * 256 + threadIdx.x) * 8;
  int c = (int)(t % 6144);
  int s = (int)(t / 6144);
  int i = c >> 11, dd = c & 2047;
  const float* tp = T + ((size_t)s * 3 + i) * R_;
  float tr[8];
#pragma unroll
  for (int r = 0; r < R_; ++r) tr[r] = tp[r];
  uint4 q = *(const uint4*)(qkvb + t);
  u16 qs[8] = {(u16)(q.x & 0xffff), (u16)(q.x >> 16), (u16)(q.y & 0xffff), (u16)(q.y >> 16),
               (u16)(q.z & 0xffff), (u16)(q.z >> 16), (u16)(q.w & 0xffff), (u16)(q.w >> 16)};
  u16 os[8];
#pragma unroll
  for (int j = 0; j < 8; ++j) {
    const float* bp = Bm + ((size_t)i * D_ + dd + j) * R_;
    float a = 0.f;
#pragma unroll
    for (int r = 0; r < R_; ++r) a += tr[r] * bp[r];
    os[j] = f2bf(bf2f(qs[j]) + 2.0f * a);
  }
  uint4 o;
  o.x = (u32)os[0] | ((u32)os[1] << 16);
  o.y = (u32)os[2] | ((u32)os[3] << 16);
  o.z = (u32)os[4] | ((u32)os[5] << 16);
  o.w = (u32)os[6] | ((u32)os[7] << 16);
  *(uint4*)(qkvb + t) = o;
}

// ---- per-head V transpose ----
__global__ __launch_bounds__(256) void k_vtrans(const u16* __restrict__ qkvb,
                                                u16* __restrict__ Vt) {
  __shared__ u16 t[64][136];
  int s0 = blockIdx.x * 64, hh = blockIdx.y;
  int tid = threadIdx.x;
#pragma unroll
  for (int it = 0; it < 4; ++it) {
    int e = it * 2048 + tid * 8;
    int sr = e >> 7, sc = e & 127;
    *(uint4*)&t[sr][sc] =
        *(const uint4*)(qkvb + (size_t)(s0 + sr) * 6144 + 4096 + hh * 128 + sc);
  }
  __syncthreads();
#pragma unroll
  for (int it = 0; it < 4; ++it) {
    int q = it * 256 + tid;
    int dh = q >> 3, sc = (q & 7) * 8;
    u16 e0 = t[sc + 0][dh], e1 = t[sc + 1][dh], e2 = t[sc + 2][dh], e3 = t[sc + 3][dh];
    u16 e4 = t[sc + 4][dh], e5 = t[sc + 5][dh], e6 = t[sc + 6][dh], e7 = t[sc + 7][dh];
    uint4 o;
    o.x = (u32)e0 | ((u32)e1 << 16);
    o.y = (u32)e2 | ((u32)e3 << 16);
    o.z = (u32)e4 | ((u32)e5 << 16);
    o.w = (u32)e6 | ((u32)e7 << 16);
    *(uint4*)(Vt + ((size_t)hh * DH_ + dh) * S_ + s0 + sc) = o;
  }
}

// ======== MFMA flash attention v3: KV-parity split (flash-decoding style) ========
// grid (16, H, 2). Block (p,h,z) handles q-tiles {p, 31-p} over KV tiles with
// parity z, keeping its own online-softmax state; emits normalized partial O
// (plane z) + (m,l) stats. 512 blocks = 2 waves/SIMD (was 1). Combine in k_attnred.
__global__ __launch_bounds__(256) void k_attn3(const u16* __restrict__ qkvb,
                                               const u16* __restrict__ Vt,
                                               u16* __restrict__ Op,
                                               float2* __restrict__ st) {
  __shared__ u16 Ks[2][64 * 128];
  __shared__ u16 VTs[2][128 * 64];
  __shared__ u16 PT[4][64 * 16];
  const int tid = threadIdx.x;
  const int lane = tid & 63, w = tid >> 6;
  const int g = lane >> 4, l4 = lane & 15;
  const int p = blockIdx.x;
  const int hh = blockIdx.y;
  const int z = blockIdx.z;
  const int ld = 6144;
  const float rs = 0.08838834764831845f;
  const int qa0 = p * 64, qb0 = (31 - p) * 64;
  const int ntb = 32 - p;
  char* pt_w = (char*)&PT[w][0];

  const int qga = qa0 + w * 16 + l4;
  const int qgb = qb0 + w * 16 + l4;

  bf16x8 qfa[4], qfb[4];
#pragma unroll
  for (int kh = 0; kh < 4; ++kh) {
    qfa[kh] = *(const bf16x8*)(qkvb + (size_t)qga * ld + hh * DH_ + kh * 32 + g * 8);
    qfb[kh] = *(const bf16x8*)(qkvb + (size_t)qgb * ld + hh * DH_ + kh * 32 + g * 8);
  }

  float ma = -3.0e38f, la = 0.f, mb = -3.0e38f, lb = 0.f;
  f32x4 acc_a[8] = {}, acc_b[8] = {};
  bf16x8 pba[2], pbb[2];

  auto stage = [&](int buf, int kt) {
    const int kv0 = kt * 64;
#pragma unroll
    for (int i = 0; i < 4; ++i) {
      int rl = (w * 4 + i) * 4 + (lane >> 4);
      int cs = (lane & 15) ^ ((rl & 7) ^ (((rl >> 3) & 3) << 1));
      __builtin_amdgcn_global_load_lds(
          (const __attribute__((address_space(1))) void*)(
              qkvb + (size_t)(kv0 + rl) * ld + 2048 + hh * DH_ + cs * 8),
          (__attribute__((address_space(3))) void*)(&Ks[buf][(w * 4 + i) * 512]), 16, 0, 0);
    }
#pragma unroll
    for (int i = 0; i < 4; ++i) {
      int dh = (w * 4 + i) * 8 + (lane >> 3);
      int cs = (lane & 7) ^ (dh & 7);
      __builtin_amdgcn_global_load_lds(
          (const __attribute__((address_space(1))) void*)(
              Vt + ((size_t)hh * DH_ + dh) * S_ + kv0 + cs * 8),
          (__attribute__((address_space(3))) void*)(&VTs[buf][(w * 4 + i) * 512]), 16, 0, 0);
    }
  };

  auto softpb = [&](f32x4* sv, float& m, float& l, f32x4* acc, int qg, bool diag,
                    int kv0, bf16x8* pb) {
    float pv[16];
    float tmax = -3.0e38f;
#pragma unroll
    for (int kb = 0; kb < 4; ++kb)
#pragma unroll
      for (int r = 0; r < 4; ++r) {
        float s = sv[kb][r] * rs;
        if (diag) {
          int kglob = kv0 + kb * 16 + g * 4 + r;
          if (kglob > qg) s = -1.0e30f;
        }
        pv[kb * 4 + r] = s;
        tmax = fmaxf(tmax, s);
      }
    tmax = fmaxf(tmax, __shfl_xor(tmax, 16, 64));
    tmax = fmaxf(tmax, __shfl_xor(tmax, 32, 64));
    float mn = fmaxf(m, tmax);
    float corr = __expf(m - mn);
    m = mn;
    float ps = 0.f;
#pragma unroll
    for (int i = 0; i < 16; ++i) { pv[i] = __expf(pv[i] - mn); ps += pv[i]; }
    ps += __shfl_xor(ps, 16, 64);
    ps += __shfl_xor(ps, 32, 64);
    l = l * corr + ps;
#pragma unroll
    for (int f = 0; f < 8; ++f) {
      acc[f][0] *= corr; acc[f][1] *= corr; acc[f][2] *= corr; acc[f][3] *= corr;
    }
#pragma unroll
    for (int kb = 0; kb < 4; ++kb)
#pragma unroll
      for (int r = 0; r < 4; ++r) {
        int key = kb * 16 + g * 4 + r;
        int byte = (key * 32 + l4 * 2) ^ (((key >> 3) & 3) << 5);
        *(u16*)(pt_w + byte) = f2bf(pv[kb * 4 + r]);
      }
#pragma unroll
    for (int ks = 0; ks < 2; ++ks) {
      union { bf16x8 v; u16 s[8]; } ub;
#pragma unroll
      for (int j = 0; j < 8; ++j) {
        int key = ks * 32 + g * 8 + j;
        int byte = (key * 32 + l4 * 2) ^ (((key >> 3) & 3) << 5);
        ub.s[j] = *(const u16*)(pt_w + byte);
      }
      pb[ks] = ub.v;
    }
  };

  stage(0, z);   // harmless over-read if z >= ntb (rows stay in-bounds); loop skips
  asm volatile("s_waitcnt vmcnt(0)" ::: "memory");
  __syncthreads();

  int it = 0;
  for (int kt = z; kt < ntb; kt += 2, ++it) {
    const int kv0 = kt * 64;
    const int buf = it & 1;
    if (kt + 2 < ntb) stage(buf ^ 1, kt + 2);

    const char* kb_base = (const char*)&Ks[buf][0];
    const char* vb_base = (const char*)&VTs[buf][0];
    const bool doa = (kt <= p);

    f32x4 sa[4] = {}, sb[4] = {};
#pragma unroll
    for (int kb = 0; kb < 4; ++kb) {
#pragma unroll
      for (int kh = 0; kh < 4; ++kh) {
        int key = kb * 16 + l4;
        int ch = (kh * 4 + g) ^ ((key & 7) ^ (((key >> 3) & 3) << 1));
        bf16x8 af = *(const bf16x8*)(kb_base + key * 256 + ch * 16);
        if (doa) sa[kb] = MFMA16(af, qfa[kh], sa[kb]);
        sb[kb] = MFMA16(af, qfb[kh], sb[kb]);
      }
    }

    if (doa) softpb(sa, ma, la, acc_a, qga, kt == p, kv0, pba);
    softpb(sb, mb, lb, acc_b, qgb, kt == ntb - 1, kv0, pbb);

#pragma unroll
    for (int f = 0; f < 8; ++f) {
#pragma unroll
      for (int ks = 0; ks < 2; ++ks) {
        int dh = f * 16 + l4;
        int ch = (ks * 4 + g) ^ (dh & 7);
        bf16x8 va = *(const bf16x8*)(vb_base + dh * 128 + ch * 16);
        if (doa) acc_a[f] = MFMA16(va, pba[ks], acc_a[f]);
        acc_b[f] = MFMA16(va, pbb[ks], acc_b[f]);
      }
    }

    if (kt + 2 < ntb) {
      asm volatile("s_waitcnt vmcnt(0)" ::: "memory");
      __syncthreads();
    }
  }

  // partial epilogue: normalized O (0 when no tiles), plus (m, l) stats
  float inva = la > 0.f ? 1.f / la : 0.f;
  float invb = lb > 0.f ? 1.f / lb : 0.f;
  u16* opa = Op + (size_t)z * S_ * D_ + (size_t)qga * D_ + hh * DH_;
  u16* opb = Op + (size_t)z * S_ * D_ + (size_t)qgb * D_ + hh * DH_;
#pragma unroll
  for (int f = 0; f < 8; ++f)
#pragma unroll
    for (int r = 0; r < 4; ++r) {
      opa[f * 16 + g * 4 + r] = f2bf(acc_a[f][r] * inva);
      opb[f * 16 + g * 4 + r] = f2bf(acc_b[f][r] * invb);
    }
  if (g == 0) {   // lanes 0-15 cover the wave's 16 queries
    float2 va; va.x = ma; va.y = la;
    float2 vb; vb.x = mb; vb.y = lb;
    st[(size_t)z * S_ * H_ + (size_t)qga * H_ + hh] = va;
    st[(size_t)z * S_ * H_ + (size_t)qgb * H_ + hh] = vb;
  }
}

// ---- combine the two KV-parity partials: O = (w0*O0 + w1*O1)/(w0+w1) ----
__global__ __launch_bounds__(256) void k_attnred(const u16* __restrict__ Op,
                                                 const float2* __restrict__ st,
                                                 u16* __restrict__ out) {
  size_t t = (size_t)blockIdx.x * 256 + threadIdx.x;   // S*H*16 threads, 8 elems each
  int dh8 = (int)(t & 15);
  int sh  = (int)(t >> 4);          // s*H + h
  float2 s0 = st[sh];
  float2 s1 = st[(size_t)S_ * H_ + sh];
  float M = fmaxf(s0.x, s1.x);
  float w0 = s0.y * __expf(s0.x - M);
  float w1 = s1.y * __expf(s1.x - M);
  float inv = 1.f / (w0 + w1);      // >0 always: plane 0 covers >=1 tile per query
  w0 *= inv; w1 *= inv;
  int h = sh & 15, s = sh >> 4;
  size_t off = (size_t)s * D_ + (size_t)h * DH_ + (size_t)dh8 * 8;
  uint4 a = *(const uint4*)(Op + off);
  uint4 b = *(const uint4*)(Op + (size_t)S_ * D_ + off);
  u16 av[8] = {(u16)(a.x & 0xffff), (u16)(a.x >> 16), (u16)(a.y & 0xffff), (u16)(a.y >> 16),
               (u16)(a.z & 0xffff), (u16)(a.z >> 16), (u16)(a.w & 0xffff), (u16)(a.w >> 16)};
  u16 bv[8] = {(u16)(b.x & 0xffff), (u16)(b.x >> 16), (u16)(b.y & 0xffff), (u16)(b.y >> 16),
               (u16)(b.z & 0xffff), (u16)(b.z >> 16), (u16)(b.w & 0xffff), (u16)(b.w >> 16)};
  u16 ov[8];
#pragma unroll
  for (int j = 0; j < 8; ++j)
    ov[j] = f2bf(w0 * bf2f(av[j]) + w1 * bf2f(bv[j]));
  uint4 o;
  o.x = (u32)ov[0] | ((u32)ov[1] << 16);
  o.y = (u32)ov[2] | ((u32)ov[3] << 16);
  o.z = (u32)ov[4] | ((u32)ov[5] << 16);
  o.w = (u32)ov[6] | ((u32)ov[7] << 16);
  *(uint4*)(out + off) = o;
}

// ---------------- silu(gate)*up ----------------
__global__ __launch_bounds__(256) void k_silumul(u16* __restrict__ gu) {
  size_t i = ((size_t)blockIdx.x * 256 + threadIdx.x) * 4;
  int s = (int)(i >> 13);
  int f = (int)(i & 8191);
  u16* gp = gu + (size_t)s * (2 * DFF_) + f;
  ushort4 gt = *(ushort4*)gp;
  ushort4 up = *(ushort4*)(gp + DFF_);
  float g0 = bf2f(gt.x), g1 = bf2f(gt.y), g2 = bf2f(gt.z), g3 = bf2f(gt.w);
  float u0 = bf2f(up.x), u1 = bf2f(up.y), u2 = bf2f(up.z), u3 = bf2f(up.w);
  ushort4 o;
  o.x = f2bf(g0 / (1.f + __expf(-g0)) * u0);
  o.y = f2bf(g1 / (1.f + __expf(-g1)) * u1);
  o.z = f2bf(g2 / (1.f + __expf(-g2)) * u2);
  o.w = f2bf(g3 / (1.f + __expf(-g3)) * u3);
  *(ushort4*)gp = o;
}

// ---------------- gumbel softmax, ONE-PASS ----------------
__global__ __launch_bounds__(256) void k_gumbel(const float* __restrict__ logits,
                                                const float* __restrict__ u,
                                                u16* __restrict__ g) {
  __shared__ float z[V_];
  __shared__ float sred[4];
  int s = blockIdx.x;
  const float* lp = logits + (size_t)s * V_;
  const float* up = u + (size_t)s * V_;
  float m = -3.0e38f;
  for (int v4 = threadIdx.x; v4 < V_ / 4; v4 += 256) {
    float4 lv = *(const float4*)(lp + v4 * 4);
    float4 uv = *(const float4*)(up + v4 * 4);
    float z0 = lv.x - __logf(-__logf(uv.x + 1e-10f) + 1e-10f);
    float z1 = lv.y - __logf(-__logf(uv.y + 1e-10f) + 1e-10f);
    float z2 = lv.z - __logf(-__logf(uv.z + 1e-10f) + 1e-10f);
    float z3 = lv.w - __logf(-__logf(uv.w + 1e-10f) + 1e-10f);
    *(float4*)(z + v4 * 4) = make_float4(z0, z1, z2, z3);
    m = fmaxf(fmaxf(fmaxf(m, z0), fmaxf(z1, z2)), z3);
  }
#pragma unroll
  for (int msk = 1; msk < 64; msk <<= 1) m = fmaxf(m, __shfl_xor(m, msk, 64));
  if ((threadIdx.x & 63) == 0) sred[threadIdx.x >> 6] = m;
  __syncthreads();
  float M = fmaxf(fmaxf(sred[0], sred[1]), fmaxf(sred[2], sred[3]));
  float l = 0.f;
  for (int v4 = threadIdx.x; v4 < V_ / 4; v4 += 256) {
    float4 zv = *(float4*)(z + v4 * 4);
    zv.x = __expf(zv.x - M); zv.y = __expf(zv.y - M);
    zv.z = __expf(zv.z - M); zv.w = __expf(zv.w - M);
    *(float4*)(z + v4 * 4) = zv;
    l += (zv.x + zv.y) + (zv.z + zv.w);
  }
#pragma unroll
  for (int msk = 1; msk < 64; msk <<= 1) l += __shfl_xor(l, msk, 64);
  __syncthreads();
  if ((threadIdx.x & 63) == 0) sred[threadIdx.x >> 6] = l;
  __syncthreads();
  float inv = 1.f / (sred[0] + sred[1] + sred[2] + sred[3]);
  u16* gp = g + (size_t)s * V_;
  for (int v4 = threadIdx.x; v4 < V_ / 4; v4 += 256) {
    float4 zv = *(float4*)(z + v4 * 4);
    ushort4 o;
    o.x = f2bf(zv.x * inv); o.y = f2bf(zv.y * inv);
    o.z = f2bf(zv.z * inv); o.w = f2bf(zv.w * inv);
    *(ushort4*)(gp + v4 * 4) = o;
  }
}

extern "C" void kernel_launch(void* const* d_in, const int* in_sizes, int n_in,
                              void* d_out, int out_size, void* d_ws, size_t ws_size,
                              hipStream_t stream) {
  const int*   ids        = (const int*)d_in[0];
  const float* u          = (const float*)d_in[1];
  const float* emb        = (const float*)d_in[2];
  const float* attn_scale = (const float*)d_in[3];
  const float* gu_scale   = (const float*)d_in[4];
  const float* dn_scale   = (const float*)d_in[5];
  const float* lora_A     = (const float*)d_in[6];
  const float* lora_B     = (const float*)d_in[7];
  const float* norm_w     = (const float*)d_in[8];
  const float* fnorm_w    = (const float*)d_in[9];
  const int*   attn_idx   = (const int*)d_in[10];
  const int*   gu_idx     = (const int*)d_in[11];
  const int*   dn_idx     = (const int*)d_in[12];

  float* out_se = (float*)d_out;
  float* out_lg = (float*)d_out + (size_t)S_ * D_;

  char* W = (char*)d_ws;
  float* h    = (float*)(W);                          // 16 MiB (layer phase)
  u16*   xb   = (u16*)(W + ((size_t)16 << 20));       // 8 MiB
  u16*   qkvb = (u16*)(W + ((size_t)72 << 20));       // 24 MiB
  u16*   Vtb  = (u16*)(W + ((size_t)96 << 20));       // 8 MiB
  u16*   ob   = (u16*)(W + ((size_t)104 << 20));      // 8 MiB
  u16*   gub  = (u16*)(W + ((size_t)112 << 20));      // 64 MiB
  // attention partials live in gub's region (dead during attention):
  u16*    apart = (u16*)(W + ((size_t)112 << 20));    // 16 MiB (2 planes of S*D bf16)
  float2* astat = (float2*)(W + ((size_t)128 << 20)); // 512 KiB (2 planes of S*H)
  u16*   wdq  = (u16*)(W + ((size_t)176 << 20));      // 64 MiB
  float* Tl   = (float*)(W + ((size_t)240 << 20));    // 192 KiB
  // head phase: embb dies after logits; gsm overwrites it; embT lives at W[125,250)
  u16*   embb = (u16*)(W);                            // 125 MiB
  u16*   gsm  = (u16*)(W);                            // 125 MiB (after logits GEMM)
  u16*   embT = (u16*)(W + ((size_t)125 << 20));      // 125 MiB
  u16*   xbh  = (u16*)d_out;                          // final-norm out, parked in out_se
  float* Pk   = (float*)(W + ((size_t)250 << 20));    // 64 MiB split-K partials
  const bool big = ws_size >= ((size_t)314 << 20);
  const size_t ZS = (size_t)4 * 1024 * 1024;

  dim3 b256(256), b512(512);

  k_gather<<<dim3(S_ * D_ / 256), b256, 0, stream>>>(ids, emb, h);

  for (int l = 0; l < L_; ++l) {
    const int*   aidx = attn_idx + (size_t)l * 4 * D_ * D_;
    const float* ascl = attn_scale + (size_t)l * 4 * D_ * (D_ / 64);
    const float* lA   = lora_A + (size_t)l * 4 * R_ * D_;
    const float* lB   = lora_B + (size_t)l * 4 * D_ * R_;

    k_rmsnorm<<<dim3(S_), b256, 0, stream>>>(h, norm_w + (size_t)l * 2 * D_, xb);
    k_dequant<<<dim3(4 * D_ * D_ / 8 / 256), b256, 0, stream>>>(aidx, ascl, wdq, 11);
    k_gemm256<OUT_BF16><<<dim3(3 * D_ / 256, 8), b512, 0, stream>>>(
        xb, D_, wdq, D_, qkvb, 3 * D_, D_, 0);
    k_lora_down<<<dim3(S_), b256, 0, stream>>>(xb, lA, Tl, 3);
    k_lora_up_qkv<<<dim3(S_ * 3 * D_ / 8 / 256), b256, 0, stream>>>(qkvb, Tl, lB);
    k_vtrans<<<dim3(S_ / 64, H_), b256, 0, stream>>>(qkvb, Vtb);
    k_attn3<<<dim3(16, H_, 2), b256, 0, stream>>>(qkvb, Vtb, apart, astat);
    k_attnred<<<dim3(S_ * H_ * 16 / 256), b256, 0, stream>>>(apart, astat, ob);
    if (big) {
      k_gemm256<OUT_F32><<<dim3(D_ / 256, 8, 4), b512, 0, stream>>>(
          ob, D_, wdq + (size_t)3 * D_ * D_, D_, Pk, D_, D_ / 4, ZS);
      k_red<<<dim3(4096), b256, 0, stream>>>(Pk, h, 1);
    } else {
      k_gemm256<OUT_F32_ACC><<<dim3(D_ / 256, 8), b512, 0, stream>>>(
          ob, D_, wdq + (size_t)3 * D_ * D_, D_, h, D_, D_, 0);
    }
    k_lora_down<<<dim3(S_), b256, 0, stream>>>(ob, lA + (size_t)3 * R_ * D_, Tl, 1);
    k_lora_up<<<dim3(S_ * D_ / 256), b256, 0, stream>>>(h, D_, Tl, lB + (size_t)3 * D_ * R_, 1);

    k_rmsnorm<<<dim3(S_), b256, 0, stream>>>(h, norm_w + (size_t)l * 2 * D_ + D_, xb);
    k_dequant<<<dim3(2 * DFF_ * D_ / 8 / 256), b256, 0, stream>>>(
        gu_idx + (size_t)l * 2 * DFF_ * D_, gu_scale + (size_t)l * 2 * DFF_ * (D_ / 64), wdq, 11);
    k_gemm256<OUT_BF16><<<dim3(2 * DFF_ / 256, 8), b512, 0, stream>>>(
        xb, D_, wdq, D_, gub, 2 * DFF_, D_, 0);
    k_silumul<<<dim3(S_ * DFF_ / 4 / 256), b256, 0, stream>>>(gub);
    k_dequant<<<dim3(D_ * DFF_ / 8 / 256), b256, 0, stream>>>(
        dn_idx + (size_t)l * D_ * DFF_, dn_scale + (size_t)l * D_ * (DFF_ / 64), wdq, 13);
    if (big) {
      k_gemm256<OUT_F32><<<dim3(D_ / 256, 8, 4), b512, 0, stream>>>(
          gub, 2 * DFF_, wdq, DFF_, Pk, D_, DFF_ / 4, ZS);
      k_red<<<dim3(4096), b256, 0, stream>>>(Pk, h, 1);
    } else {
      k_gemm256<OUT_F32_ACC><<<dim3(D_ / 256, 8), b512, 0, stream>>>(
          gub, 2 * DFF_, wdq, DFF_, h, D_, DFF_, 0);
    }
  }

  // ---- head ----
  k_rmsnorm<<<dim3(S_), b256, 0, stream>>>(h, fnorm_w, xbh);   // h read before embprep clobbers W[0,..)
  k_embprep<<<dim3(V_ / 64, D_ / 64), b256, 0, stream>>>(emb, embb, embT);
  k_gemm256<OUT_F32><<<dim3(V_ / 256, 8), b512, 0, stream>>>(
      xbh, D_, embb, D_, out_lg, V_, D_, 0);
  k_gumbel<<<dim3(S_), b256, 0, stream>>>(out_lg, u, gsm);     // overwrites dead embb region
  if (big) {
    k_gemm256<OUT_F32><<<dim3(D_ / 256, 8, 4), b512, 0, stream>>>(
        gsm, V_, embT, V_, Pk, D_, V_ / 4, ZS);
    k_red<<<dim3(4096), b256, 0, stream>>>(Pk, out_se, 0);
  } else {
    k_gemm256<OUT_F32><<<dim3(D_ / 256, 8), b512, 0, stream>>>(
        gsm, V_, embT, V_, out_se, D_, V_, 0);
  }
}